// Round 1
// baseline (2219.562 us; speedup 1.0000x reference)
//
#include <hip/hip_runtime.h>
#include <hip/hip_bf16.h>

using bf16 = __hip_bfloat16;
typedef __attribute__((ext_vector_type(8))) short bf16x8;   // 8 bf16 (4 VGPRs)
typedef __attribute__((ext_vector_type(4))) float f32x4;    // MFMA accumulator

constexpr int NN = 200000;   // nodes
constexpr int NE = 800000;   // edges
constexpr int NG = 4000;     // graphs
constexpr int ED = 16;       // edge feature dim
constexpr float BN_EPS = 1e-5f;

// ---------------- storage-type helpers (fp32 or bf16 node features) --------
__device__ __forceinline__ float  ld1(const float* p) { return *p; }
__device__ __forceinline__ float  ld1(const bf16*  p) { return __bfloat162float(*p); }
__device__ __forceinline__ float2 ld2f(const float* p) { return *(const float2*)p; }
__device__ __forceinline__ float2 ld2f(const bf16*  p) {
    union { ushort2 u; bf16 h[2]; } t;
    t.u = *(const ushort2*)p;
    return make_float2(__bfloat162float(t.h[0]), __bfloat162float(t.h[1]));
}
__device__ __forceinline__ float4 ld4(const float* p) { return *(const float4*)p; }
__device__ __forceinline__ float4 ld4(const bf16*  p) {
    union { ushort4 u; bf16 h[4]; } t;
    t.u = *(const ushort4*)p;
    return make_float4(__bfloat162float(t.h[0]), __bfloat162float(t.h[1]),
                       __bfloat162float(t.h[2]), __bfloat162float(t.h[3]));
}
__device__ __forceinline__ void st1(float* p, float v) { *p = v; }
__device__ __forceinline__ void st1(bf16*  p, float v) { *p = __float2bfloat16(v); }
__device__ __forceinline__ void st4(float* p, float4 v) { *(float4*)p = v; }
__device__ __forceinline__ void st4(bf16*  p, float4 v) {
    union { ushort4 u; bf16 h[4]; } t;
    t.h[0] = __float2bfloat16(v.x); t.h[1] = __float2bfloat16(v.y);
    t.h[2] = __float2bfloat16(v.z); t.h[3] = __float2bfloat16(v.w);
    *(ushort4*)p = t.u;
}
__device__ __forceinline__ float bfraw(unsigned short u) {
    union { unsigned short s; bf16 h; } t; t.s = u;
    return __bfloat162float(t.h);
}

// ===========================================================================
// CSR-by-dst build (once per call; reused by all 3 conv layers)
// ===========================================================================
constexpr int SCAN_CHUNK = 1024;
constexpr int SCAN_NBLK  = (NN + SCAN_CHUNK - 1) / SCAN_CHUNK;   // 196

__global__ __launch_bounds__(256)
void k_hist(const int* __restrict__ ei, int* __restrict__ cnt)
{
    int e = blockIdx.x * 256 + threadIdx.x;
    const int stride = gridDim.x * 256;
    for (; e < NE; e += stride) atomicAdd(&cnt[ei[NE + e]], 1);
}

__global__ __launch_bounds__(256)
void k_scan_block(const int* __restrict__ cnt, int* __restrict__ bsum)
{
    __shared__ int red[256];
    const int b = blockIdx.x, t = threadIdx.x;
    const int base = b * SCAN_CHUNK + t * 4;
    int s = 0;
    #pragma unroll
    for (int k = 0; k < 4; ++k) { const int i = base + k; if (i < NN) s += cnt[i]; }
    red[t] = s; __syncthreads();
    for (int off = 128; off > 0; off >>= 1) {
        if (t < off) red[t] += red[t + off];
        __syncthreads();
    }
    if (t == 0) bsum[b] = red[0];
}

__global__ __launch_bounds__(256)
void k_scan_top(int* __restrict__ bsum, int n)
{
    __shared__ int sh[256];
    const int t = threadIdx.x;
    const int orig = (t < n) ? bsum[t] : 0;
    sh[t] = orig; __syncthreads();
    for (int off = 1; off < 256; off <<= 1) {
        const int v = (t >= off) ? sh[t - off] : 0;
        __syncthreads();
        sh[t] += v;
        __syncthreads();
    }
    if (t < n) bsum[t] = sh[t] - orig;   // exclusive
}

__global__ __launch_bounds__(256)
void k_scan_emit(const int* __restrict__ cnt, const int* __restrict__ bsum,
                 int* __restrict__ row_ptr, int* __restrict__ cursor)
{
    __shared__ int sh[256];
    const int b = blockIdx.x, t = threadIdx.x;
    const int base = b * SCAN_CHUNK + t * 4;
    int c[4]; int s = 0;
    #pragma unroll
    for (int k = 0; k < 4; ++k) {
        const int i = base + k;
        c[k] = (i < NN) ? cnt[i] : 0;    // read BEFORE aliased write below
        s += c[k];
    }
    const int orig = s;
    sh[t] = s; __syncthreads();
    for (int off = 1; off < 256; off <<= 1) {
        const int v = (t >= off) ? sh[t - off] : 0;
        __syncthreads();
        sh[t] += v;
        __syncthreads();
    }
    int run = bsum[b] + sh[t] - orig;     // exclusive prefix of this thread
    #pragma unroll
    for (int k = 0; k < 4; ++k) {
        const int i = base + k;
        if (i < NN) { row_ptr[i] = run; cursor[i] = run; run += c[k]; }
    }
    if (b == 0 && t == 0) row_ptr[NN] = NE;
}

__global__ __launch_bounds__(256)
void k_scatter(const int* __restrict__ ei, int* __restrict__ cursor,
               int* __restrict__ perm)
{
    int e = blockIdx.x * 256 + threadIdx.x;
    const int stride = gridDim.x * 256;
    for (; e < NE; e += stride) {
        const int d = ei[NE + e];
        const int p = atomicAdd(&cursor[d], 1);
        perm[p] = e;
    }
}

// Pre-gather edge metadata into perm order (fallback path: fp32 [NE,16]).
__global__ __launch_bounds__(256)
void k_gather_edges(const int* __restrict__ ei, const float* __restrict__ ea,
                    const int* __restrict__ perm, int* __restrict__ src_perm,
                    float* __restrict__ ea_perm)
{
    const int t = blockIdx.x * 256 + threadIdx.x;    // over NE*16
    if (t >= NE * ED) return;
    const int idx = t >> 4, k = t & 15;
    const int e = perm[idx];
    ea_perm[t] = ea[(size_t)e * ED + k];
    if (k == 0) src_perm[idx] = ei[e];
}

// Full path: edge features as bf16 [NE,32], zero-padded K 16->32 (MFMA K=32).
__global__ __launch_bounds__(256)
void k_gather_edges_bf(const int* __restrict__ ei, const float* __restrict__ ea,
                       const int* __restrict__ perm, int* __restrict__ src_perm,
                       bf16* __restrict__ ea_bf)
{
    const int t = blockIdx.x * 256 + threadIdx.x;    // over NE*16 (2 bf16 each)
    if (t >= NE * 16) return;
    const int idx = t >> 4, k2 = (t & 15) * 2;       // k2 in 0..30
    const int e = perm[idx];
    union { ushort2 u; bf16 h[2]; } o;
    if (k2 < ED) {
        const float2 v = *(const float2*)&ea[(size_t)e * ED + k2];
        o.h[0] = __float2bfloat16(v.x);
        o.h[1] = __float2bfloat16(v.y);
    } else {
        o.u = make_ushort2(0, 0);
    }
    *(ushort2*)&ea_bf[(size_t)idx * 32 + k2] = o.u;
    if ((t & 15) == 0) src_perm[idx] = ei[e];
}

// One-shot: W[K,N] fp32 -> Wt[N,K] bf16 (transposed for the MFMA GEMM).
__global__ __launch_bounds__(256)
void k_wt(const float* __restrict__ W, bf16* __restrict__ Wt, int K, int N)
{
    const int i = blockIdx.x * 256 + threadIdx.x;
    if (i >= K * N) return;
    const int k = i / N, n = i % N;
    Wt[(size_t)n * K + k] = __float2bfloat16(W[i]);
}

// One-shot: We[16,cin] fp32 -> Wte[cin,32] bf16, K zero-padded 16->32.
__global__ __launch_bounds__(256)
void k_wte(const float* __restrict__ We, bf16* __restrict__ Wte, int cin)
{
    const int i = blockIdx.x * 256 + threadIdx.x;    // over cin*32
    if (i >= cin * 32) return;
    const int n = i >> 5, k = i & 31;
    Wte[i] = __float2bfloat16((k < ED) ? We[k * cin + n] : 0.f);
}

// ===========================================================================
// Fallback per-node aggregation (original node_agg2, verified path).
// ===========================================================================
template<typename XT, int CIN>
__global__ __launch_bounds__(256)
void node_agg2(const XT* __restrict__ x, const float* __restrict__ ea_perm,
               const int* __restrict__ src_perm, const int* __restrict__ row_ptr,
               const float* __restrict__ We, const float* __restrict__ be,
               bf16* __restrict__ agg)
{
    constexpr int HALF = CIN / 2;     // channels per wave
    constexpr int CPL  = HALF / 64;   // channels per lane (1 or 2)
    const int lane = threadIdx.x & 63;
    const int gw   = blockIdx.x * 4 + (threadIdx.x >> 6);
    const int node = gw >> 1;
    const int half = gw & 1;
    if (node >= NN) return;
    const int c0 = half * HALF + lane * CPL;

    float wcol[16 * CPL];
    #pragma unroll
    for (int k = 0; k < ED; ++k)
        #pragma unroll
        for (int q = 0; q < CPL; ++q)
            wcol[k * CPL + q] = We[k * CIN + c0 + q];
    float bv[CPL];
    #pragma unroll
    for (int q = 0; q < CPL; ++q) bv[q] = be[c0 + q];

    float acc[CPL];
    if (CPL == 2) {
        const float2 v = ld2f(&x[(size_t)node * CIN + c0]);
        acc[0] = v.x; acc[CPL - 1] = v.y;
    } else {
        acc[0] = ld1(&x[(size_t)node * CIN + c0]);
    }

    const int e0 = row_ptr[node], e1 = row_ptr[node + 1];
    for (int base = e0; base < e1; base += 4) {
        int ss[4];
        #pragma unroll
        for (int j = 0; j < 4; ++j) {
            int idx = base + j; if (idx >= e1) idx = e1 - 1;
            ss[j] = src_perm[idx];
        }
        float xv0[4], xv1[4];
        #pragma unroll
        for (int j = 0; j < 4; ++j) {
            if (CPL == 2) {
                const float2 v = ld2f(&x[(size_t)ss[j] * CIN + c0]);
                xv0[j] = v.x; xv1[j] = v.y;
            } else {
                xv0[j] = ld1(&x[(size_t)ss[j] * CIN + c0]);
            }
        }
        #pragma unroll
        for (int j = 0; j < 4; ++j) {
            if (base + j < e1) {
                const float* ep = ea_perm + (size_t)(base + j) * ED;
                float ev[ED];
                *(float4*)&ev[0]  = *(const float4*)(ep + 0);
                *(float4*)&ev[4]  = *(const float4*)(ep + 4);
                *(float4*)&ev[8]  = *(const float4*)(ep + 8);
                *(float4*)&ev[12] = *(const float4*)(ep + 12);
                float m[CPL];
                #pragma unroll
                for (int q = 0; q < CPL; ++q) m[q] = bv[q];
                #pragma unroll
                for (int k = 0; k < ED; ++k)
                    #pragma unroll
                    for (int q = 0; q < CPL; ++q)
                        m[q] = fmaf(ev[k], wcol[k * CPL + q], m[q]);
                m[0] += xv0[j];
                if (CPL == 2) m[CPL - 1] += xv1[j];
                #pragma unroll
                for (int q = 0; q < CPL; ++q) acc[q] += fmaxf(m[q], 0.f);
            }
        }
    }

    if (CPL == 2) {
        union { ushort2 u; bf16 h[2]; } t;
        t.h[0] = __float2bfloat16(acc[0]);
        t.h[1] = __float2bfloat16(acc[CPL - 1]);
        *(ushort2*)&agg[(size_t)node * CIN + c0] = t.u;
    } else {
        st1(&agg[(size_t)node * CIN + c0], acc[0]);
    }
}

// ===========================================================================
// Full-path aggregation v3: edge MLP precomputed (emsg, bf16, perm order);
// this kernel is a lean stream: acc += relu(x[src] + emsg[e]).
// Wave handles 128 channels (2 bf16/lane); WPN = CIN/128 waves per node.
// CSR indices scalarized via readfirstlane -> s_load path; 8-deep prefetch.
// ===========================================================================
template<typename XT, int CIN>
__global__ __launch_bounds__(256)
void node_agg3(const XT* __restrict__ x, const bf16* __restrict__ emsg,
               const int* __restrict__ src_perm, const int* __restrict__ row_ptr,
               bf16* __restrict__ agg)
{
    constexpr int WPN = CIN / 128;    // waves per node (1 or 2)
    const int lane = threadIdx.x & 63;
    int gw = blockIdx.x * 4 + (threadIdx.x >> 6);
    gw = __builtin_amdgcn_readfirstlane(gw);   // wave-uniform -> SGPR
    const int node = gw / WPN;
    const int half = gw - node * WPN;
    if (node >= NN) return;
    const int c0 = half * 128 + lane * 2;

    const float2 a0 = ld2f(&x[(size_t)node * CIN + c0]);
    float acc0 = a0.x, acc1 = a0.y;

    const int e0 = row_ptr[node], e1 = row_ptr[node + 1];
    for (int base = e0; base < e1; base += 8) {
        int ss[8];
        #pragma unroll
        for (int j = 0; j < 8; ++j) {
            int idx = base + j; if (idx >= e1) idx = e1 - 1;
            ss[j] = src_perm[idx];
        }
        float2 xv[8]; ushort2 mv[8];
        #pragma unroll
        for (int j = 0; j < 8; ++j) {
            int idx = base + j; if (idx >= e1) idx = e1 - 1;
            xv[j] = ld2f(&x[(size_t)ss[j] * CIN + c0]);
            mv[j] = *(const ushort2*)&emsg[(size_t)idx * CIN + c0];
        }
        #pragma unroll
        for (int j = 0; j < 8; ++j) {
            if (base + j < e1) {
                acc0 += fmaxf(xv[j].x + bfraw(mv[j].x), 0.f);
                acc1 += fmaxf(xv[j].y + bfraw(mv[j].y), 0.f);
            }
        }
    }

    union { ushort2 u; bf16 h[2]; } t;
    t.h[0] = __float2bfloat16(acc0);
    t.h[1] = __float2bfloat16(acc1);
    *(ushort2*)&agg[(size_t)node * CIN + c0] = t.u;
}

// ===========================================================================
// MFMA GEMM: C[M,N] = (relu?)(A[M,K] @ Wt[N,K]^T + bias)
// A bf16 row-major, Wt bf16 [N,K] (pre-transposed), C bf16, fp32 accumulate.
// 128x128 tile, BK=32, 256 threads = 4 waves (each 64x64), 16x16x32 MFMA.
// LDS rows padded to 40 bf16 (80 B) to break bank aliasing on ds_read_b128.
// Used for conv layers (K=128/256, N=256, RELU) and emsg (K=32, N=cin, no relu).
// ===========================================================================
template<int K, int N, bool RELU>
__global__ __launch_bounds__(256)
void gemm_mfma(const bf16* __restrict__ A, const bf16* __restrict__ Wt,
               const float* __restrict__ bias, bf16* __restrict__ C, int M)
{
    constexpr int LDT = 40;                 // padded LDS row stride (bf16)
    __shared__ short As[128 * LDT];
    __shared__ short Bs[128 * LDT];
    const int tid  = threadIdx.x;
    const int bm   = blockIdx.y * 128;
    const int bn   = blockIdx.x * 128;
    const int lane = tid & 63;
    const int wave = tid >> 6;
    const int wr   = (wave >> 1) * 64;      // wave row offset in tile
    const int wc   = (wave & 1) * 64;       // wave col offset
    const int l15  = lane & 15;
    const int quad = lane >> 4;

    f32x4 acc[4][4];
    #pragma unroll
    for (int i = 0; i < 4; ++i)
        #pragma unroll
        for (int j = 0; j < 4; ++j)
            acc[i][j] = (f32x4){0.f, 0.f, 0.f, 0.f};

    for (int k0 = 0; k0 < K; k0 += 32) {
        // stage A(128x32) and Wt(128x32) tiles -> LDS (16 B per thread-chunk)
        #pragma unroll
        for (int c = tid; c < 512; c += 256) {
            const int row = c >> 2, part = c & 3;
            int ar = bm + row; if (ar >= M) ar = M - 1;   // clamp; rows discarded at store
            *(ulonglong2*)&As[row * LDT + part * 8] =
                *(const ulonglong2*)&A[(size_t)ar * K + k0 + part * 8];
            *(ulonglong2*)&Bs[row * LDT + part * 8] =
                *(const ulonglong2*)&Wt[(size_t)(bn + row) * K + k0 + part * 8];
        }
        __syncthreads();

        bf16x8 af[4], bfr[4];
        #pragma unroll
        for (int i = 0; i < 4; ++i) {
            af[i]  = *(const bf16x8*)&As[(wr + i * 16 + l15) * LDT + quad * 8];
            bfr[i] = *(const bf16x8*)&Bs[(wc + i * 16 + l15) * LDT + quad * 8];
        }
        #pragma unroll
        for (int mi = 0; mi < 4; ++mi)
            #pragma unroll
            for (int ni = 0; ni < 4; ++ni)
                acc[mi][ni] = __builtin_amdgcn_mfma_f32_16x16x32_bf16(
                                  af[mi], bfr[ni], acc[mi][ni], 0, 0, 0);
        __syncthreads();
    }

    // epilogue: D row = quad*4+reg, col = lane&15 (m89-verified C/D layout)
    float bv[4];
    #pragma unroll
    for (int ni = 0; ni < 4; ++ni)
        bv[ni] = bias[bn + wc + ni * 16 + l15];
    #pragma unroll
    for (int mi = 0; mi < 4; ++mi) {
        const int row0 = bm + wr + mi * 16 + quad * 4;
        #pragma unroll
        for (int r = 0; r < 4; ++r) {
            const int row = row0 + r;
            if (row < M) {
                #pragma unroll
                for (int ni = 0; ni < 4; ++ni) {
                    float v = acc[mi][ni][r] + bv[ni];
                    if (RELU) v = fmaxf(v, 0.f);
                    C[(size_t)row * N + bn + wc + ni * 16 + l15] = __float2bfloat16(v);
                }
            }
        }
    }
}

// ---------------------------------------------------------------------------
// fp32 GEMM (dense head only): C = (relu?)(A @ W + bias)
// ---------------------------------------------------------------------------
template<bool RELU, typename InT, typename OutT>
__global__ __launch_bounds__(256)
void gemm_rk(const InT* __restrict__ A, const float* __restrict__ W,
             const float* __restrict__ bias, OutT* __restrict__ C,
             int M, int N, int K)
{
    __shared__ float Asm[16][64];
    __shared__ float Wsm[16][64];
    const int bm = blockIdx.y * 64;
    const int bn = blockIdx.x * 64;
    const int tid = threadIdx.x;
    const int tx = tid & 15, ty = tid >> 4;
    const int ar = tid >> 2, ac = (tid & 3) * 4;
    const int wrr = tid >> 4, wcc = (tid & 15) * 4;

    float acc[4][4] = {};

    for (int k0 = 0; k0 < K; k0 += 16) {
        float4 av = make_float4(0.f, 0.f, 0.f, 0.f);
        if (bm + ar < M)
            av = ld4(A + (size_t)(bm + ar) * K + k0 + ac);
        Asm[ac + 0][ar] = av.x; Asm[ac + 1][ar] = av.y;
        Asm[ac + 2][ar] = av.z; Asm[ac + 3][ar] = av.w;

        float4 wv = make_float4(0.f, 0.f, 0.f, 0.f);
        if (bn + wcc < N)
            wv = *(const float4*)(W + (size_t)(k0 + wrr) * N + bn + wcc);
        *(float4*)&Wsm[wrr][wcc] = wv;
        __syncthreads();

        #pragma unroll
        for (int k = 0; k < 16; ++k) {
            const float4 a4 = *(const float4*)&Asm[k][ty * 4];
            const float4 b4 = *(const float4*)&Wsm[k][tx * 4];
            const float aa[4] = {a4.x, a4.y, a4.z, a4.w};
            const float bb[4] = {b4.x, b4.y, b4.z, b4.w};
            #pragma unroll
            for (int i = 0; i < 4; ++i)
                #pragma unroll
                for (int j = 0; j < 4; ++j)
                    acc[i][j] += aa[i] * bb[j];
        }
        __syncthreads();
    }

    float bvals[4];
    #pragma unroll
    for (int j = 0; j < 4; ++j) {
        const int col = bn + tx * 4 + j;
        bvals[j] = (col < N) ? bias[col] : 0.f;
    }
    #pragma unroll
    for (int i = 0; i < 4; ++i) {
        const int row = bm + ty * 4 + i;
        if (row >= M) continue;
        float v[4];
        #pragma unroll
        for (int j = 0; j < 4; ++j) {
            v[j] = acc[i][j] + bvals[j];
            if (RELU) v[j] = fmaxf(v[j], 0.f);
        }
        if (bn + tx * 4 + 3 < N) {
            st4(C + (size_t)row * N + bn + tx * 4, make_float4(v[0], v[1], v[2], v[3]));
        } else {
            #pragma unroll
            for (int j = 0; j < 4; ++j) {
                const int col = bn + tx * 4 + j;
                if (col < N) st1(C + (size_t)row * N + col, v[j]);
            }
        }
    }
}

// ---------------------------------------------------------------------------
// BatchNorm stats + normalize (bf16 H), fp32 accumulate.
// ---------------------------------------------------------------------------
template<typename InT>
__global__ __launch_bounds__(256)
void bn_stats(const InT* __restrict__ h, float* __restrict__ stats, int nodes)
{
    const int c = threadIdx.x;
    size_t n0 = (size_t)blockIdx.x * 128;
    size_t n1 = n0 + 128; if (n1 > (size_t)nodes) n1 = nodes;
    if (n0 >= (size_t)nodes) return;
    float s = 0.f, s2 = 0.f;
    for (size_t n = n0; n < n1; ++n) {
        const float v = ld1(&h[n * 256 + c]);
        s += v; s2 += v * v;
    }
    atomicAdd(&stats[c], s);
    atomicAdd(&stats[256 + c], s2);
}

template<typename T>
__global__ __launch_bounds__(256)
void bn_norm(T* __restrict__ h, const float* __restrict__ stats,
             const float* __restrict__ gamma, const float* __restrict__ beta, int n4)
{
    int i = blockIdx.x * 256 + threadIdx.x;
    const int stride = gridDim.x * 256;
    const float inv = 1.f / (float)NN;
    for (; i < n4; i += stride) {
        const int c = (i * 4) & 255;
        float4 v  = ld4(h + (size_t)i * 4);
        const float4 s  = *(const float4*)&stats[c];
        const float4 s2 = *(const float4*)&stats[256 + c];
        const float4 g  = *(const float4*)&gamma[c];
        const float4 b  = *(const float4*)&beta[c];
        float mu, sc;
        mu = s.x * inv; sc = rsqrtf(s2.x * inv - mu * mu + BN_EPS) * g.x; v.x = (v.x - mu) * sc + b.x;
        mu = s.y * inv; sc = rsqrtf(s2.y * inv - mu * mu + BN_EPS) * g.y; v.y = (v.y - mu) * sc + b.y;
        mu = s.z * inv; sc = rsqrtf(s2.z * inv - mu * mu + BN_EPS) * g.z; v.z = (v.z - mu) * sc + b.z;
        mu = s.w * inv; sc = rsqrtf(s2.w * inv - mu * mu + BN_EPS) * g.w; v.w = (v.w - mu) * sc + b.w;
        st4(h + (size_t)i * 4, v);
    }
}

// ---------------------------------------------------------------------------
// Mean-pool over sorted batch ids.
// ---------------------------------------------------------------------------
template<typename InT>
__global__ __launch_bounds__(256)
void pool_sum(const InT* __restrict__ h, const int* __restrict__ batch,
              float* __restrict__ sums, float* __restrict__ cnts)
{
    const int c = threadIdx.x;
    size_t n0 = (size_t)blockIdx.x * 128;
    size_t n1 = n0 + 128; if (n1 > (size_t)NN) n1 = NN;
    if (n0 >= (size_t)NN) return;
    int cur = batch[n0];
    float s = 0.f, cnt = 0.f;
    for (size_t n = n0; n < n1; ++n) {
        const int b = batch[n];
        if (b != cur) {
            atomicAdd(&sums[(size_t)cur * 256 + c], s);
            if (c == 0) atomicAdd(&cnts[cur], cnt);
            s = 0.f; cnt = 0.f; cur = b;
        }
        s += ld1(&h[n * 256 + c]);
        cnt += 1.f;
    }
    atomicAdd(&sums[(size_t)cur * 256 + c], s);
    if (c == 0) atomicAdd(&cnts[cur], cnt);
}

__global__ __launch_bounds__(256)
void pool_div(float* __restrict__ sums, const float* __restrict__ cnts)
{
    const int i = blockIdx.x * 256 + threadIdx.x;   // NG*256 threads exactly
    const int g = i >> 8;
    sums[i] = sums[i] / fmaxf(cnts[g], 1.f);
}

__global__ __launch_bounds__(256)
void head_out(const float* __restrict__ y, const float* __restrict__ Wo,
              const float* __restrict__ bo, float* __restrict__ out)
{
    const int g = blockIdx.x * 256 + threadIdx.x;
    if (g >= NG) return;
    float s = bo[0];
    #pragma unroll
    for (int k = 0; k < 32; ++k) s += y[g * 32 + k] * Wo[k];
    out[g] = s;
}

__global__ __launch_bounds__(256)
void diag_fill(float* __restrict__ out, int n, float v)
{
    const int i = blockIdx.x * 256 + threadIdx.x;
    if (i < n) out[i] = v;
}

// ---------------------------------------------------------------------------
extern "C" void kernel_launch(void* const* d_in, const int* in_sizes, int n_in,
                              void* d_out, int out_size, void* d_ws, size_t ws_size,
                              hipStream_t stream)
{
    const float* x    = (const float*)d_in[0];
    const int*   ei   = (const int*)d_in[1];
    const int*   batch= (const int*)d_in[2];
    const float* ea   = (const float*)d_in[3];
    const float* We[3] = {(const float*)d_in[4],  (const float*)d_in[10], (const float*)d_in[16]};
    const float* be[3] = {(const float*)d_in[5],  (const float*)d_in[11], (const float*)d_in[17]};
    const float* Wn[3] = {(const float*)d_in[6],  (const float*)d_in[12], (const float*)d_in[18]};
    const float* bnb[3]= {(const float*)d_in[7],  (const float*)d_in[13], (const float*)d_in[19]};
    const float* gm[3] = {(const float*)d_in[8],  (const float*)d_in[14], (const float*)d_in[20]};
    const float* bt[3] = {(const float*)d_in[9],  (const float*)d_in[15], (const float*)d_in[21]};
    const float* Wd0 = (const float*)d_in[22]; const float* bd0 = (const float*)d_in[23];
    const float* Wd1 = (const float*)d_in[24]; const float* bd1 = (const float*)d_in[25];
    const float* Wd2 = (const float*)d_in[26]; const float* bd2 = (const float*)d_in[27];
    const float* Wo  = (const float*)d_in[28]; const float* bo  = (const float*)d_in[29];
    float* out = (float*)d_out;
    float* ws  = (float*)d_ws;

    // ---- workspace layout (float offsets; 16B alignment kept) ----
    constexpr size_t OFF_H    = 0;                          // NN*256 bf16
    constexpr size_t OFF_AGG  = 25600000;                   // NN*256 bf16
    constexpr size_t OFF_ST   = 51200000;                   // 512 fl
    constexpr size_t OFF_WT0  = 51200512;                   // 128*256 bf16
    constexpr size_t OFF_WT1  = OFF_WT0 + 16384;            // 256*256 bf16
    constexpr size_t OFF_WT2  = OFF_WT1 + 32768;            // 256*256 bf16
    constexpr size_t OFF_WTE0 = OFF_WT2 + 32768;            // 128*32 bf16
    constexpr size_t OFF_WTE1 = OFF_WTE0 + 2048;            // 256*32 bf16
    constexpr size_t OFF_WTE2 = OFF_WTE1 + 4096;            // 256*32 bf16
    constexpr size_t OFF_EA   = OFF_WTE2 + 4096;            // NE*16 fp32 | NE*32 bf16
    constexpr size_t OFF_SRC  = OFF_EA + 12800000;          // NE int
    constexpr size_t OFF_RP   = OFF_SRC + NE;               // NN+1 int
    constexpr size_t OFF_CUR  = OFF_RP + (NN + 1);          // NN int
    constexpr size_t OFF_PERM = OFF_CUR + NN;               // NE int
    constexpr size_t OFF_BSUM = OFF_PERM + NE;              // SCAN_NBLK int
    constexpr size_t BASE_END = OFF_BSUM + SCAN_NBLK;
    constexpr size_t OFF_EMSG = (BASE_END + 3) & ~(size_t)3;  // NE*256 bf16
    constexpr size_t NEED_BASE = BASE_END * 4;
    constexpr size_t NEED_FULL = (OFF_EMSG + (size_t)NE * 128) * 4;

    bf16*  H        = (bf16*)(ws + OFF_H);
    bf16*  AGG      = (bf16*)(ws + OFF_AGG);
    float* st       = ws + OFF_ST;
    bf16*  wt0      = (bf16*)(ws + OFF_WT0);
    bf16*  wt1      = (bf16*)(ws + OFF_WT1);
    bf16*  wt2      = (bf16*)(ws + OFF_WT2);
    bf16*  wte[3]   = {(bf16*)(ws + OFF_WTE0), (bf16*)(ws + OFF_WTE1), (bf16*)(ws + OFF_WTE2)};
    float* ea_perm  = ws + OFF_EA;              // fallback layout (fp32)
    bf16*  ea_bf    = (bf16*)(ws + OFF_EA);     // full layout (bf16 padded)
    int*   src_perm = (int*)(ws + OFF_SRC);
    int*   row_ptr  = (int*)(ws + OFF_RP);
    int*   cursor   = (int*)(ws + OFF_CUR);
    int*   perm     = (int*)(ws + OFF_PERM);
    int*   bsum     = (int*)(ws + OFF_BSUM);
    bf16*  emsg     = (bf16*)(ws + OFF_EMSG);

    if (ws_size < NEED_BASE) {
        diag_fill<<<(NG + 255) / 256, 256, 0, stream>>>(out, NG, (float)(ws_size >> 20));
        return;
    }
    const bool full = (ws_size >= NEED_FULL);

    // ---- one-time prep: CSR build, edge pre-gather, weight transpose ----
    hipMemsetAsync(row_ptr, 0, (size_t)(NN + 1) * 4, stream);
    k_hist<<<1024, 256, 0, stream>>>(ei, row_ptr);
    k_scan_block<<<SCAN_NBLK, 256, 0, stream>>>(row_ptr, bsum);
    k_scan_top<<<1, 256, 0, stream>>>(bsum, SCAN_NBLK);
    k_scan_emit<<<SCAN_NBLK, 256, 0, stream>>>(row_ptr, bsum, row_ptr, cursor);
    k_scatter<<<1024, 256, 0, stream>>>(ei, cursor, perm);
    if (full) {
        k_gather_edges_bf<<<(NE * 16 + 255) / 256, 256, 0, stream>>>(ei, ea, perm, src_perm, ea_bf);
        k_wte<<<(128 * 32 + 255) / 256, 256, 0, stream>>>(We[0], wte[0], 128);
        k_wte<<<(256 * 32 + 255) / 256, 256, 0, stream>>>(We[1], wte[1], 256);
        k_wte<<<(256 * 32 + 255) / 256, 256, 0, stream>>>(We[2], wte[2], 256);
    } else {
        k_gather_edges<<<(NE * ED + 255) / 256, 256, 0, stream>>>(ei, ea, perm, src_perm, ea_perm);
    }
    k_wt<<<(128 * 256 + 255) / 256, 256, 0, stream>>>(Wn[0], wt0, 128, 256);
    k_wt<<<(256 * 256 + 255) / 256, 256, 0, stream>>>(Wn[1], wt1, 256, 256);
    k_wt<<<(256 * 256 + 255) / 256, 256, 0, stream>>>(Wn[2], wt2, 256, 256);

    const dim3 mfma_grid(2, (NN + 127) / 128);    // conv GEMMs: N=256
    const dim3 emsg_grid128(1, NE / 128);         // emsg GEMM layer0: N=128
    const dim3 emsg_grid256(2, NE / 128);         // emsg GEMM layers1-2: N=256
    const int  agg2_grid = (NN * 2) / 4;          // node_agg2: 2 waves/node
    const int  agg3_grid128 = NN / 4;             // node_agg3 CIN=128: 1 wave/node
    const int  agg3_grid256 = (NN * 2) / 4;       // node_agg3 CIN=256: 2 waves/node

    // ---- layer 0 (cin=128 -> 256), input x fp32 ----
    if (full) {
        gemm_mfma<32, 128, false><<<emsg_grid128, 256, 0, stream>>>(ea_bf, wte[0], be[0], emsg, NE);
        node_agg3<float, 128><<<agg3_grid128, 256, 0, stream>>>(x, emsg, src_perm, row_ptr, AGG);
    } else {
        node_agg2<float, 128><<<agg2_grid, 256, 0, stream>>>(x, ea_perm, src_perm, row_ptr, We[0], be[0], AGG);
    }
    gemm_mfma<128, 256, true><<<mfma_grid, 256, 0, stream>>>(AGG, wt0, bnb[0], H, NN);
    hipMemsetAsync(st, 0, 512 * 4, stream);
    bn_stats<bf16><<<(NN + 127) / 128, 256, 0, stream>>>(H, st, NN);
    bn_norm<bf16><<<2048, 256, 0, stream>>>(H, st, gm[0], bt[0], NN * 256 / 4);

    // ---- layers 1,2 (256 -> 256), input H bf16 ----
    for (int l = 1; l < 3; ++l) {
        if (full) {
            gemm_mfma<32, 256, false><<<emsg_grid256, 256, 0, stream>>>(ea_bf, wte[l], be[l], emsg, NE);
            node_agg3<bf16, 256><<<agg3_grid256, 256, 0, stream>>>(H, emsg, src_perm, row_ptr, AGG);
        } else {
            node_agg2<bf16, 256><<<agg2_grid, 256, 0, stream>>>(H, ea_perm, src_perm, row_ptr, We[l], be[l], AGG);
        }
        gemm_mfma<256, 256, true><<<mfma_grid, 256, 0, stream>>>(AGG, (l == 1) ? wt1 : wt2, bnb[l], H, NN);
        hipMemsetAsync(st, 0, 512 * 4, stream);
        bn_stats<bf16><<<(NN + 127) / 128, 256, 0, stream>>>(H, st, NN);
        bn_norm<bf16><<<2048, 256, 0, stream>>>(H, st, gm[l], bt[l], NN * 256 / 4);
    }

    // ---- head scratch overlays AGG (dead after last conv GEMM) ----
    float* poolb = (float*)AGG;           // NG*256 = 1,024,000 fl
    float* cnts  = poolb + 1024000;       // NG
    float* y1    = poolb + 1028000;       // NG*512
    float* y2    = poolb + 3076000;       // NG*128
    float* y3    = poolb + 3588000;       // NG*32

    hipMemsetAsync(poolb, 0, (size_t)NG * 256 * 4, stream);
    hipMemsetAsync(cnts, 0, (size_t)NG * 4, stream);
    pool_sum<bf16><<<(NN + 127) / 128, 256, 0, stream>>>(H, batch, poolb, cnts);
    pool_div<<<NG, 256, 0, stream>>>(poolb, cnts);

    // ---- dense head (fp32) ----
    gemm_rk<true, float, float><<<dim3(8, (NG + 63) / 64), 256, 0, stream>>>(poolb, Wd0, bd0, y1, NG, 512, 256);
    gemm_rk<true, float, float><<<dim3(2, (NG + 63) / 64), 256, 0, stream>>>(y1, Wd1, bd1, y2, NG, 128, 512);
    gemm_rk<true, float, float><<<dim3(1, (NG + 63) / 64), 256, 0, stream>>>(y2, Wd2, bd2, y3, NG, 32, 128);
    head_out<<<(NG + 255) / 256, 256, 0, stream>>>(y3, Wo, bo, out);
}

// Round 3
// 1842.770 us; speedup vs baseline: 1.2045x; 1.2045x over previous
//
#include <hip/hip_runtime.h>
#include <hip/hip_bf16.h>

using bf16 = __hip_bfloat16;
typedef __attribute__((ext_vector_type(8))) short bf16x8;   // 8 bf16 (4 VGPRs)
typedef __attribute__((ext_vector_type(4))) float f32x4;    // MFMA accumulator

constexpr int NN = 200000;   // nodes
constexpr int NE = 800000;   // edges
constexpr int NG = 4000;     // graphs
constexpr int ED = 16;       // edge feature dim
constexpr float BN_EPS = 1e-5f;

constexpr int NCHUNK = 8;            // emsg chunks (weight-balanced)
constexpr int CAP_E  = 140032;       // max edges/chunk buffer (1094*128 exact)
constexpr int EMSG_GY = CAP_E / 128; // 1094 grid rows for emsg gemm

// ---------------- storage-type helpers (fp32 or bf16 node features) --------
__device__ __forceinline__ float  ld1(const float* p) { return *p; }
__device__ __forceinline__ float  ld1(const bf16*  p) { return __bfloat162float(*p); }
__device__ __forceinline__ float2 ld2f(const float* p) { return *(const float2*)p; }
__device__ __forceinline__ float2 ld2f(const bf16*  p) {
    union { ushort2 u; bf16 h[2]; } t;
    t.u = *(const ushort2*)p;
    return make_float2(__bfloat162float(t.h[0]), __bfloat162float(t.h[1]));
}
__device__ __forceinline__ float4 ld4(const float* p) { return *(const float4*)p; }
__device__ __forceinline__ float4 ld4(const bf16*  p) {
    union { ushort4 u; bf16 h[4]; } t;
    t.u = *(const ushort4*)p;
    return make_float4(__bfloat162float(t.h[0]), __bfloat162float(t.h[1]),
                       __bfloat162float(t.h[2]), __bfloat162float(t.h[3]));
}
__device__ __forceinline__ void st1(float* p, float v) { *p = v; }
__device__ __forceinline__ void st1(bf16*  p, float v) { *p = __float2bfloat16(v); }
__device__ __forceinline__ void st4(float* p, float4 v) { *(float4*)p = v; }
__device__ __forceinline__ void st4(bf16*  p, float4 v) {
    union { ushort4 u; bf16 h[4]; } t;
    t.h[0] = __float2bfloat16(v.x); t.h[1] = __float2bfloat16(v.y);
    t.h[2] = __float2bfloat16(v.z); t.h[3] = __float2bfloat16(v.w);
    *(ushort4*)p = t.u;
}
__device__ __forceinline__ float bfraw(unsigned short u) {
    union { unsigned short s; bf16 h; } t; t.s = u;
    return __bfloat162float(t.h);
}

// ===========================================================================
// CSR-by-dst build (once per call; reused by all 3 conv layers)
// ===========================================================================
constexpr int SCAN_CHUNK = 1024;
constexpr int SCAN_NBLK  = (NN + SCAN_CHUNK - 1) / SCAN_CHUNK;   // 196

__global__ __launch_bounds__(256)
void k_hist(const int* __restrict__ ei, int* __restrict__ cnt)
{
    int e = blockIdx.x * 256 + threadIdx.x;
    const int stride = gridDim.x * 256;
    for (; e < NE; e += stride) atomicAdd(&cnt[ei[NE + e]], 1);
}

__global__ __launch_bounds__(256)
void k_scan_block(const int* __restrict__ cnt, int* __restrict__ bsum)
{
    __shared__ int red[256];
    const int b = blockIdx.x, t = threadIdx.x;
    const int base = b * SCAN_CHUNK + t * 4;
    int s = 0;
    #pragma unroll
    for (int k = 0; k < 4; ++k) { const int i = base + k; if (i < NN) s += cnt[i]; }
    red[t] = s; __syncthreads();
    for (int off = 128; off > 0; off >>= 1) {
        if (t < off) red[t] += red[t + off];
        __syncthreads();
    }
    if (t == 0) bsum[b] = red[0];
}

__global__ __launch_bounds__(256)
void k_scan_top(int* __restrict__ bsum, int n)
{
    __shared__ int sh[256];
    const int t = threadIdx.x;
    const int orig = (t < n) ? bsum[t] : 0;
    sh[t] = orig; __syncthreads();
    for (int off = 1; off < 256; off <<= 1) {
        const int v = (t >= off) ? sh[t - off] : 0;
        __syncthreads();
        sh[t] += v;
        __syncthreads();
    }
    if (t < n) bsum[t] = sh[t] - orig;   // exclusive
}

__global__ __launch_bounds__(256)
void k_scan_emit(const int* __restrict__ cnt, const int* __restrict__ bsum,
                 int* __restrict__ row_ptr, int* __restrict__ cursor)
{
    __shared__ int sh[256];
    const int b = blockIdx.x, t = threadIdx.x;
    const int base = b * SCAN_CHUNK + t * 4;
    int c[4]; int s = 0;
    #pragma unroll
    for (int k = 0; k < 4; ++k) {
        const int i = base + k;
        c[k] = (i < NN) ? cnt[i] : 0;    // read BEFORE aliased write below
        s += c[k];
    }
    const int orig = s;
    sh[t] = s; __syncthreads();
    for (int off = 1; off < 256; off <<= 1) {
        const int v = (t >= off) ? sh[t - off] : 0;
        __syncthreads();
        sh[t] += v;
        __syncthreads();
    }
    int run = bsum[b] + sh[t] - orig;     // exclusive prefix of this thread
    #pragma unroll
    for (int k = 0; k < 4; ++k) {
        const int i = base + k;
        if (i < NN) { row_ptr[i] = run; cursor[i] = run; run += c[k]; }
    }
    if (b == 0 && t == 0) row_ptr[NN] = NE;
}

__global__ __launch_bounds__(256)
void k_scatter(const int* __restrict__ ei, int* __restrict__ cursor,
               int* __restrict__ perm)
{
    int e = blockIdx.x * 256 + threadIdx.x;
    const int stride = gridDim.x * 256;
    for (; e < NE; e += stride) {
        const int d = ei[NE + e];
        const int p = atomicAdd(&cursor[d], 1);
        perm[p] = e;
    }
}

// Weight-balanced chunk boundaries: W(n) = row_ptr[n] + 4n; chunk c covers
// nodes [cb[c], cb[c+1]).  Guarantees nodes/chunk <= 50000; edges/chunk
// ~100k for this input's ~Poisson(4) degrees (hard-clamped to CAP_E in
// consumers as insurance).
__global__ __launch_bounds__(64)
void k_bounds(const int* __restrict__ row_ptr, int* __restrict__ cb,
              int* __restrict__ eb)
{
    const int t = threadIdx.x;
    if (t > NCHUNK) return;
    const long long target = (long long)t * (NE + 4LL * NN) / NCHUNK;
    int lo = 0, hi = NN;
    while (lo < hi) {
        const int mid = (lo + hi) >> 1;
        const long long W = (long long)row_ptr[mid] + 4LL * mid;
        if (W >= target) hi = mid; else lo = mid + 1;
    }
    cb[t] = lo;
    eb[t] = row_ptr[lo];
}

// Pre-gather edge metadata into perm order (fallback path: fp32 [NE,16]).
__global__ __launch_bounds__(256)
void k_gather_edges(const int* __restrict__ ei, const float* __restrict__ ea,
                    const int* __restrict__ perm, int* __restrict__ src_perm,
                    float* __restrict__ ea_perm)
{
    const int t = blockIdx.x * 256 + threadIdx.x;    // over NE*16
    if (t >= NE * ED) return;
    const int idx = t >> 4, k = t & 15;
    const int e = perm[idx];
    ea_perm[t] = ea[(size_t)e * ED + k];
    if (k == 0) src_perm[idx] = ei[e];
}

// Full path: edge features as bf16 [NE,32], zero-padded K 16->32 (MFMA K=32).
__global__ __launch_bounds__(256)
void k_gather_edges_bf(const int* __restrict__ ei, const float* __restrict__ ea,
                       const int* __restrict__ perm, int* __restrict__ src_perm,
                       bf16* __restrict__ ea_bf)
{
    const int t = blockIdx.x * 256 + threadIdx.x;    // over NE*16 (2 bf16 each)
    if (t >= NE * 16) return;
    const int idx = t >> 4, k2 = (t & 15) * 2;       // k2 in 0..30
    const int e = perm[idx];
    union { ushort2 u; bf16 h[2]; } o;
    if (k2 < ED) {
        const float2 v = *(const float2*)&ea[(size_t)e * ED + k2];
        o.h[0] = __float2bfloat16(v.x);
        o.h[1] = __float2bfloat16(v.y);
    } else {
        o.u = make_ushort2(0, 0);
    }
    *(ushort2*)&ea_bf[(size_t)idx * 32 + k2] = o.u;
    if ((t & 15) == 0) src_perm[idx] = ei[e];
}

// One-shot: W[K,N] fp32 -> Wt[N,K] bf16 (transposed for the MFMA GEMM).
__global__ __launch_bounds__(256)
void k_wt(const float* __restrict__ W, bf16* __restrict__ Wt, int K, int N)
{
    const int i = blockIdx.x * 256 + threadIdx.x;
    if (i >= K * N) return;
    const int k = i / N, n = i % N;
    Wt[(size_t)n * K + k] = __float2bfloat16(W[i]);
}

// One-shot: We[16,cin] fp32 -> Wte[cin,32] bf16, K zero-padded 16->32.
__global__ __launch_bounds__(256)
void k_wte(const float* __restrict__ We, bf16* __restrict__ Wte, int cin)
{
    const int i = blockIdx.x * 256 + threadIdx.x;    // over cin*32
    if (i >= cin * 32) return;
    const int n = i >> 5, k = i & 31;
    Wte[i] = __float2bfloat16((k < ED) ? We[k * cin + n] : 0.f);
}

// BN fold coefficients: A = g*rsqrt(var+eps), B = beta - mu*A.
// st layout: [0..255]=sum, [256..511]=sumsq, [512..767]=A, [768..1023]=B.
__global__ __launch_bounds__(256)
void k_bnab(float* __restrict__ st, const float* __restrict__ g,
            const float* __restrict__ b)
{
    const int c = threadIdx.x;
    const float inv = 1.f / (float)NN;
    const float mu  = st[c] * inv;
    const float var = st[256 + c] * inv - mu * mu;
    const float A   = g[c] * rsqrtf(var + BN_EPS);
    st[512 + c] = A;
    st[768 + c] = b[c] - mu * A;
}

// ===========================================================================
// Fallback per-node aggregation (node_agg2 + optional BN fold on inputs).
// ===========================================================================
template<typename XT, int CIN, bool FOLD>
__global__ __launch_bounds__(256)
void node_agg2(const XT* __restrict__ x, const float* __restrict__ ea_perm,
               const int* __restrict__ src_perm, const int* __restrict__ row_ptr,
               const float* __restrict__ We, const float* __restrict__ be,
               const float* __restrict__ st, bf16* __restrict__ agg)
{
    constexpr int HALF = CIN / 2;     // channels per wave
    constexpr int CPL  = HALF / 64;   // channels per lane (1 or 2)
    const int lane = threadIdx.x & 63;
    const int gw   = blockIdx.x * 4 + (threadIdx.x >> 6);
    const int node = gw >> 1;
    const int half = gw & 1;
    if (node >= NN) return;
    const int c0 = half * HALF + lane * CPL;

    float wcol[16 * CPL];
    #pragma unroll
    for (int k = 0; k < ED; ++k)
        #pragma unroll
        for (int q = 0; q < CPL; ++q)
            wcol[k * CPL + q] = We[k * CIN + c0 + q];
    float bv[CPL];
    #pragma unroll
    for (int q = 0; q < CPL; ++q) bv[q] = be[c0 + q];

    float Af[CPL], Bf[CPL];
    #pragma unroll
    for (int q = 0; q < CPL; ++q) {
        Af[q] = FOLD ? st[512 + c0 + q] : 1.f;
        Bf[q] = FOLD ? st[768 + c0 + q] : 0.f;
    }

    float acc[CPL];
    if (CPL == 2) {
        const float2 v = ld2f(&x[(size_t)node * CIN + c0]);
        acc[0] = FOLD ? fmaf(v.x, Af[0], Bf[0]) : v.x;
        acc[CPL - 1] = FOLD ? fmaf(v.y, Af[CPL - 1], Bf[CPL - 1]) : v.y;
    } else {
        const float v = ld1(&x[(size_t)node * CIN + c0]);
        acc[0] = FOLD ? fmaf(v, Af[0], Bf[0]) : v;
    }

    const int e0 = row_ptr[node], e1 = row_ptr[node + 1];
    for (int base = e0; base < e1; base += 4) {
        int ss[4];
        #pragma unroll
        for (int j = 0; j < 4; ++j) {
            int idx = base + j; if (idx >= e1) idx = e1 - 1;
            ss[j] = src_perm[idx];
        }
        float xv0[4], xv1[4];
        #pragma unroll
        for (int j = 0; j < 4; ++j) {
            if (CPL == 2) {
                const float2 v = ld2f(&x[(size_t)ss[j] * CIN + c0]);
                xv0[j] = FOLD ? fmaf(v.x, Af[0], Bf[0]) : v.x;
                xv1[j] = FOLD ? fmaf(v.y, Af[CPL - 1], Bf[CPL - 1]) : v.y;
            } else {
                const float v = ld1(&x[(size_t)ss[j] * CIN + c0]);
                xv0[j] = FOLD ? fmaf(v, Af[0], Bf[0]) : v;
            }
        }
        #pragma unroll
        for (int j = 0; j < 4; ++j) {
            if (base + j < e1) {
                const float* ep = ea_perm + (size_t)(base + j) * ED;
                float ev[ED];
                *(float4*)&ev[0]  = *(const float4*)(ep + 0);
                *(float4*)&ev[4]  = *(const float4*)(ep + 4);
                *(float4*)&ev[8]  = *(const float4*)(ep + 8);
                *(float4*)&ev[12] = *(const float4*)(ep + 12);
                float m[CPL];
                #pragma unroll
                for (int q = 0; q < CPL; ++q) m[q] = bv[q];
                #pragma unroll
                for (int k = 0; k < ED; ++k)
                    #pragma unroll
                    for (int q = 0; q < CPL; ++q)
                        m[q] = fmaf(ev[k], wcol[k * CPL + q], m[q]);
                m[0] += xv0[j];
                if (CPL == 2) m[CPL - 1] += xv1[j];
                #pragma unroll
                for (int q = 0; q < CPL; ++q) acc[q] += fmaxf(m[q], 0.f);
            }
        }
    }

    if (CPL == 2) {
        union { ushort2 u; bf16 h[2]; } t;
        t.h[0] = __float2bfloat16(acc[0]);
        t.h[1] = __float2bfloat16(acc[CPL - 1]);
        *(ushort2*)&agg[(size_t)node * CIN + c0] = t.u;
    } else {
        st1(&agg[(size_t)node * CIN + c0], acc[0]);
    }
}

// ===========================================================================
// Chunked edge-MLP GEMM: emsg[e_local, CIN] = ea_bf[e0+e_local] @ Wte + be
// for edges [eb[c], eb[c+1]).  K=32 (single step), 128x128 tile, 4 waves.
// All writes hard-clamped to the CAP_E-row buffer.
// ===========================================================================
template<int CIN>
__global__ __launch_bounds__(256)
void emsg_gemm(const bf16* __restrict__ Abase, const bf16* __restrict__ Wt,
               const float* __restrict__ bias, bf16* __restrict__ Cl,
               const int* __restrict__ eb, int c)
{
    constexpr int LDT = 40;
    __shared__ short As[128 * LDT];
    __shared__ short Bs[128 * LDT];
    const int e0 = eb[c], e1 = eb[c + 1];
    int Mc = e1 - e0;
    if (Mc > CAP_E) Mc = CAP_E;           // insurance: never write past buffer
    const int bm = blockIdx.y * 128;
    if (bm >= Mc) return;
    const int bn   = blockIdx.x * 128;
    const int tid  = threadIdx.x;
    const int lane = tid & 63;
    const int wave = tid >> 6;
    const int wr   = (wave >> 1) * 64;
    const int wc   = (wave & 1) * 64;
    const int l15  = lane & 15;
    const int quad = lane >> 4;

    // stage: 128 rows x 32 K (bf16) for A (edges) and Wt (cols)
    #pragma unroll
    for (int c2 = tid; c2 < 512; c2 += 256) {
        const int row = c2 >> 2, part = c2 & 3;
        int ar = bm + row; if (ar >= Mc) ar = Mc - 1;
        *(ulonglong2*)&As[row * LDT + part * 8] =
            *(const ulonglong2*)&Abase[(size_t)(e0 + ar) * 32 + part * 8];
        *(ulonglong2*)&Bs[row * LDT + part * 8] =
            *(const ulonglong2*)&Wt[(size_t)(bn + row) * 32 + part * 8];
    }
    __syncthreads();

    f32x4 acc[4][4];
    #pragma unroll
    for (int i = 0; i < 4; ++i)
        #pragma unroll
        for (int j = 0; j < 4; ++j)
            acc[i][j] = (f32x4){0.f, 0.f, 0.f, 0.f};

    bf16x8 af[4], bfr[4];
    #pragma unroll
    for (int i = 0; i < 4; ++i) {
        af[i]  = *(const bf16x8*)&As[(wr + i * 16 + l15) * LDT + quad * 8];
        bfr[i] = *(const bf16x8*)&Bs[(wc + i * 16 + l15) * LDT + quad * 8];
    }
    #pragma unroll
    for (int mi = 0; mi < 4; ++mi)
        #pragma unroll
        for (int ni = 0; ni < 4; ++ni)
            acc[mi][ni] = __builtin_amdgcn_mfma_f32_16x16x32_bf16(
                              af[mi], bfr[ni], acc[mi][ni], 0, 0, 0);

    float bv[4];
    #pragma unroll
    for (int ni = 0; ni < 4; ++ni)
        bv[ni] = bias[bn + wc + ni * 16 + l15];
    #pragma unroll
    for (int mi = 0; mi < 4; ++mi) {
        const int lr0 = bm + wr + mi * 16 + quad * 4;
        #pragma unroll
        for (int r = 0; r < 4; ++r) {
            const int lr = lr0 + r;
            if (lr < Mc) {
                #pragma unroll
                for (int ni = 0; ni < 4; ++ni) {
                    const float v = acc[mi][ni][r] + bv[ni];
                    Cl[(size_t)lr * CIN + bn + wc + ni * 16 + l15] =
                        __float2bfloat16(v);
                }
            }
        }
    }
}

// ===========================================================================
// Chunked streaming aggregation: for nodes [cb[c], cb[c+1]):
//   agg[n] = fold(x[n]) + sum_e relu(fold(x[src_e]) + emsg_local[e])
// Wave = 128 channels (2 bf16/lane); WPN = CIN/128 waves per node.
// emsg reads hard-clamped to the CAP_E-row buffer.
// ===========================================================================
template<typename XT, int CIN, bool FOLD>
__global__ __launch_bounds__(256)
void node_agg3(const XT* __restrict__ x, const bf16* __restrict__ emsg,
               const int* __restrict__ src_perm, const int* __restrict__ row_ptr,
               const float* __restrict__ st, const int* __restrict__ cb,
               const int* __restrict__ eb, int c, bf16* __restrict__ agg)
{
    constexpr int WPN = CIN / 128;
    const int lane = threadIdx.x & 63;
    int gw = blockIdx.x * 4 + (threadIdx.x >> 6);
    gw = __builtin_amdgcn_readfirstlane(gw);
    const int nl   = gw / WPN;
    const int half = gw - nl * WPN;
    const int node = cb[c] + nl;
    if (node >= cb[c + 1]) return;
    const int c0 = half * 128 + lane * 2;

    float A0 = 1.f, A1 = 1.f, B0 = 0.f, B1 = 0.f;
    if (FOLD) {
        A0 = st[512 + c0]; A1 = st[512 + c0 + 1];
        B0 = st[768 + c0]; B1 = st[768 + c0 + 1];
    }

    const float2 a0 = ld2f(&x[(size_t)node * CIN + c0]);
    float acc0 = FOLD ? fmaf(a0.x, A0, B0) : a0.x;
    float acc1 = FOLD ? fmaf(a0.y, A1, B1) : a0.y;

    const int e0 = row_ptr[node], e1 = row_ptr[node + 1];
    const int eb0 = eb[c];
    for (int base = e0; base < e1; base += 8) {
        int ss[8];
        #pragma unroll
        for (int j = 0; j < 8; ++j) {
            int idx = base + j; if (idx >= e1) idx = e1 - 1;
            ss[j] = src_perm[idx];
        }
        float2 xv[8]; ushort2 mv[8];
        #pragma unroll
        for (int j = 0; j < 8; ++j) {
            int idx = base + j; if (idx >= e1) idx = e1 - 1;
            int li = idx - eb0; if (li >= CAP_E) li = CAP_E - 1;   // insurance
            xv[j] = ld2f(&x[(size_t)ss[j] * CIN + c0]);
            mv[j] = *(const ushort2*)&emsg[(size_t)li * CIN + c0];
        }
        #pragma unroll
        for (int j = 0; j < 8; ++j) {
            if (base + j < e1) {
                const float v0 = FOLD ? fmaf(xv[j].x, A0, B0) : xv[j].x;
                const float v1 = FOLD ? fmaf(xv[j].y, A1, B1) : xv[j].y;
                acc0 += fmaxf(v0 + bfraw(mv[j].x), 0.f);
                acc1 += fmaxf(v1 + bfraw(mv[j].y), 0.f);
            }
        }
    }

    union { ushort2 u; bf16 h[2]; } t;
    t.h[0] = __float2bfloat16(acc0);
    t.h[1] = __float2bfloat16(acc1);
    *(ushort2*)&agg[(size_t)node * CIN + c0] = t.u;
}

// ===========================================================================
// Conv MFMA GEMM: C[M,256] = relu(A[M,K] @ Wt[256,K]^T + bias), bf16 out.
// STATS: also accumulate per-channel sum/sumsq of the post-relu output
// into st[0..255]/st[256..511] (quad-reduce + atomics).
// ===========================================================================
template<int K, bool STATS>
__global__ __launch_bounds__(256)
void gemm_mfma(const bf16* __restrict__ A, const bf16* __restrict__ Wt,
               const float* __restrict__ bias, bf16* __restrict__ C, int M,
               float* __restrict__ st)
{
    constexpr int LDT = 40;                 // padded LDS row stride (bf16)
    __shared__ short As[128 * LDT];
    __shared__ short Bs[128 * LDT];
    const int tid  = threadIdx.x;
    const int bm   = blockIdx.y * 128;
    const int bn   = blockIdx.x * 128;      // 0 or 128 (N = 256)
    const int lane = tid & 63;
    const int wave = tid >> 6;
    const int wr   = (wave >> 1) * 64;
    const int wc   = (wave & 1) * 64;
    const int l15  = lane & 15;
    const int quad = lane >> 4;

    f32x4 acc[4][4];
    #pragma unroll
    for (int i = 0; i < 4; ++i)
        #pragma unroll
        for (int j = 0; j < 4; ++j)
            acc[i][j] = (f32x4){0.f, 0.f, 0.f, 0.f};

    for (int k0 = 0; k0 < K; k0 += 32) {
        #pragma unroll
        for (int c = tid; c < 512; c += 256) {
            const int row = c >> 2, part = c & 3;
            int ar = bm + row; if (ar >= M) ar = M - 1;
            *(ulonglong2*)&As[row * LDT + part * 8] =
                *(const ulonglong2*)&A[(size_t)ar * K + k0 + part * 8];
            *(ulonglong2*)&Bs[row * LDT + part * 8] =
                *(const ulonglong2*)&Wt[(size_t)(bn + row) * K + k0 + part * 8];
        }
        __syncthreads();

        bf16x8 af[4], bfr[4];
        #pragma unroll
        for (int i = 0; i < 4; ++i) {
            af[i]  = *(const bf16x8*)&As[(wr + i * 16 + l15) * LDT + quad * 8];
            bfr[i] = *(const bf16x8*)&Bs[(wc + i * 16 + l15) * LDT + quad * 8];
        }
        #pragma unroll
        for (int mi = 0; mi < 4; ++mi)
            #pragma unroll
            for (int ni = 0; ni < 4; ++ni)
                acc[mi][ni] = __builtin_amdgcn_mfma_f32_16x16x32_bf16(
                                  af[mi], bfr[ni], acc[mi][ni], 0, 0, 0);
        __syncthreads();
    }

    float bv[4];
    #pragma unroll
    for (int ni = 0; ni < 4; ++ni)
        bv[ni] = bias[bn + wc + ni * 16 + l15];
    float ps[4]  = {0.f, 0.f, 0.f, 0.f};
    float ps2[4] = {0.f, 0.f, 0.f, 0.f};
    #pragma unroll
    for (int mi = 0; mi < 4; ++mi) {
        const int row0 = bm + wr + mi * 16 + quad * 4;
        #pragma unroll
        for (int r = 0; r < 4; ++r) {
            const int row = row0 + r;
            if (row < M) {
                #pragma unroll
                for (int ni = 0; ni < 4; ++ni) {
                    float v = acc[mi][ni][r] + bv[ni];
                    v = fmaxf(v, 0.f);
                    C[(size_t)row * 256 + bn + wc + ni * 16 + l15] = __float2bfloat16(v);
                    if (STATS) { ps[ni] += v; ps2[ni] = fmaf(v, v, ps2[ni]); }
                }
            }
        }
    }
    if (STATS) {
        #pragma unroll
        for (int ni = 0; ni < 4; ++ni) {
            float s = ps[ni], q = ps2[ni];
            s += __shfl_xor(s, 16); s += __shfl_xor(s, 32);
            q += __shfl_xor(q, 16); q += __shfl_xor(q, 32);
            if (quad == 0) {
                const int col = bn + wc + ni * 16 + l15;
                atomicAdd(&st[col], s);
                atomicAdd(&st[256 + col], q);
            }
        }
    }
}

// ---------------------------------------------------------------------------
// fp32 GEMM (dense head only): C = (relu?)(A @ W + bias)
// ---------------------------------------------------------------------------
template<bool RELU, typename InT, typename OutT>
__global__ __launch_bounds__(256)
void gemm_rk(const InT* __restrict__ A, const float* __restrict__ W,
             const float* __restrict__ bias, OutT* __restrict__ C,
             int M, int N, int K)
{
    __shared__ float Asm[16][64];
    __shared__ float Wsm[16][64];
    const int bm = blockIdx.y * 64;
    const int bn = blockIdx.x * 64;
    const int tid = threadIdx.x;
    const int tx = tid & 15, ty = tid >> 4;
    const int ar = tid >> 2, ac = (tid & 3) * 4;
    const int wrr = tid >> 4, wcc = (tid & 15) * 4;

    float acc[4][4] = {};

    for (int k0 = 0; k0 < K; k0 += 16) {
        float4 av = make_float4(0.f, 0.f, 0.f, 0.f);
        if (bm + ar < M)
            av = ld4(A + (size_t)(bm + ar) * K + k0 + ac);
        Asm[ac + 0][ar] = av.x; Asm[ac + 1][ar] = av.y;
        Asm[ac + 2][ar] = av.z; Asm[ac + 3][ar] = av.w;

        float4 wv = make_float4(0.f, 0.f, 0.f, 0.f);
        if (bn + wcc < N)
            wv = *(const float4*)(W + (size_t)(k0 + wrr) * N + bn + wcc);
        *(float4*)&Wsm[wrr][wcc] = wv;
        __syncthreads();

        #pragma unroll
        for (int k = 0; k < 16; ++k) {
            const float4 a4 = *(const float4*)&Asm[k][ty * 4];
            const float4 b4 = *(const float4*)&Wsm[k][tx * 4];
            const float aa[4] = {a4.x, a4.y, a4.z, a4.w};
            const float bb[4] = {b4.x, b4.y, b4.z, b4.w};
            #pragma unroll
            for (int i = 0; i < 4; ++i)
                #pragma unroll
                for (int j = 0; j < 4; ++j)
                    acc[i][j] += aa[i] * bb[j];
        }
        __syncthreads();
    }

    float bvals[4];
    #pragma unroll
    for (int j = 0; j < 4; ++j) {
        const int col = bn + tx * 4 + j;
        bvals[j] = (col < N) ? bias[col] : 0.f;
    }
    #pragma unroll
    for (int i = 0; i < 4; ++i) {
        const int row = bm + ty * 4 + i;
        if (row >= M) continue;
        float v[4];
        #pragma unroll
        for (int j = 0; j < 4; ++j) {
            v[j] = acc[i][j] + bvals[j];
            if (RELU) v[j] = fmaxf(v[j], 0.f);
        }
        if (bn + tx * 4 + 3 < N) {
            st4(C + (size_t)row * N + bn + tx * 4, make_float4(v[0], v[1], v[2], v[3]));
        } else {
            #pragma unroll
            for (int j = 0; j < 4; ++j) {
                const int col = bn + tx * 4 + j;
                if (col < N) st1(C + (size_t)row * N + col, v[j]);
            }
        }
    }
}

// ---------------------------------------------------------------------------
// Mean-pool over sorted batch ids, with BN fold applied on the fly.
// ---------------------------------------------------------------------------
template<typename InT, bool FOLD>
__global__ __launch_bounds__(256)
void pool_sum(const InT* __restrict__ h, const int* __restrict__ batch,
              const float* __restrict__ st,
              float* __restrict__ sums, float* __restrict__ cnts)
{
    const int c = threadIdx.x;
    size_t n0 = (size_t)blockIdx.x * 128;
    size_t n1 = n0 + 128; if (n1 > (size_t)NN) n1 = NN;
    if (n0 >= (size_t)NN) return;
    const float A = FOLD ? st[512 + c] : 1.f;
    const float B = FOLD ? st[768 + c] : 0.f;
    int cur = batch[n0];
    float s = 0.f, cnt = 0.f;
    for (size_t n = n0; n < n1; ++n) {
        const int b = batch[n];
        if (b != cur) {
            atomicAdd(&sums[(size_t)cur * 256 + c], s);
            if (c == 0) atomicAdd(&cnts[cur], cnt);
            s = 0.f; cnt = 0.f; cur = b;
        }
        const float v = ld1(&h[n * 256 + c]);
        s += FOLD ? fmaf(v, A, B) : v;
        cnt += 1.f;
    }
    atomicAdd(&sums[(size_t)cur * 256 + c], s);
    if (c == 0) atomicAdd(&cnts[cur], cnt);
}

__global__ __launch_bounds__(256)
void pool_div(float* __restrict__ sums, const float* __restrict__ cnts)
{
    const int i = blockIdx.x * 256 + threadIdx.x;   // NG*256 threads exactly
    const int g = i >> 8;
    sums[i] = sums[i] / fmaxf(cnts[g], 1.f);
}

__global__ __launch_bounds__(256)
void head_out(const float* __restrict__ y, const float* __restrict__ Wo,
              const float* __restrict__ bo, float* __restrict__ out)
{
    const int g = blockIdx.x * 256 + threadIdx.x;
    if (g >= NG) return;
    float s = bo[0];
    #pragma unroll
    for (int k = 0; k < 32; ++k) s += y[g * 32 + k] * Wo[k];
    out[g] = s;
}

__global__ __launch_bounds__(256)
void diag_fill(float* __restrict__ out, int n, float v)
{
    const int i = blockIdx.x * 256 + threadIdx.x;
    if (i < n) out[i] = v;
}

// ---------------------------------------------------------------------------
extern "C" void kernel_launch(void* const* d_in, const int* in_sizes, int n_in,
                              void* d_out, int out_size, void* d_ws, size_t ws_size,
                              hipStream_t stream)
{
    const float* x    = (const float*)d_in[0];
    const int*   ei   = (const int*)d_in[1];
    const int*   batch= (const int*)d_in[2];
    const float* ea   = (const float*)d_in[3];
    const float* We[3] = {(const float*)d_in[4],  (const float*)d_in[10], (const float*)d_in[16]};
    const float* be[3] = {(const float*)d_in[5],  (const float*)d_in[11], (const float*)d_in[17]};
    const float* Wn[3] = {(const float*)d_in[6],  (const float*)d_in[12], (const float*)d_in[18]};
    const float* bnb[3]= {(const float*)d_in[7],  (const float*)d_in[13], (const float*)d_in[19]};
    const float* gm[3] = {(const float*)d_in[8],  (const float*)d_in[14], (const float*)d_in[20]};
    const float* bt[3] = {(const float*)d_in[9],  (const float*)d_in[15], (const float*)d_in[21]};
    const float* Wd0 = (const float*)d_in[22]; const float* bd0 = (const float*)d_in[23];
    const float* Wd1 = (const float*)d_in[24]; const float* bd1 = (const float*)d_in[25];
    const float* Wd2 = (const float*)d_in[26]; const float* bd2 = (const float*)d_in[27];
    const float* Wo  = (const float*)d_in[28]; const float* bo  = (const float*)d_in[29];
    float* out = (float*)d_out;
    float* ws  = (float*)d_ws;

    // ---- workspace layout (float offsets; 16B alignment kept) ----
    constexpr size_t OFF_H    = 0;                            // NN*256 bf16
    constexpr size_t OFF_AGG  = 25600000;                     // NN*256 bf16
    constexpr size_t OFF_ST   = 51200000;                     // 1536 fl
    constexpr size_t OFF_WT0  = OFF_ST + 1536;                // 128*256 bf16
    constexpr size_t OFF_WT1  = OFF_WT0 + 16384;              // 256*256 bf16
    constexpr size_t OFF_WT2  = OFF_WT1 + 32768;              // 256*256 bf16
    constexpr size_t OFF_WTE0 = OFF_WT2 + 32768;              // 128*32 bf16
    constexpr size_t OFF_WTE1 = OFF_WTE0 + 2048;              // 256*32 bf16
    constexpr size_t OFF_WTE2 = OFF_WTE1 + 4096;              // 256*32 bf16
    constexpr size_t OFF_EA   = OFF_WTE2 + 4096;              // NE*16 fp32 | NE*32 bf16
    constexpr size_t OFF_SRC  = OFF_EA + 12800000;            // NE int
    constexpr size_t OFF_RP   = OFF_SRC + NE;                 // NN+1 int
    constexpr size_t OFF_CUR  = OFF_RP + (NN + 1);            // NN int
    constexpr size_t OFF_PERM = OFF_CUR + NN;                 // NE int
    constexpr size_t OFF_BSUM = OFF_PERM + NE;                // SCAN_NBLK int
    constexpr size_t OFF_CB   = OFF_BSUM + SCAN_NBLK;         // NCHUNK+1 int
    constexpr size_t OFF_EB   = OFF_CB + (NCHUNK + 1);        // NCHUNK+1 int
    constexpr size_t BASE_END = OFF_EB + (NCHUNK + 1);
    constexpr size_t OFF_EMSG = (BASE_END + 3) & ~(size_t)3;  // CAP_E*256 bf16
    constexpr size_t NEED_BASE = BASE_END * 4;
    constexpr size_t NEED_MID  = (OFF_EMSG + (size_t)CAP_E * 128) * 4;

    bf16*  H        = (bf16*)(ws + OFF_H);
    bf16*  AGG      = (bf16*)(ws + OFF_AGG);
    float* st       = ws + OFF_ST;
    bf16*  wt0      = (bf16*)(ws + OFF_WT0);
    bf16*  wt1      = (bf16*)(ws + OFF_WT1);
    bf16*  wt2      = (bf16*)(ws + OFF_WT2);
    bf16*  wte[3]   = {(bf16*)(ws + OFF_WTE0), (bf16*)(ws + OFF_WTE1), (bf16*)(ws + OFF_WTE2)};
    float* ea_perm  = ws + OFF_EA;              // fallback layout (fp32)
    bf16*  ea_bf    = (bf16*)(ws + OFF_EA);     // mid-tier layout (bf16 padded)
    int*   src_perm = (int*)(ws + OFF_SRC);
    int*   row_ptr  = (int*)(ws + OFF_RP);
    int*   cursor   = (int*)(ws + OFF_CUR);
    int*   perm     = (int*)(ws + OFF_PERM);
    int*   bsum     = (int*)(ws + OFF_BSUM);
    int*   cb       = (int*)(ws + OFF_CB);
    int*   eb       = (int*)(ws + OFF_EB);
    bf16*  emsg     = (bf16*)(ws + OFF_EMSG);

    if (ws_size < NEED_BASE) {
        diag_fill<<<(NG + 255) / 256, 256, 0, stream>>>(out, NG, (float)(ws_size >> 20));
        return;
    }
    const bool full = (ws_size >= NEED_MID);

    // ---- one-time prep: CSR build, edge pre-gather, weight transpose ----
    hipMemsetAsync(row_ptr, 0, (size_t)(NN + 1) * 4, stream);
    k_hist<<<1024, 256, 0, stream>>>(ei, row_ptr);
    k_scan_block<<<SCAN_NBLK, 256, 0, stream>>>(row_ptr, bsum);
    k_scan_top<<<1, 256, 0, stream>>>(bsum, SCAN_NBLK);
    k_scan_emit<<<SCAN_NBLK, 256, 0, stream>>>(row_ptr, bsum, row_ptr, cursor);
    k_scatter<<<1024, 256, 0, stream>>>(ei, cursor, perm);
    if (full) {
        k_bounds<<<1, 64, 0, stream>>>(row_ptr, cb, eb);
        k_gather_edges_bf<<<(NE * 16 + 255) / 256, 256, 0, stream>>>(ei, ea, perm, src_perm, ea_bf);
        k_wte<<<(128 * 32 + 255) / 256, 256, 0, stream>>>(We[0], wte[0], 128);
        k_wte<<<(256 * 32 + 255) / 256, 256, 0, stream>>>(We[1], wte[1], 256);
        k_wte<<<(256 * 32 + 255) / 256, 256, 0, stream>>>(We[2], wte[2], 256);
    } else {
        k_gather_edges<<<(NE * ED + 255) / 256, 256, 0, stream>>>(ei, ea, perm, src_perm, ea_perm);
    }
    k_wt<<<(128 * 256 + 255) / 256, 256, 0, stream>>>(Wn[0], wt0, 128, 256);
    k_wt<<<(256 * 256 + 255) / 256, 256, 0, stream>>>(Wn[1], wt1, 256, 256);
    k_wt<<<(256 * 256 + 255) / 256, 256, 0, stream>>>(Wn[2], wt2, 256, 256);

    const dim3 mfma_grid(2, (NN + 127) / 128);    // conv GEMMs: N=256
    const int  agg2_grid = (NN * 2) / 4;          // fallback: 2 waves/node

    // ---- layer 0 (cin=128 -> 256), input x fp32, no fold ----
    if (full) {
        for (int c = 0; c < NCHUNK; ++c) {
            emsg_gemm<128><<<dim3(1, EMSG_GY), 256, 0, stream>>>(ea_bf, wte[0], be[0], emsg, eb, c);
            node_agg3<float, 128, false><<<12500, 256, 0, stream>>>(
                x, emsg, src_perm, row_ptr, st, cb, eb, c, AGG);
        }
    } else {
        node_agg2<float, 128, false><<<agg2_grid, 256, 0, stream>>>(
            x, ea_perm, src_perm, row_ptr, We[0], be[0], st, AGG);
    }
    hipMemsetAsync(st, 0, 512 * 4, stream);
    gemm_mfma<128, true><<<mfma_grid, 256, 0, stream>>>(AGG, wt0, bnb[0], H, NN, st);
    k_bnab<<<1, 256, 0, stream>>>(st, gm[0], bt[0]);

    // ---- layers 1,2 (256 -> 256), input H bf16 raw + fold(A,B) ----
    for (int l = 1; l < 3; ++l) {
        if (full) {
            for (int c = 0; c < NCHUNK; ++c) {
                emsg_gemm<256><<<dim3(2, EMSG_GY), 256, 0, stream>>>(ea_bf, wte[l], be[l], emsg, eb, c);
                node_agg3<bf16, 256, true><<<25000, 256, 0, stream>>>(
                    H, emsg, src_perm, row_ptr, st, cb, eb, c, AGG);
            }
        } else {
            node_agg2<bf16, 256, true><<<agg2_grid, 256, 0, stream>>>(
                H, ea_perm, src_perm, row_ptr, We[l], be[l], st, AGG);
        }
        hipMemsetAsync(st, 0, 512 * 4, stream);
        gemm_mfma<256, true><<<mfma_grid, 256, 0, stream>>>(
            AGG, (l == 1) ? wt1 : wt2, bnb[l], H, NN, st);
        k_bnab<<<1, 256, 0, stream>>>(st, gm[l], bt[l]);
    }

    // ---- head scratch overlays AGG (dead after last conv GEMM) ----
    float* poolb = (float*)AGG;           // NG*256 = 1,024,000 fl
    float* cnts  = poolb + 1024000;       // NG
    float* y1    = poolb + 1028000;       // NG*512
    float* y2    = poolb + 3076000;       // NG*128
    float* y3    = poolb + 3588000;       // NG*32

    hipMemsetAsync(poolb, 0, (size_t)NG * 256 * 4, stream);
    hipMemsetAsync(cnts, 0, (size_t)NG * 4, stream);
    pool_sum<bf16, true><<<(NN + 127) / 128, 256, 0, stream>>>(H, batch, st, poolb, cnts);
    pool_div<<<NG, 256, 0, stream>>>(poolb, cnts);

    // ---- dense head (fp32) ----
    gemm_rk<true, float, float><<<dim3(8, (NG + 63) / 64), 256, 0, stream>>>(poolb, Wd0, bd0, y1, NG, 512, 256);
    gemm_rk<true, float, float><<<dim3(2, (NG + 63) / 64), 256, 0, stream>>>(y1, Wd1, bd1, y2, NG, 128, 512);
    gemm_rk<true, float, float><<<dim3(1, (NG + 63) / 64), 256, 0, stream>>>(y2, Wd2, bd2, y3, NG, 32, 128);
    head_out<<<(NG + 255) / 256, 256, 0, stream>>>(y3, Wo, bo, out);
}

// Round 4
// 1710.797 us; speedup vs baseline: 1.2974x; 1.0771x over previous
//
#include <hip/hip_runtime.h>
#include <hip/hip_bf16.h>

using bf16 = __hip_bfloat16;
typedef __attribute__((ext_vector_type(8))) short bf16x8;   // 8 bf16 (4 VGPRs)
typedef __attribute__((ext_vector_type(4))) float f32x4;    // MFMA accumulator

constexpr int NN = 200000;   // nodes
constexpr int NE = 800000;   // edges
constexpr int NG = 4000;     // graphs
constexpr int ED = 16;       // edge feature dim
constexpr float BN_EPS = 1e-5f;

// ---------------- storage-type helpers (fp32 or bf16 node features) --------
__device__ __forceinline__ float  ld1(const float* p) { return *p; }
__device__ __forceinline__ float  ld1(const bf16*  p) { return __bfloat162float(*p); }
__device__ __forceinline__ float2 ld2f(const float* p) { return *(const float2*)p; }
__device__ __forceinline__ float2 ld2f(const bf16*  p) {
    union { ushort2 u; bf16 h[2]; } t;
    t.u = *(const ushort2*)p;
    return make_float2(__bfloat162float(t.h[0]), __bfloat162float(t.h[1]));
}
__device__ __forceinline__ float4 ld4(const float* p) { return *(const float4*)p; }
__device__ __forceinline__ float4 ld4(const bf16*  p) {
    union { ushort4 u; bf16 h[4]; } t;
    t.u = *(const ushort4*)p;
    return make_float4(__bfloat162float(t.h[0]), __bfloat162float(t.h[1]),
                       __bfloat162float(t.h[2]), __bfloat162float(t.h[3]));
}
__device__ __forceinline__ void st1(float* p, float v) { *p = v; }
__device__ __forceinline__ void st1(bf16*  p, float v) { *p = __float2bfloat16(v); }
__device__ __forceinline__ void st4(float* p, float4 v) { *(float4*)p = v; }
__device__ __forceinline__ void st4(bf16*  p, float4 v) {
    union { ushort4 u; bf16 h[4]; } t;
    t.h[0] = __float2bfloat16(v.x); t.h[1] = __float2bfloat16(v.y);
    t.h[2] = __float2bfloat16(v.z); t.h[3] = __float2bfloat16(v.w);
    *(ushort4*)p = t.u;
}
__device__ __forceinline__ float bfraw(unsigned short u) {
    union { unsigned short s; bf16 h; } t; t.s = u;
    return __bfloat162float(t.h);
}

// async global -> LDS, 16 B per lane (m97 pattern). LDS dest must be the
// wave-uniform chunk base; HW adds lane*16.
__device__ __forceinline__ void gld16(const void* g, void* l)
{
    __builtin_amdgcn_global_load_lds(
        (const __attribute__((address_space(1))) void*)g,
        (__attribute__((address_space(3))) void*)l, 16, 0, 0);
}

// ===========================================================================
// CSR-by-dst build (once per call; reused by all 3 conv layers)
// ===========================================================================
constexpr int SCAN_CHUNK = 1024;
constexpr int SCAN_NBLK  = (NN + SCAN_CHUNK - 1) / SCAN_CHUNK;   // 196

__global__ __launch_bounds__(256)
void k_hist(const int* __restrict__ ei, int* __restrict__ cnt)
{
    int e = blockIdx.x * 256 + threadIdx.x;
    const int stride = gridDim.x * 256;
    for (; e < NE; e += stride) atomicAdd(&cnt[ei[NE + e]], 1);
}

__global__ __launch_bounds__(256)
void k_scan_block(const int* __restrict__ cnt, int* __restrict__ bsum)
{
    __shared__ int red[256];
    const int b = blockIdx.x, t = threadIdx.x;
    const int base = b * SCAN_CHUNK + t * 4;
    int s = 0;
    #pragma unroll
    for (int k = 0; k < 4; ++k) { const int i = base + k; if (i < NN) s += cnt[i]; }
    red[t] = s; __syncthreads();
    for (int off = 128; off > 0; off >>= 1) {
        if (t < off) red[t] += red[t + off];
        __syncthreads();
    }
    if (t == 0) bsum[b] = red[0];
}

__global__ __launch_bounds__(256)
void k_scan_top(int* __restrict__ bsum, int n)
{
    __shared__ int sh[256];
    const int t = threadIdx.x;
    const int orig = (t < n) ? bsum[t] : 0;
    sh[t] = orig; __syncthreads();
    for (int off = 1; off < 256; off <<= 1) {
        const int v = (t >= off) ? sh[t - off] : 0;
        __syncthreads();
        sh[t] += v;
        __syncthreads();
    }
    if (t < n) bsum[t] = sh[t] - orig;   // exclusive
}

__global__ __launch_bounds__(256)
void k_scan_emit(const int* __restrict__ cnt, const int* __restrict__ bsum,
                 int* __restrict__ row_ptr, int* __restrict__ cursor)
{
    __shared__ int sh[256];
    const int b = blockIdx.x, t = threadIdx.x;
    const int base = b * SCAN_CHUNK + t * 4;
    int c[4]; int s = 0;
    #pragma unroll
    for (int k = 0; k < 4; ++k) {
        const int i = base + k;
        c[k] = (i < NN) ? cnt[i] : 0;    // read BEFORE aliased write below
        s += c[k];
    }
    const int orig = s;
    sh[t] = s; __syncthreads();
    for (int off = 1; off < 256; off <<= 1) {
        const int v = (t >= off) ? sh[t - off] : 0;
        __syncthreads();
        sh[t] += v;
        __syncthreads();
    }
    int run = bsum[b] + sh[t] - orig;     // exclusive prefix of this thread
    #pragma unroll
    for (int k = 0; k < 4; ++k) {
        const int i = base + k;
        if (i < NN) { row_ptr[i] = run; cursor[i] = run; run += c[k]; }
    }
    if (b == 0 && t == 0) row_ptr[NN] = NE;
}

__global__ __launch_bounds__(256)
void k_scatter(const int* __restrict__ ei, int* __restrict__ cursor,
               int* __restrict__ perm)
{
    int e = blockIdx.x * 256 + threadIdx.x;
    const int stride = gridDim.x * 256;
    for (; e < NE; e += stride) {
        const int d = ei[NE + e];
        const int p = atomicAdd(&cursor[d], 1);
        perm[p] = e;
    }
}

// Weight-balanced chunk boundaries: W(n) = row_ptr[n] + 4n; chunk c covers
// nodes [cb[c], cb[c+1]).  Max chunk weight = (NE+4NN)/nchunk, so
// edges/chunk <= (NE+4NN)/nchunk and nodes/chunk <= (NE+4NN)/(4*nchunk).
__global__ __launch_bounds__(64)
void k_bounds(const int* __restrict__ row_ptr, int* __restrict__ cb,
              int* __restrict__ eb, int nchunk)
{
    const int t = threadIdx.x;
    if (t > nchunk) return;
    const long long target = (long long)t * (NE + 4LL * NN) / nchunk;
    int lo = 0, hi = NN;
    while (lo < hi) {
        const int mid = (lo + hi) >> 1;
        const long long W = (long long)row_ptr[mid] + 4LL * mid;
        if (W >= target) hi = mid; else lo = mid + 1;
    }
    cb[t] = lo;
    eb[t] = row_ptr[lo];
}

// Pre-gather edge metadata into perm order (fallback path: fp32 [NE,16]).
__global__ __launch_bounds__(256)
void k_gather_edges(const int* __restrict__ ei, const float* __restrict__ ea,
                    const int* __restrict__ perm, int* __restrict__ src_perm,
                    float* __restrict__ ea_perm)
{
    const int t = blockIdx.x * 256 + threadIdx.x;    // over NE*16
    if (t >= NE * ED) return;
    const int idx = t >> 4, k = t & 15;
    const int e = perm[idx];
    ea_perm[t] = ea[(size_t)e * ED + k];
    if (k == 0) src_perm[idx] = ei[e];
}

// Full path: edge features as bf16 [NE,32], zero-padded K 16->32 (MFMA K=32).
__global__ __launch_bounds__(256)
void k_gather_edges_bf(const int* __restrict__ ei, const float* __restrict__ ea,
                       const int* __restrict__ perm, int* __restrict__ src_perm,
                       bf16* __restrict__ ea_bf)
{
    const int t = blockIdx.x * 256 + threadIdx.x;    // over NE*16 (2 bf16 each)
    if (t >= NE * 16) return;
    const int idx = t >> 4, k2 = (t & 15) * 2;       // k2 in 0..30
    const int e = perm[idx];
    union { ushort2 u; bf16 h[2]; } o;
    if (k2 < ED) {
        const float2 v = *(const float2*)&ea[(size_t)e * ED + k2];
        o.h[0] = __float2bfloat16(v.x);
        o.h[1] = __float2bfloat16(v.y);
    } else {
        o.u = make_ushort2(0, 0);
    }
    *(ushort2*)&ea_bf[(size_t)idx * 32 + k2] = o.u;
    if ((t & 15) == 0) src_perm[idx] = ei[e];
}

// One-shot: W[K,N] fp32 -> Wt[N,K] bf16 (transposed for the MFMA GEMM).
__global__ __launch_bounds__(256)
void k_wt(const float* __restrict__ W, bf16* __restrict__ Wt, int K, int N)
{
    const int i = blockIdx.x * 256 + threadIdx.x;
    if (i >= K * N) return;
    const int k = i / N, n = i % N;
    Wt[(size_t)n * K + k] = __float2bfloat16(W[i]);
}

// One-shot: We[16,cin] fp32 -> Wte[cin,32] bf16, K zero-padded 16->32.
__global__ __launch_bounds__(256)
void k_wte(const float* __restrict__ We, bf16* __restrict__ Wte, int cin)
{
    const int i = blockIdx.x * 256 + threadIdx.x;    // over cin*32
    if (i >= cin * 32) return;
    const int n = i >> 5, k = i & 31;
    Wte[i] = __float2bfloat16((k < ED) ? We[k * cin + n] : 0.f);
}

// BN fold coefficients: A = g*rsqrt(var+eps), B = beta - mu*A.
// st layout: [0..255]=sum, [256..511]=sumsq, [512..767]=A, [768..1023]=B.
__global__ __launch_bounds__(256)
void k_bnab(float* __restrict__ st, const float* __restrict__ g,
            const float* __restrict__ b)
{
    const int c = threadIdx.x;
    const float inv = 1.f / (float)NN;
    const float mu  = st[c] * inv;
    const float var = st[256 + c] * inv - mu * mu;
    const float A   = g[c] * rsqrtf(var + BN_EPS);
    st[512 + c] = A;
    st[768 + c] = b[c] - mu * A;
}

// ===========================================================================
// Fallback per-node aggregation (node_agg2 + optional BN fold on inputs).
// ===========================================================================
template<typename XT, int CIN, bool FOLD>
__global__ __launch_bounds__(256)
void node_agg2(const XT* __restrict__ x, const float* __restrict__ ea_perm,
               const int* __restrict__ src_perm, const int* __restrict__ row_ptr,
               const float* __restrict__ We, const float* __restrict__ be,
               const float* __restrict__ st, bf16* __restrict__ agg)
{
    constexpr int HALF = CIN / 2;     // channels per wave
    constexpr int CPL  = HALF / 64;   // channels per lane (1 or 2)
    const int lane = threadIdx.x & 63;
    const int gw   = blockIdx.x * 4 + (threadIdx.x >> 6);
    const int node = gw >> 1;
    const int half = gw & 1;
    if (node >= NN) return;
    const int c0 = half * HALF + lane * CPL;

    float wcol[16 * CPL];
    #pragma unroll
    for (int k = 0; k < ED; ++k)
        #pragma unroll
        for (int q = 0; q < CPL; ++q)
            wcol[k * CPL + q] = We[k * CIN + c0 + q];
    float bv[CPL];
    #pragma unroll
    for (int q = 0; q < CPL; ++q) bv[q] = be[c0 + q];

    float Af[CPL], Bf[CPL];
    #pragma unroll
    for (int q = 0; q < CPL; ++q) {
        Af[q] = FOLD ? st[512 + c0 + q] : 1.f;
        Bf[q] = FOLD ? st[768 + c0 + q] : 0.f;
    }

    float acc[CPL];
    if (CPL == 2) {
        const float2 v = ld2f(&x[(size_t)node * CIN + c0]);
        acc[0] = fmaf(v.x, Af[0], Bf[0]);
        acc[CPL - 1] = fmaf(v.y, Af[CPL - 1], Bf[CPL - 1]);
    } else {
        const float v = ld1(&x[(size_t)node * CIN + c0]);
        acc[0] = fmaf(v, Af[0], Bf[0]);
    }

    const int e0 = row_ptr[node], e1 = row_ptr[node + 1];
    for (int base = e0; base < e1; base += 4) {
        int ss[4];
        #pragma unroll
        for (int j = 0; j < 4; ++j) {
            int idx = base + j; if (idx >= e1) idx = e1 - 1;
            ss[j] = src_perm[idx];
        }
        float xv0[4], xv1[4];
        #pragma unroll
        for (int j = 0; j < 4; ++j) {
            if (CPL == 2) {
                const float2 v = ld2f(&x[(size_t)ss[j] * CIN + c0]);
                xv0[j] = fmaf(v.x, Af[0], Bf[0]);
                xv1[j] = fmaf(v.y, Af[CPL - 1], Bf[CPL - 1]);
            } else {
                const float v = ld1(&x[(size_t)ss[j] * CIN + c0]);
                xv0[j] = fmaf(v, Af[0], Bf[0]);
            }
        }
        #pragma unroll
        for (int j = 0; j < 4; ++j) {
            if (base + j < e1) {
                const float* ep = ea_perm + (size_t)(base + j) * ED;
                float ev[ED];
                *(float4*)&ev[0]  = *(const float4*)(ep + 0);
                *(float4*)&ev[4]  = *(const float4*)(ep + 4);
                *(float4*)&ev[8]  = *(const float4*)(ep + 8);
                *(float4*)&ev[12] = *(const float4*)(ep + 12);
                float m[CPL];
                #pragma unroll
                for (int q = 0; q < CPL; ++q) m[q] = bv[q];
                #pragma unroll
                for (int k = 0; k < ED; ++k)
                    #pragma unroll
                    for (int q = 0; q < CPL; ++q)
                        m[q] = fmaf(ev[k], wcol[k * CPL + q], m[q]);
                m[0] += xv0[j];
                if (CPL == 2) m[CPL - 1] += xv1[j];
                #pragma unroll
                for (int q = 0; q < CPL; ++q) acc[q] += fmaxf(m[q], 0.f);
            }
        }
    }

    if (CPL == 2) {
        union { ushort2 u; bf16 h[2]; } t;
        t.h[0] = __float2bfloat16(acc[0]);
        t.h[1] = __float2bfloat16(acc[CPL - 1]);
        *(ushort2*)&agg[(size_t)node * CIN + c0] = t.u;
    } else {
        st1(&agg[(size_t)node * CIN + c0], acc[0]);
    }
}

// ===========================================================================
// Chunked edge-MLP GEMM: emsg[e_local, CIN] = ea_bf[e0+e_local] @ Wte + be
// for edges [eb[c], eb[c+1]).  K=32 single step, 128x128 tile, 4 waves.
// m97-style global_load_lds staging (linear LDS, 16 B/lane).
// All writes hard-clamped to the cap-row buffer.
// ===========================================================================
template<int CIN>
__global__ __launch_bounds__(256)
void emsg_gemm(const bf16* __restrict__ Abase, const bf16* __restrict__ Wt,
               const float* __restrict__ bias, bf16* __restrict__ Cl,
               const int* __restrict__ eb, int c, int cap)
{
    __shared__ short As[128 * 32];   // 8 KB, linear (gload_lds requirement)
    __shared__ short Bs[128 * 32];
    const int e0 = eb[c], e1 = eb[c + 1];
    int Mc = e1 - e0;
    if (Mc > cap) Mc = cap;               // insurance: never leave buffer
    const int bm = blockIdx.y * 128;
    if (bm >= Mc) return;
    const int bn   = blockIdx.x * 128;
    const int tid  = threadIdx.x;
    const int lane = tid & 63;
    const int wave = tid >> 6;
    const int wr   = (wave >> 1) * 64;
    const int wc   = (wave & 1) * 64;
    const int l15  = lane & 15;
    const int quad = lane >> 4;
    const int rsub = lane >> 2;            // row within 16-row chunk
    const int part = lane & 3;             // 16 B part within 64 B row

    // stage A(128x32) + Wt(128x32): each wave issues 2 chunks of each.
    #pragma unroll
    for (int i = 0; i < 2; ++i) {
        const int ca = wave * 2 + i;
        int ar = bm + ca * 16 + rsub; if (ar >= Mc) ar = Mc - 1;
        gld16(&Abase[(size_t)(e0 + ar) * 32 + part * 8], &As[ca * 512]);
        gld16(&Wt[(size_t)(bn + ca * 16 + rsub) * 32 + part * 8], &Bs[ca * 512]);
    }
    __syncthreads();

    f32x4 acc[4][4];
    #pragma unroll
    for (int i = 0; i < 4; ++i)
        #pragma unroll
        for (int j = 0; j < 4; ++j)
            acc[i][j] = (f32x4){0.f, 0.f, 0.f, 0.f};

    bf16x8 af[4], bfr[4];
    #pragma unroll
    for (int i = 0; i < 4; ++i) {
        af[i]  = *(const bf16x8*)&As[(wr + i * 16 + l15) * 32 + quad * 8];
        bfr[i] = *(const bf16x8*)&Bs[(wc + i * 16 + l15) * 32 + quad * 8];
    }
    #pragma unroll
    for (int mi = 0; mi < 4; ++mi)
        #pragma unroll
        for (int ni = 0; ni < 4; ++ni)
            acc[mi][ni] = __builtin_amdgcn_mfma_f32_16x16x32_bf16(
                              af[mi], bfr[ni], acc[mi][ni], 0, 0, 0);

    float bv[4];
    #pragma unroll
    for (int ni = 0; ni < 4; ++ni)
        bv[ni] = bias[bn + wc + ni * 16 + l15];
    #pragma unroll
    for (int mi = 0; mi < 4; ++mi) {
        const int lr0 = bm + wr + mi * 16 + quad * 4;
        #pragma unroll
        for (int r = 0; r < 4; ++r) {
            const int lr = lr0 + r;
            if (lr < Mc) {
                #pragma unroll
                for (int ni = 0; ni < 4; ++ni) {
                    const float v = acc[mi][ni][r] + bv[ni];
                    Cl[(size_t)lr * CIN + bn + wc + ni * 16 + l15] =
                        __float2bfloat16(v);
                }
            }
        }
    }
}

// ===========================================================================
// Chunked streaming aggregation: for nodes [cb[c], cb[c+1]):
//   agg[n] = fold(x[n]) + sum_e relu(fold(x[src_e]) + emsg_local[e])
// One wave per node; CPL = CIN/64 channels per lane (2 or 4), 8-deep prefetch.
// ===========================================================================
template<typename XT, int CIN, bool FOLD>
__global__ __launch_bounds__(256)
void node_agg3(const XT* __restrict__ x, const bf16* __restrict__ emsg,
               const int* __restrict__ src_perm, const int* __restrict__ row_ptr,
               const float* __restrict__ st, const int* __restrict__ cb,
               const int* __restrict__ eb, int c, int cap, bf16* __restrict__ agg)
{
    constexpr int CPL = CIN / 64;     // 2 (layer0 fp32) or 4 (bf16 256)
    const int lane = threadIdx.x & 63;
    int gw = blockIdx.x * 4 + (threadIdx.x >> 6);
    gw = __builtin_amdgcn_readfirstlane(gw);   // wave-uniform -> SGPR
    const int node = cb[c] + gw;
    if (node >= cb[c + 1]) return;
    const int c0 = lane * CPL;

    float Af[CPL], Bf[CPL];
    #pragma unroll
    for (int q = 0; q < CPL; ++q) {
        Af[q] = FOLD ? st[512 + c0 + q] : 1.f;
        Bf[q] = FOLD ? st[768 + c0 + q] : 0.f;
    }

    float acc[CPL];
    if constexpr (CPL == 4) {
        const float4 v = ld4(&x[(size_t)node * CIN + c0]);
        acc[0] = fmaf(v.x, Af[0], Bf[0]); acc[1] = fmaf(v.y, Af[1], Bf[1]);
        acc[2] = fmaf(v.z, Af[2], Bf[2]); acc[3] = fmaf(v.w, Af[3], Bf[3]);
    } else {
        const float2 v = ld2f(&x[(size_t)node * CIN + c0]);
        acc[0] = fmaf(v.x, Af[0], Bf[0]);
        acc[CPL - 1] = fmaf(v.y, Af[CPL - 1], Bf[CPL - 1]);
    }

    const int e0 = row_ptr[node], e1 = row_ptr[node + 1];
    const int eb0 = eb[c];
    for (int base = e0; base < e1; base += 8) {
        int ss[8], li[8];
        #pragma unroll
        for (int j = 0; j < 8; ++j) {
            int idx = base + j; if (idx >= e1) idx = e1 - 1;
            ss[j] = src_perm[idx];
            int l = idx - eb0; if (l >= cap) l = cap - 1;   // insurance
            li[j] = l;
        }
        if constexpr (CPL == 4) {
            float4 xv[8]; ushort4 mv[8];
            #pragma unroll
            for (int j = 0; j < 8; ++j) {
                xv[j] = ld4(&x[(size_t)ss[j] * CIN + c0]);
                mv[j] = *(const ushort4*)&emsg[(size_t)li[j] * CIN + c0];
            }
            #pragma unroll
            for (int j = 0; j < 8; ++j) {
                if (base + j < e1) {
                    acc[0] += fmaxf(fmaf(xv[j].x, Af[0], Bf[0]) + bfraw(mv[j].x), 0.f);
                    acc[1] += fmaxf(fmaf(xv[j].y, Af[1], Bf[1]) + bfraw(mv[j].y), 0.f);
                    acc[2] += fmaxf(fmaf(xv[j].z, Af[2], Bf[2]) + bfraw(mv[j].z), 0.f);
                    acc[3] += fmaxf(fmaf(xv[j].w, Af[3], Bf[3]) + bfraw(mv[j].w), 0.f);
                }
            }
        } else {
            float2 xv[8]; ushort2 mv[8];
            #pragma unroll
            for (int j = 0; j < 8; ++j) {
                xv[j] = ld2f(&x[(size_t)ss[j] * CIN + c0]);
                mv[j] = *(const ushort2*)&emsg[(size_t)li[j] * CIN + c0];
            }
            #pragma unroll
            for (int j = 0; j < 8; ++j) {
                if (base + j < e1) {
                    acc[0] += fmaxf(fmaf(xv[j].x, Af[0], Bf[0]) + bfraw(mv[j].x), 0.f);
                    acc[CPL - 1] += fmaxf(fmaf(xv[j].y, Af[CPL - 1], Bf[CPL - 1])
                                          + bfraw(mv[j].y), 0.f);
                }
            }
        }
    }

    if constexpr (CPL == 4) {
        union { ushort4 u; bf16 h[4]; } t;
        t.h[0] = __float2bfloat16(acc[0]); t.h[1] = __float2bfloat16(acc[1]);
        t.h[2] = __float2bfloat16(acc[2]); t.h[3] = __float2bfloat16(acc[3]);
        *(ushort4*)&agg[(size_t)node * CIN + c0] = t.u;
    } else {
        union { ushort2 u; bf16 h[2]; } t;
        t.h[0] = __float2bfloat16(acc[0]);
        t.h[1] = __float2bfloat16(acc[CPL - 1]);
        *(ushort2*)&agg[(size_t)node * CIN + c0] = t.u;
    }
}

// ===========================================================================
// Conv MFMA GEMM: C[M,256] = relu(A[M,K] @ Wt[256,K]^T + bias), bf16 out.
// m97-style global_load_lds staging: linear [128][32] LDS, 16 B/lane,
// 2-barrier K-loop.  STATS: per-channel sum/sumsq of post-relu output
// into st[0..255]/st[256..511] (quad-reduce + atomics).
// ===========================================================================
template<int K, bool STATS>
__global__ __launch_bounds__(256, 3)
void gemm_mfma(const bf16* __restrict__ A, const bf16* __restrict__ Wt,
               const float* __restrict__ bias, bf16* __restrict__ C, int M,
               float* __restrict__ st)
{
    __shared__ short As[128 * 32];   // 8 KB, linear
    __shared__ short Bs[128 * 32];
    const int tid  = threadIdx.x;
    const int bm   = blockIdx.y * 128;
    const int bn   = blockIdx.x * 128;      // 0 or 128 (N = 256)
    const int lane = tid & 63;
    const int wave = tid >> 6;
    const int wr   = (wave >> 1) * 64;
    const int wc   = (wave & 1) * 64;
    const int l15  = lane & 15;
    const int quad = lane >> 4;
    const int rsub = lane >> 2;             // row within 16-row chunk
    const int part = lane & 3;              // 16 B part within 64 B row

    f32x4 acc[4][4];
    #pragma unroll
    for (int i = 0; i < 4; ++i)
        #pragma unroll
        for (int j = 0; j < 4; ++j)
            acc[i][j] = (f32x4){0.f, 0.f, 0.f, 0.f};

    for (int k0 = 0; k0 < K; k0 += 32) {
        // stage A(128x32) and Wt(128x32) tiles: 16 gload_lds instrs total.
        #pragma unroll
        for (int i = 0; i < 2; ++i) {
            const int ca = wave * 2 + i;
            int ar = bm + ca * 16 + rsub; if (ar >= M) ar = M - 1;
            gld16(&A[(size_t)ar * K + k0 + part * 8], &As[ca * 512]);
            gld16(&Wt[(size_t)(bn + ca * 16 + rsub) * K + k0 + part * 8],
                  &Bs[ca * 512]);
        }
        __syncthreads();

        bf16x8 af[4], bfr[4];
        #pragma unroll
        for (int i = 0; i < 4; ++i) {
            af[i]  = *(const bf16x8*)&As[(wr + i * 16 + l15) * 32 + quad * 8];
            bfr[i] = *(const bf16x8*)&Bs[(wc + i * 16 + l15) * 32 + quad * 8];
        }
        #pragma unroll
        for (int mi = 0; mi < 4; ++mi)
            #pragma unroll
            for (int ni = 0; ni < 4; ++ni)
                acc[mi][ni] = __builtin_amdgcn_mfma_f32_16x16x32_bf16(
                                  af[mi], bfr[ni], acc[mi][ni], 0, 0, 0);
        __syncthreads();
    }

    float bv[4];
    #pragma unroll
    for (int ni = 0; ni < 4; ++ni)
        bv[ni] = bias[bn + wc + ni * 16 + l15];
    float ps[4]  = {0.f, 0.f, 0.f, 0.f};
    float ps2[4] = {0.f, 0.f, 0.f, 0.f};
    #pragma unroll
    for (int mi = 0; mi < 4; ++mi) {
        const int row0 = bm + wr + mi * 16 + quad * 4;
        #pragma unroll
        for (int r = 0; r < 4; ++r) {
            const int row = row0 + r;
            if (row < M) {
                #pragma unroll
                for (int ni = 0; ni < 4; ++ni) {
                    float v = acc[mi][ni][r] + bv[ni];
                    v = fmaxf(v, 0.f);
                    C[(size_t)row * 256 + bn + wc + ni * 16 + l15] = __float2bfloat16(v);
                    if (STATS) { ps[ni] += v; ps2[ni] = fmaf(v, v, ps2[ni]); }
                }
            }
        }
    }
    if (STATS) {
        #pragma unroll
        for (int ni = 0; ni < 4; ++ni) {
            float s = ps[ni], q = ps2[ni];
            s += __shfl_xor(s, 16); s += __shfl_xor(s, 32);
            q += __shfl_xor(q, 16); q += __shfl_xor(q, 32);
            if (quad == 0) {
                const int col = bn + wc + ni * 16 + l15;
                atomicAdd(&st[col], s);
                atomicAdd(&st[256 + col], q);
            }
        }
    }
}

// ---------------------------------------------------------------------------
// fp32 GEMM (dense head only): C = (relu?)(A @ W + bias)
// ---------------------------------------------------------------------------
template<bool RELU, typename InT, typename OutT>
__global__ __launch_bounds__(256)
void gemm_rk(const InT* __restrict__ A, const float* __restrict__ W,
             const float* __restrict__ bias, OutT* __restrict__ C,
             int M, int N, int K)
{
    __shared__ float Asm[16][64];
    __shared__ float Wsm[16][64];
    const int bm = blockIdx.y * 64;
    const int bn = blockIdx.x * 64;
    const int tid = threadIdx.x;
    const int tx = tid & 15, ty = tid >> 4;
    const int ar = tid >> 2, ac = (tid & 3) * 4;
    const int wrr = tid >> 4, wcc = (tid & 15) * 4;

    float acc[4][4] = {};

    for (int k0 = 0; k0 < K; k0 += 16) {
        float4 av = make_float4(0.f, 0.f, 0.f, 0.f);
        if (bm + ar < M)
            av = ld4(A + (size_t)(bm + ar) * K + k0 + ac);
        Asm[ac + 0][ar] = av.x; Asm[ac + 1][ar] = av.y;
        Asm[ac + 2][ar] = av.z; Asm[ac + 3][ar] = av.w;

        float4 wv = make_float4(0.f, 0.f, 0.f, 0.f);
        if (bn + wcc < N)
            wv = *(const float4*)(W + (size_t)(k0 + wrr) * N + bn + wcc);
        *(float4*)&Wsm[wrr][wcc] = wv;
        __syncthreads();

        #pragma unroll
        for (int k = 0; k < 16; ++k) {
            const float4 a4 = *(const float4*)&Asm[k][ty * 4];
            const float4 b4 = *(const float4*)&Wsm[k][tx * 4];
            const float aa[4] = {a4.x, a4.y, a4.z, a4.w};
            const float bb[4] = {b4.x, b4.y, b4.z, b4.w};
            #pragma unroll
            for (int i = 0; i < 4; ++i)
                #pragma unroll
                for (int j = 0; j < 4; ++j)
                    acc[i][j] += aa[i] * bb[j];
        }
        __syncthreads();
    }

    float bvals[4];
    #pragma unroll
    for (int j = 0; j < 4; ++j) {
        const int col = bn + tx * 4 + j;
        bvals[j] = (col < N) ? bias[col] : 0.f;
    }
    #pragma unroll
    for (int i = 0; i < 4; ++i) {
        const int row = bm + ty * 4 + i;
        if (row >= M) continue;
        float v[4];
        #pragma unroll
        for (int j = 0; j < 4; ++j) {
            v[j] = acc[i][j] + bvals[j];
            if (RELU) v[j] = fmaxf(v[j], 0.f);
        }
        if (bn + tx * 4 + 3 < N) {
            st4(C + (size_t)row * N + bn + tx * 4, make_float4(v[0], v[1], v[2], v[3]));
        } else {
            #pragma unroll
            for (int j = 0; j < 4; ++j) {
                const int col = bn + tx * 4 + j;
                if (col < N) st1(C + (size_t)row * N + col, v[j]);
            }
        }
    }
}

// ---------------------------------------------------------------------------
// Mean-pool over sorted batch ids, with BN fold applied on the fly.
// ---------------------------------------------------------------------------
template<typename InT, bool FOLD>
__global__ __launch_bounds__(256)
void pool_sum(const InT* __restrict__ h, const int* __restrict__ batch,
              const float* __restrict__ st,
              float* __restrict__ sums, float* __restrict__ cnts)
{
    const int c = threadIdx.x;
    size_t n0 = (size_t)blockIdx.x * 128;
    size_t n1 = n0 + 128; if (n1 > (size_t)NN) n1 = NN;
    if (n0 >= (size_t)NN) return;
    const float A = FOLD ? st[512 + c] : 1.f;
    const float B = FOLD ? st[768 + c] : 0.f;
    int cur = batch[n0];
    float s = 0.f, cnt = 0.f;
    for (size_t n = n0; n < n1; ++n) {
        const int b = batch[n];
        if (b != cur) {
            atomicAdd(&sums[(size_t)cur * 256 + c], s);
            if (c == 0) atomicAdd(&cnts[cur], cnt);
            s = 0.f; cnt = 0.f; cur = b;
        }
        const float v = ld1(&h[n * 256 + c]);
        s += fmaf(v, A, B);
        cnt += 1.f;
    }
    atomicAdd(&sums[(size_t)cur * 256 + c], s);
    if (c == 0) atomicAdd(&cnts[cur], cnt);
}

__global__ __launch_bounds__(256)
void pool_div(float* __restrict__ sums, const float* __restrict__ cnts)
{
    const int i = blockIdx.x * 256 + threadIdx.x;   // NG*256 threads exactly
    const int g = i >> 8;
    sums[i] = sums[i] / fmaxf(cnts[g], 1.f);
}

__global__ __launch_bounds__(256)
void head_out(const float* __restrict__ y, const float* __restrict__ Wo,
              const float* __restrict__ bo, float* __restrict__ out)
{
    const int g = blockIdx.x * 256 + threadIdx.x;
    if (g >= NG) return;
    float s = bo[0];
    #pragma unroll
    for (int k = 0; k < 32; ++k) s += y[g * 32 + k] * Wo[k];
    out[g] = s;
}

__global__ __launch_bounds__(256)
void diag_fill(float* __restrict__ out, int n, float v)
{
    const int i = blockIdx.x * 256 + threadIdx.x;
    if (i < n) out[i] = v;
}

// ---------------------------------------------------------------------------
extern "C" void kernel_launch(void* const* d_in, const int* in_sizes, int n_in,
                              void* d_out, int out_size, void* d_ws, size_t ws_size,
                              hipStream_t stream)
{
    const float* x    = (const float*)d_in[0];
    const int*   ei   = (const int*)d_in[1];
    const int*   batch= (const int*)d_in[2];
    const float* ea   = (const float*)d_in[3];
    const float* We[3] = {(const float*)d_in[4],  (const float*)d_in[10], (const float*)d_in[16]};
    const float* be[3] = {(const float*)d_in[5],  (const float*)d_in[11], (const float*)d_in[17]};
    const float* Wn[3] = {(const float*)d_in[6],  (const float*)d_in[12], (const float*)d_in[18]};
    const float* bnb[3]= {(const float*)d_in[7],  (const float*)d_in[13], (const float*)d_in[19]};
    const float* gm[3] = {(const float*)d_in[8],  (const float*)d_in[14], (const float*)d_in[20]};
    const float* bt[3] = {(const float*)d_in[9],  (const float*)d_in[15], (const float*)d_in[21]};
    const float* Wd0 = (const float*)d_in[22]; const float* bd0 = (const float*)d_in[23];
    const float* Wd1 = (const float*)d_in[24]; const float* bd1 = (const float*)d_in[25];
    const float* Wd2 = (const float*)d_in[26]; const float* bd2 = (const float*)d_in[27];
    const float* Wo  = (const float*)d_in[28]; const float* bo  = (const float*)d_in[29];
    float* out = (float*)d_out;
    float* ws  = (float*)d_ws;

    // ---- workspace layout (float offsets; 16B alignment kept) ----
    constexpr size_t OFF_H    = 0;                            // NN*256 bf16
    constexpr size_t OFF_AGG  = 25600000;                     // NN*256 bf16
    constexpr size_t OFF_ST   = 51200000;                     // 1536 fl
    constexpr size_t OFF_WT0  = OFF_ST + 1536;                // 128*256 bf16
    constexpr size_t OFF_WT1  = OFF_WT0 + 16384;              // 256*256 bf16
    constexpr size_t OFF_WT2  = OFF_WT1 + 32768;              // 256*256 bf16
    constexpr size_t OFF_WTE0 = OFF_WT2 + 32768;              // 128*32 bf16
    constexpr size_t OFF_WTE1 = OFF_WTE0 + 2048;              // 256*32 bf16
    constexpr size_t OFF_WTE2 = OFF_WTE1 + 4096;              // 256*32 bf16
    constexpr size_t OFF_EA   = OFF_WTE2 + 4096;              // NE*16 fp32 | NE*32 bf16
    constexpr size_t OFF_SRC  = OFF_EA + 12800000;            // NE int
    constexpr size_t OFF_RP   = OFF_SRC + NE;                 // NN+1 int
    constexpr size_t OFF_CUR  = OFF_RP + (NN + 1);            // NN int
    constexpr size_t OFF_PERM = OFF_CUR + NN;                 // NE int
    constexpr size_t OFF_BSUM = OFF_PERM + NE;                // SCAN_NBLK int
    constexpr size_t OFF_CB   = OFF_BSUM + SCAN_NBLK;         // <=9 int
    constexpr size_t OFF_EB   = OFF_CB + 12;                  // <=9 int
    constexpr size_t BASE_END = OFF_EB + 12;
    constexpr size_t OFF_EMSG = (BASE_END + 3) & ~(size_t)3;  // cap*256 bf16
    constexpr size_t NEED_BASE = BASE_END * 4;

    bf16*  H        = (bf16*)(ws + OFF_H);
    bf16*  AGG      = (bf16*)(ws + OFF_AGG);
    float* st       = ws + OFF_ST;
    bf16*  wt0      = (bf16*)(ws + OFF_WT0);
    bf16*  wt1      = (bf16*)(ws + OFF_WT1);
    bf16*  wt2      = (bf16*)(ws + OFF_WT2);
    bf16*  wte[3]   = {(bf16*)(ws + OFF_WTE0), (bf16*)(ws + OFF_WTE1), (bf16*)(ws + OFF_WTE2)};
    float* ea_perm  = ws + OFF_EA;              // fallback layout (fp32)
    bf16*  ea_bf    = (bf16*)(ws + OFF_EA);     // full layout (bf16 padded)
    int*   src_perm = (int*)(ws + OFF_SRC);
    int*   row_ptr  = (int*)(ws + OFF_RP);
    int*   cursor   = (int*)(ws + OFF_CUR);
    int*   perm     = (int*)(ws + OFF_PERM);
    int*   bsum     = (int*)(ws + OFF_BSUM);
    int*   cb       = (int*)(ws + OFF_CB);
    int*   eb       = (int*)(ws + OFF_EB);
    bf16*  emsg     = (bf16*)(ws + OFF_EMSG);

    if (ws_size < NEED_BASE) {
        diag_fill<<<(NG + 255) / 256, 256, 0, stream>>>(out, NG, (float)(ws_size >> 20));
        return;
    }

    // Adaptive chunking: pick the largest emsg buffer that fits.
    // Safe caps: max edges/chunk = (NE+4NN)/nchunk (weight-balance bound).
    int nchunk = 0, cap = 0;
    if      (ws_size >= (OFF_EMSG + 400000ull * 128) * 4) { nchunk = 4; cap = 400000; }
    else if (ws_size >= (OFF_EMSG + 200000ull * 128) * 4) { nchunk = 8; cap = 200000; }
    else if (ws_size >= (OFF_EMSG + 140032ull * 128) * 4) { nchunk = 8; cap = 140032; }
    const bool full = nchunk > 0;

    // ---- one-time prep: CSR build, edge pre-gather, weight transpose ----
    hipMemsetAsync(row_ptr, 0, (size_t)(NN + 1) * 4, stream);
    k_hist<<<1024, 256, 0, stream>>>(ei, row_ptr);
    k_scan_block<<<SCAN_NBLK, 256, 0, stream>>>(row_ptr, bsum);
    k_scan_top<<<1, 256, 0, stream>>>(bsum, SCAN_NBLK);
    k_scan_emit<<<SCAN_NBLK, 256, 0, stream>>>(row_ptr, bsum, row_ptr, cursor);
    k_scatter<<<1024, 256, 0, stream>>>(ei, cursor, perm);
    if (full) {
        k_bounds<<<1, 64, 0, stream>>>(row_ptr, cb, eb, nchunk);
        k_gather_edges_bf<<<(NE * 16 + 255) / 256, 256, 0, stream>>>(ei, ea, perm, src_perm, ea_bf);
        k_wte<<<(128 * 32 + 255) / 256, 256, 0, stream>>>(We[0], wte[0], 128);
        k_wte<<<(256 * 32 + 255) / 256, 256, 0, stream>>>(We[1], wte[1], 256);
        k_wte<<<(256 * 32 + 255) / 256, 256, 0, stream>>>(We[2], wte[2], 256);
    } else {
        k_gather_edges<<<(NE * ED + 255) / 256, 256, 0, stream>>>(ei, ea, perm, src_perm, ea_perm);
    }
    k_wt<<<(128 * 256 + 255) / 256, 256, 0, stream>>>(Wn[0], wt0, 128, 256);
    k_wt<<<(256 * 256 + 255) / 256, 256, 0, stream>>>(Wn[1], wt1, 256, 256);
    k_wt<<<(256 * 256 + 255) / 256, 256, 0, stream>>>(Wn[2], wt2, 256, 256);

    const dim3 mfma_grid(2, (NN + 127) / 128);        // conv GEMMs: N=256
    const int  agg2_grid = (NN * 2) / 4;              // fallback: 2 waves/node
    const int  egy = full ? (cap + 127) / 128 : 1;    // emsg gemm grid rows
    const int  a3b = full ? (100000 / nchunk + 2) : 1;// agg3 blocks (4 nodes/blk)

    // ---- layer 0 (cin=128 -> 256), input x fp32, no fold ----
    if (full) {
        for (int c = 0; c < nchunk; ++c) {
            emsg_gemm<128><<<dim3(1, egy), 256, 0, stream>>>(ea_bf, wte[0], be[0], emsg, eb, c, cap);
            node_agg3<float, 128, false><<<a3b, 256, 0, stream>>>(
                x, emsg, src_perm, row_ptr, st, cb, eb, c, cap, AGG);
        }
    } else {
        node_agg2<float, 128, false><<<agg2_grid, 256, 0, stream>>>(
            x, ea_perm, src_perm, row_ptr, We[0], be[0], st, AGG);
    }
    hipMemsetAsync(st, 0, 512 * 4, stream);
    gemm_mfma<128, true><<<mfma_grid, 256, 0, stream>>>(AGG, wt0, bnb[0], H, NN, st);
    k_bnab<<<1, 256, 0, stream>>>(st, gm[0], bt[0]);

    // ---- layers 1,2 (256 -> 256), input H bf16 raw + fold(A,B) ----
    for (int l = 1; l < 3; ++l) {
        if (full) {
            for (int c = 0; c < nchunk; ++c) {
                emsg_gemm<256><<<dim3(2, egy), 256, 0, stream>>>(ea_bf, wte[l], be[l], emsg, eb, c, cap);
                node_agg3<bf16, 256, true><<<a3b, 256, 0, stream>>>(
                    H, emsg, src_perm, row_ptr, st, cb, eb, c, cap, AGG);
            }
        } else {
            node_agg2<bf16, 256, true><<<agg2_grid, 256, 0, stream>>>(
                H, ea_perm, src_perm, row_ptr, We[l], be[l], st, AGG);
        }
        hipMemsetAsync(st, 0, 512 * 4, stream);
        gemm_mfma<256, true><<<mfma_grid, 256, 0, stream>>>(
            AGG, (l == 1) ? wt1 : wt2, bnb[l], H, NN, st);
        k_bnab<<<1, 256, 0, stream>>>(st, gm[l], bt[l]);
    }

    // ---- head scratch overlays AGG (dead after last conv GEMM) ----
    float* poolb = (float*)AGG;           // NG*256 = 1,024,000 fl
    float* cnts  = poolb + 1024000;       // NG
    float* y1    = poolb + 1028000;       // NG*512
    float* y2    = poolb + 3076000;       // NG*128
    float* y3    = poolb + 3588000;       // NG*32

    hipMemsetAsync(poolb, 0, (size_t)NG * 256 * 4, stream);
    hipMemsetAsync(cnts, 0, (size_t)NG * 4, stream);
    pool_sum<bf16, true><<<(NN + 127) / 128, 256, 0, stream>>>(H, batch, st, poolb, cnts);
    pool_div<<<NG, 256, 0, stream>>>(poolb, cnts);

    // ---- dense head (fp32) ----
    gemm_rk<true, float, float><<<dim3(8, (NG + 63) / 64), 256, 0, stream>>>(poolb, Wd0, bd0, y1, NG, 512, 256);
    gemm_rk<true, float, float><<<dim3(2, (NG + 63) / 64), 256, 0, stream>>>(y1, Wd1, bd1, y2, NG, 128, 512);
    gemm_rk<true, float, float><<<dim3(1, (NG + 63) / 64), 256, 0, stream>>>(y2, Wd2, bd2, y3, NG, 32, 128);
    head_out<<<(NG + 255) / 256, 256, 0, stream>>>(y3, Wo, bo, out);
}

// Round 5
// 1650.117 us; speedup vs baseline: 1.3451x; 1.0368x over previous
//
#include <hip/hip_runtime.h>
#include <hip/hip_bf16.h>

using bf16 = __hip_bfloat16;
typedef __attribute__((ext_vector_type(8))) short bf16x8;   // 8 bf16 (4 VGPRs)
typedef __attribute__((ext_vector_type(4))) float f32x4;    // MFMA accumulator

constexpr int NN = 200000;   // nodes
constexpr int NE = 800000;   // edges
constexpr int NG = 4000;     // graphs
constexpr int ED = 16;       // edge feature dim
constexpr float BN_EPS = 1e-5f;

constexpr int WSTEP = 88;                              // block weight step
constexpr int NB    = (NE + NN + WSTEP - 1) / WSTEP;   // 11364 fused blocks

// ---------------- storage-type helpers (fp32 or bf16 node features) --------
__device__ __forceinline__ float  ld1(const float* p) { return *p; }
__device__ __forceinline__ float  ld1(const bf16*  p) { return __bfloat162float(*p); }
__device__ __forceinline__ float2 ld2f(const float* p) { return *(const float2*)p; }
__device__ __forceinline__ float2 ld2f(const bf16*  p) {
    union { ushort2 u; bf16 h[2]; } t;
    t.u = *(const ushort2*)p;
    return make_float2(__bfloat162float(t.h[0]), __bfloat162float(t.h[1]));
}
__device__ __forceinline__ float4 ld4(const float* p) { return *(const float4*)p; }
__device__ __forceinline__ float4 ld4(const bf16*  p) {
    union { ushort4 u; bf16 h[4]; } t;
    t.u = *(const ushort4*)p;
    return make_float4(__bfloat162float(t.h[0]), __bfloat162float(t.h[1]),
                       __bfloat162float(t.h[2]), __bfloat162float(t.h[3]));
}
__device__ __forceinline__ void st1(float* p, float v) { *p = v; }
__device__ __forceinline__ void st1(bf16*  p, float v) { *p = __float2bfloat16(v); }
__device__ __forceinline__ void st4(float* p, float4 v) { *(float4*)p = v; }
__device__ __forceinline__ void st4(bf16*  p, float4 v) {
    union { ushort4 u; bf16 h[4]; } t;
    t.h[0] = __float2bfloat16(v.x); t.h[1] = __float2bfloat16(v.y);
    t.h[2] = __float2bfloat16(v.z); t.h[3] = __float2bfloat16(v.w);
    *(ushort4*)p = t.u;
}
__device__ __forceinline__ float bfraw(unsigned short u) {
    union { unsigned short s; bf16 h; } t; t.s = u;
    return __bfloat162float(t.h);
}

// async global -> LDS, 16 B per lane (m97 pattern). LDS dest must be the
// wave-uniform chunk base; HW adds lane*16.
__device__ __forceinline__ void gld16(const void* g, void* l)
{
    __builtin_amdgcn_global_load_lds(
        (const __attribute__((address_space(1))) void*)g,
        (__attribute__((address_space(3))) void*)l, 16, 0, 0);
}

// ===========================================================================
// CSR-by-dst build (once per call; reused by all 3 conv layers)
// ===========================================================================
constexpr int SCAN_CHUNK = 1024;
constexpr int SCAN_NBLK  = (NN + SCAN_CHUNK - 1) / SCAN_CHUNK;   // 196

__global__ __launch_bounds__(256)
void k_hist(const int* __restrict__ ei, int* __restrict__ cnt)
{
    int e = blockIdx.x * 256 + threadIdx.x;
    const int stride = gridDim.x * 256;
    for (; e < NE; e += stride) atomicAdd(&cnt[ei[NE + e]], 1);
}

__global__ __launch_bounds__(256)
void k_scan_block(const int* __restrict__ cnt, int* __restrict__ bsum)
{
    __shared__ int red[256];
    const int b = blockIdx.x, t = threadIdx.x;
    const int base = b * SCAN_CHUNK + t * 4;
    int s = 0;
    #pragma unroll
    for (int k = 0; k < 4; ++k) { const int i = base + k; if (i < NN) s += cnt[i]; }
    red[t] = s; __syncthreads();
    for (int off = 128; off > 0; off >>= 1) {
        if (t < off) red[t] += red[t + off];
        __syncthreads();
    }
    if (t == 0) bsum[b] = red[0];
}

__global__ __launch_bounds__(256)
void k_scan_top(int* __restrict__ bsum, int n)
{
    __shared__ int sh[256];
    const int t = threadIdx.x;
    const int orig = (t < n) ? bsum[t] : 0;
    sh[t] = orig; __syncthreads();
    for (int off = 1; off < 256; off <<= 1) {
        const int v = (t >= off) ? sh[t - off] : 0;
        __syncthreads();
        sh[t] += v;
        __syncthreads();
    }
    if (t < n) bsum[t] = sh[t] - orig;   // exclusive
}

__global__ __launch_bounds__(256)
void k_scan_emit(const int* __restrict__ cnt, const int* __restrict__ bsum,
                 int* __restrict__ row_ptr, int* __restrict__ cursor)
{
    __shared__ int sh[256];
    const int b = blockIdx.x, t = threadIdx.x;
    const int base = b * SCAN_CHUNK + t * 4;
    int c[4]; int s = 0;
    #pragma unroll
    for (int k = 0; k < 4; ++k) {
        const int i = base + k;
        c[k] = (i < NN) ? cnt[i] : 0;    // read BEFORE aliased write below
        s += c[k];
    }
    const int orig = s;
    sh[t] = s; __syncthreads();
    for (int off = 1; off < 256; off <<= 1) {
        const int v = (t >= off) ? sh[t - off] : 0;
        __syncthreads();
        sh[t] += v;
        __syncthreads();
    }
    int run = bsum[b] + sh[t] - orig;     // exclusive prefix of this thread
    #pragma unroll
    for (int k = 0; k < 4; ++k) {
        const int i = base + k;
        if (i < NN) { row_ptr[i] = run; cursor[i] = run; run += c[k]; }
    }
    if (b == 0 && t == 0) row_ptr[NN] = NE;
}

__global__ __launch_bounds__(256)
void k_scatter(const int* __restrict__ ei, int* __restrict__ cursor,
               int* __restrict__ perm)
{
    int e = blockIdx.x * 256 + threadIdx.x;
    const int stride = gridDim.x * 256;
    for (; e < NE; e += stride) {
        const int d = ei[NE + e];
        const int p = atomicAdd(&cursor[d], 1);
        perm[p] = e;
    }
}

// Fused-block boundaries: nb[t] = first node of block t, by binary search on
// W(n) = row_ptr[n] + n with target t*(NE+NN)/NB.  Block weight <= step +
// max node weight (~20 here) <= 128, so edges/block <= 128 and nodes/block
// <= 128 (both clamped in the consumer as insurance).
__global__ __launch_bounds__(256)
void k_bounds2(const int* __restrict__ row_ptr, int* __restrict__ nb)
{
    const int t = blockIdx.x * 256 + threadIdx.x;
    if (t > NB) return;
    const long long target = (long long)t * (NE + NN) / NB;
    int lo = 0, hi = NN;
    while (lo < hi) {
        const int mid = (lo + hi) >> 1;
        const long long W = (long long)row_ptr[mid] + mid;
        if (W >= target) hi = mid; else lo = mid + 1;
    }
    nb[t] = lo;
}

// Edge features as bf16 [NE,32] in perm order, zero-padded K 16->32.
__global__ __launch_bounds__(256)
void k_gather_edges_bf(const int* __restrict__ ei, const float* __restrict__ ea,
                       const int* __restrict__ perm, int* __restrict__ src_perm,
                       bf16* __restrict__ ea_bf)
{
    const int t = blockIdx.x * 256 + threadIdx.x;    // over NE*16 (2 bf16 each)
    if (t >= NE * 16) return;
    const int idx = t >> 4, k2 = (t & 15) * 2;       // k2 in 0..30
    const int e = perm[idx];
    union { ushort2 u; bf16 h[2]; } o;
    if (k2 < ED) {
        const float2 v = *(const float2*)&ea[(size_t)e * ED + k2];
        o.h[0] = __float2bfloat16(v.x);
        o.h[1] = __float2bfloat16(v.y);
    } else {
        o.u = make_ushort2(0, 0);
    }
    *(ushort2*)&ea_bf[(size_t)idx * 32 + k2] = o.u;
    if ((t & 15) == 0) src_perm[idx] = ei[e];
}

// One-shot: W[K,N] fp32 -> Wt[N,K] bf16 (transposed for the MFMA GEMM).
__global__ __launch_bounds__(256)
void k_wt(const float* __restrict__ W, bf16* __restrict__ Wt, int K, int N)
{
    const int i = blockIdx.x * 256 + threadIdx.x;
    if (i >= K * N) return;
    const int k = i / N, n = i % N;
    Wt[(size_t)n * K + k] = __float2bfloat16(W[i]);
}

// One-shot: We[16,cin] fp32 -> Wte[cin,32] bf16, K zero-padded 16->32.
__global__ __launch_bounds__(256)
void k_wte(const float* __restrict__ We, bf16* __restrict__ Wte, int cin)
{
    const int i = blockIdx.x * 256 + threadIdx.x;    // over cin*32
    if (i >= cin * 32) return;
    const int n = i >> 5, k = i & 31;
    Wte[i] = __float2bfloat16((k < ED) ? We[k * cin + n] : 0.f);
}

// BN fold coefficients: A = g*rsqrt(var+eps), B = beta - mu*A.
// st layout: [0..255]=sum, [256..511]=sumsq, [512..767]=A, [768..1023]=B.
__global__ __launch_bounds__(256)
void k_bnab(float* __restrict__ st, const float* __restrict__ g,
            const float* __restrict__ b)
{
    const int c = threadIdx.x;
    const float inv = 1.f / (float)NN;
    const float mu  = st[c] * inv;
    const float var = st[256 + c] * inv - mu * mu;
    const float A   = g[c] * rsqrtf(var + BN_EPS);
    st[512 + c] = A;
    st[768 + c] = b[c] - mu * A;
}

// ===========================================================================
// FUSED edge-MLP + aggregation.  One block owns nodes [nb[b], nb[b+1]) and
// their contiguous CSR edge range [e0, e1), e1-e0 <= 128.
// Phase 1: MFMA  msg[e][c] = (ea_bf[e] @ Wte + be)  -> LDS (bf16, same
//          rounding as the old emsg path).
// Phase 2: per node (wave-strided), lanes = channels:
//          agg[n] = fold(x[n]) + sum_e relu(fold(x[src_e]) + msg[e]).
// ===========================================================================
template<typename XT, int CIN, bool FOLD>
__global__ __launch_bounds__(256)
void fused_agg(const XT* __restrict__ x, const bf16* __restrict__ ea_bf,
               const bf16* __restrict__ Wte, const float* __restrict__ be,
               const int* __restrict__ src_perm, const int* __restrict__ row_ptr,
               const int* __restrict__ nb, const float* __restrict__ st,
               bf16* __restrict__ agg)
{
    constexpr int MSTR  = CIN + 8;                 // msg LDS row stride (bf16)
    constexpr int NPASS = (CIN == 256) ? 2 : 1;    // 64-row MFMA passes
    constexpr int CPL   = CIN / 64;                // channels per lane (2 or 4)
    __shared__ short ea_s[128 * 32];               // 8 KB
    __shared__ short msg[128 * MSTR];              // 67.6 KB (256) / 34 KB (128)

    const int tid  = threadIdx.x;
    const int lane = tid & 63;
    const int wv   = tid >> 6;
    const int b    = blockIdx.x;
    const int n0 = nb[b], n1 = nb[b + 1];
    if (n0 >= n1) return;                          // empty block (uniform)
    const int e0 = row_ptr[n0];
    const int e1 = row_ptr[n1];
    int ne = e1 - e0; if (ne > 128) ne = 128;      // insurance clamp

    const int l15  = lane & 15;
    const int quad = lane >> 4;
    const int rsub = lane >> 2;
    const int part = lane & 3;

    // ---- stage ea rows [e0, e0+ne) -> LDS (8 KB, 2 gld16 issues/thread) ----
    #pragma unroll
    for (int i = 0; i < 2; ++i) {
        const int c = i * 4 + wv;                  // 16-row chunk id (0..7)
        int r = c * 16 + rsub;
        if (r >= ne) r = (ne > 0) ? ne - 1 : 0;
        size_t gr = (size_t)(e0 + r); if (gr >= NE) gr = NE - 1;
        gld16(&ea_bf[gr * 32 + part * 8], &ea_s[c * 512]);
    }

    // ---- Wte fragments + bias for this wave's column strip (registers) ----
    const int wc = (CIN == 256) ? wv * 64 : (wv & 1) * 64;
    bf16x8 bfr[4];
    #pragma unroll
    for (int i = 0; i < 4; ++i)
        bfr[i] = *(const bf16x8*)&Wte[(size_t)(wc + i * 16 + l15) * 32 + quad * 8];
    float bv[4];
    #pragma unroll
    for (int ni = 0; ni < 4; ++ni)
        bv[ni] = be[wc + ni * 16 + l15];

    __syncthreads();                               // ea staged

    // ---- phase 1: MFMA edge-MLP -> msg LDS ----
    #pragma unroll
    for (int p = 0; p < NPASS; ++p) {
        const int wr = (CIN == 256) ? p * 64 : (wv >> 1) * 64;
        f32x4 acc[4][4];
        #pragma unroll
        for (int i = 0; i < 4; ++i)
            #pragma unroll
            for (int j = 0; j < 4; ++j)
                acc[i][j] = (f32x4){0.f, 0.f, 0.f, 0.f};
        bf16x8 af[4];
        #pragma unroll
        for (int i = 0; i < 4; ++i)
            af[i] = *(const bf16x8*)&ea_s[(wr + i * 16 + l15) * 32 + quad * 8];
        #pragma unroll
        for (int mi = 0; mi < 4; ++mi)
            #pragma unroll
            for (int ni = 0; ni < 4; ++ni)
                acc[mi][ni] = __builtin_amdgcn_mfma_f32_16x16x32_bf16(
                                  af[mi], bfr[ni], acc[mi][ni], 0, 0, 0);
        #pragma unroll
        for (int mi = 0; mi < 4; ++mi) {
            const int row0 = wr + mi * 16 + quad * 4;
            #pragma unroll
            for (int r = 0; r < 4; ++r) {
                const int row = row0 + r;
                #pragma unroll
                for (int ni = 0; ni < 4; ++ni) {
                    const float v = acc[mi][ni][r] + bv[ni];
                    msg[row * MSTR + wc + ni * 16 + l15] = (short)__bfloat16_as_ushort(__float2bfloat16(v));
                }
            }
        }
    }
    __syncthreads();                               // msg ready

    // ---- phase 2: node-major aggregation ----
    const int c0 = lane * CPL;
    float Af[CPL], Bf[CPL];
    #pragma unroll
    for (int q = 0; q < CPL; ++q) {
        Af[q] = FOLD ? st[512 + c0 + q] : 1.f;
        Bf[q] = FOLD ? st[768 + c0 + q] : 0.f;
    }

    for (int ni = wv; ni < n1 - n0; ni += 4) {
        const int node = n0 + ni;
        float acc2[CPL];
        if constexpr (CPL == 4) {
            const float4 v = ld4(&x[(size_t)node * CIN + c0]);
            acc2[0] = fmaf(v.x, Af[0], Bf[0]); acc2[1] = fmaf(v.y, Af[1], Bf[1]);
            acc2[2] = fmaf(v.z, Af[2], Bf[2]); acc2[3] = fmaf(v.w, Af[3], Bf[3]);
        } else {
            const float2 v = ld2f(&x[(size_t)node * CIN + c0]);
            acc2[0] = fmaf(v.x, Af[0], Bf[0]);
            acc2[CPL - 1] = fmaf(v.y, Af[CPL - 1], Bf[CPL - 1]);
        }

        const int f0 = row_ptr[node], f1 = row_ptr[node + 1];
        for (int base2 = f0; base2 < f1; base2 += 4) {
            int ss[4], li[4];
            #pragma unroll
            for (int j = 0; j < 4; ++j) {
                int idx = base2 + j; if (idx >= f1) idx = f1 - 1;
                ss[j] = src_perm[idx];
                int l = idx - e0; if (l > 127) l = 127;    // insurance
                li[j] = l;
            }
            if constexpr (CPL == 4) {
                float4 xv[4]; ushort4 mv[4];
                #pragma unroll
                for (int j = 0; j < 4; ++j) {
                    xv[j] = ld4(&x[(size_t)ss[j] * CIN + c0]);
                    mv[j] = *(const ushort4*)&msg[li[j] * MSTR + c0];
                }
                #pragma unroll
                for (int j = 0; j < 4; ++j) {
                    if (base2 + j < f1) {
                        acc2[0] += fmaxf(fmaf(xv[j].x, Af[0], Bf[0]) + bfraw(mv[j].x), 0.f);
                        acc2[1] += fmaxf(fmaf(xv[j].y, Af[1], Bf[1]) + bfraw(mv[j].y), 0.f);
                        acc2[2] += fmaxf(fmaf(xv[j].z, Af[2], Bf[2]) + bfraw(mv[j].z), 0.f);
                        acc2[3] += fmaxf(fmaf(xv[j].w, Af[3], Bf[3]) + bfraw(mv[j].w), 0.f);
                    }
                }
            } else {
                float2 xv[4]; ushort2 mv[4];
                #pragma unroll
                for (int j = 0; j < 4; ++j) {
                    xv[j] = ld2f(&x[(size_t)ss[j] * CIN + c0]);
                    mv[j] = *(const ushort2*)&msg[li[j] * MSTR + c0];
                }
                #pragma unroll
                for (int j = 0; j < 4; ++j) {
                    if (base2 + j < f1) {
                        acc2[0] += fmaxf(fmaf(xv[j].x, Af[0], Bf[0]) + bfraw(mv[j].x), 0.f);
                        acc2[CPL - 1] += fmaxf(fmaf(xv[j].y, Af[CPL - 1], Bf[CPL - 1])
                                               + bfraw(mv[j].y), 0.f);
                    }
                }
            }
        }

        if constexpr (CPL == 4) {
            union { ushort4 u; bf16 h[4]; } t;
            t.h[0] = __float2bfloat16(acc2[0]); t.h[1] = __float2bfloat16(acc2[1]);
            t.h[2] = __float2bfloat16(acc2[2]); t.h[3] = __float2bfloat16(acc2[3]);
            *(ushort4*)&agg[(size_t)node * CIN + c0] = t.u;
        } else {
            union { ushort2 u; bf16 h[2]; } t;
            t.h[0] = __float2bfloat16(acc2[0]);
            t.h[1] = __float2bfloat16(acc2[CPL - 1]);
            *(ushort2*)&agg[(size_t)node * CIN + c0] = t.u;
        }
    }
}

// ===========================================================================
// Conv MFMA GEMM: C[M,256] = relu(A[M,K] @ Wt[256,K]^T + bias), bf16 out.
// m97-style global_load_lds staging (linear [128][32] LDS, 16 B/lane).
// STATS: per-channel sum/sumsq of post-relu output into st (quad-reduce).
// ===========================================================================
template<int K, bool STATS>
__global__ __launch_bounds__(256, 3)
void gemm_mfma(const bf16* __restrict__ A, const bf16* __restrict__ Wt,
               const float* __restrict__ bias, bf16* __restrict__ C, int M,
               float* __restrict__ st)
{
    __shared__ short As[128 * 32];   // 8 KB, linear
    __shared__ short Bs[128 * 32];
    const int tid  = threadIdx.x;
    const int bm   = blockIdx.y * 128;
    const int bn   = blockIdx.x * 128;      // 0 or 128 (N = 256)
    const int lane = tid & 63;
    const int wave = tid >> 6;
    const int wr   = (wave >> 1) * 64;
    const int wc   = (wave & 1) * 64;
    const int l15  = lane & 15;
    const int quad = lane >> 4;
    const int rsub = lane >> 2;
    const int part = lane & 3;

    f32x4 acc[4][4];
    #pragma unroll
    for (int i = 0; i < 4; ++i)
        #pragma unroll
        for (int j = 0; j < 4; ++j)
            acc[i][j] = (f32x4){0.f, 0.f, 0.f, 0.f};

    for (int k0 = 0; k0 < K; k0 += 32) {
        #pragma unroll
        for (int i = 0; i < 2; ++i) {
            const int ca = wave * 2 + i;
            int ar = bm + ca * 16 + rsub; if (ar >= M) ar = M - 1;
            gld16(&A[(size_t)ar * K + k0 + part * 8], &As[ca * 512]);
            gld16(&Wt[(size_t)(bn + ca * 16 + rsub) * K + k0 + part * 8],
                  &Bs[ca * 512]);
        }
        __syncthreads();

        bf16x8 af[4], bfr[4];
        #pragma unroll
        for (int i = 0; i < 4; ++i) {
            af[i]  = *(const bf16x8*)&As[(wr + i * 16 + l15) * 32 + quad * 8];
            bfr[i] = *(const bf16x8*)&Bs[(wc + i * 16 + l15) * 32 + quad * 8];
        }
        #pragma unroll
        for (int mi = 0; mi < 4; ++mi)
            #pragma unroll
            for (int ni = 0; ni < 4; ++ni)
                acc[mi][ni] = __builtin_amdgcn_mfma_f32_16x16x32_bf16(
                                  af[mi], bfr[ni], acc[mi][ni], 0, 0, 0);
        __syncthreads();
    }

    float bv[4];
    #pragma unroll
    for (int ni = 0; ni < 4; ++ni)
        bv[ni] = bias[bn + wc + ni * 16 + l15];
    float ps[4]  = {0.f, 0.f, 0.f, 0.f};
    float ps2[4] = {0.f, 0.f, 0.f, 0.f};
    #pragma unroll
    for (int mi = 0; mi < 4; ++mi) {
        const int row0 = bm + wr + mi * 16 + quad * 4;
        #pragma unroll
        for (int r = 0; r < 4; ++r) {
            const int row = row0 + r;
            if (row < M) {
                #pragma unroll
                for (int ni = 0; ni < 4; ++ni) {
                    float v = acc[mi][ni][r] + bv[ni];
                    v = fmaxf(v, 0.f);
                    C[(size_t)row * 256 + bn + wc + ni * 16 + l15] = __float2bfloat16(v);
                    if (STATS) { ps[ni] += v; ps2[ni] = fmaf(v, v, ps2[ni]); }
                }
            }
        }
    }
    if (STATS) {
        #pragma unroll
        for (int ni = 0; ni < 4; ++ni) {
            float s = ps[ni], q = ps2[ni];
            s += __shfl_xor(s, 16); s += __shfl_xor(s, 32);
            q += __shfl_xor(q, 16); q += __shfl_xor(q, 32);
            if (quad == 0) {
                const int col = bn + wc + ni * 16 + l15;
                atomicAdd(&st[col], s);
                atomicAdd(&st[256 + col], q);
            }
        }
    }
}

// ---------------------------------------------------------------------------
// fp32 GEMM (dense head only): C = (relu?)(A @ W + bias)
// ---------------------------------------------------------------------------
template<bool RELU, typename InT, typename OutT>
__global__ __launch_bounds__(256)
void gemm_rk(const InT* __restrict__ A, const float* __restrict__ W,
             const float* __restrict__ bias, OutT* __restrict__ C,
             int M, int N, int K)
{
    __shared__ float Asm[16][64];
    __shared__ float Wsm[16][64];
    const int bm = blockIdx.y * 64;
    const int bn = blockIdx.x * 64;
    const int tid = threadIdx.x;
    const int tx = tid & 15, ty = tid >> 4;
    const int ar = tid >> 2, ac = (tid & 3) * 4;
    const int wrr = tid >> 4, wcc = (tid & 15) * 4;

    float acc[4][4] = {};

    for (int k0 = 0; k0 < K; k0 += 16) {
        float4 av = make_float4(0.f, 0.f, 0.f, 0.f);
        if (bm + ar < M)
            av = ld4(A + (size_t)(bm + ar) * K + k0 + ac);
        Asm[ac + 0][ar] = av.x; Asm[ac + 1][ar] = av.y;
        Asm[ac + 2][ar] = av.z; Asm[ac + 3][ar] = av.w;

        float4 wv = make_float4(0.f, 0.f, 0.f, 0.f);
        if (bn + wcc < N)
            wv = *(const float4*)(W + (size_t)(k0 + wrr) * N + bn + wcc);
        *(float4*)&Wsm[wrr][wcc] = wv;
        __syncthreads();

        #pragma unroll
        for (int k = 0; k < 16; ++k) {
            const float4 a4 = *(const float4*)&Asm[k][ty * 4];
            const float4 b4 = *(const float4*)&Wsm[k][tx * 4];
            const float aa[4] = {a4.x, a4.y, a4.z, a4.w};
            const float bb[4] = {b4.x, b4.y, b4.z, b4.w};
            #pragma unroll
            for (int i = 0; i < 4; ++i)
                #pragma unroll
                for (int j = 0; j < 4; ++j)
                    acc[i][j] += aa[i] * bb[j];
        }
        __syncthreads();
    }

    float bvals[4];
    #pragma unroll
    for (int j = 0; j < 4; ++j) {
        const int col = bn + tx * 4 + j;
        bvals[j] = (col < N) ? bias[col] : 0.f;
    }
    #pragma unroll
    for (int i = 0; i < 4; ++i) {
        const int row = bm + ty * 4 + i;
        if (row >= M) continue;
        float v[4];
        #pragma unroll
        for (int j = 0; j < 4; ++j) {
            v[j] = acc[i][j] + bvals[j];
            if (RELU) v[j] = fmaxf(v[j], 0.f);
        }
        if (bn + tx * 4 + 3 < N) {
            st4(C + (size_t)row * N + bn + tx * 4, make_float4(v[0], v[1], v[2], v[3]));
        } else {
            #pragma unroll
            for (int j = 0; j < 4; ++j) {
                const int col = bn + tx * 4 + j;
                if (col < N) st1(C + (size_t)row * N + col, v[j]);
            }
        }
    }
}

// ---------------------------------------------------------------------------
// Mean-pool over sorted batch ids, with BN fold applied on the fly.
// ---------------------------------------------------------------------------
template<typename InT, bool FOLD>
__global__ __launch_bounds__(256)
void pool_sum(const InT* __restrict__ h, const int* __restrict__ batch,
              const float* __restrict__ st,
              float* __restrict__ sums, float* __restrict__ cnts)
{
    const int c = threadIdx.x;
    size_t n0 = (size_t)blockIdx.x * 128;
    size_t n1 = n0 + 128; if (n1 > (size_t)NN) n1 = NN;
    if (n0 >= (size_t)NN) return;
    const float A = FOLD ? st[512 + c] : 1.f;
    const float B = FOLD ? st[768 + c] : 0.f;
    int cur = batch[n0];
    float s = 0.f, cnt = 0.f;
    for (size_t n = n0; n < n1; ++n) {
        const int b = batch[n];
        if (b != cur) {
            atomicAdd(&sums[(size_t)cur * 256 + c], s);
            if (c == 0) atomicAdd(&cnts[cur], cnt);
            s = 0.f; cnt = 0.f; cur = b;
        }
        const float v = ld1(&h[n * 256 + c]);
        s += fmaf(v, A, B);
        cnt += 1.f;
    }
    atomicAdd(&sums[(size_t)cur * 256 + c], s);
    if (c == 0) atomicAdd(&cnts[cur], cnt);
}

__global__ __launch_bounds__(256)
void pool_div(float* __restrict__ sums, const float* __restrict__ cnts)
{
    const int i = blockIdx.x * 256 + threadIdx.x;   // NG*256 threads exactly
    const int g = i >> 8;
    sums[i] = sums[i] / fmaxf(cnts[g], 1.f);
}

__global__ __launch_bounds__(256)
void head_out(const float* __restrict__ y, const float* __restrict__ Wo,
              const float* __restrict__ bo, float* __restrict__ out)
{
    const int g = blockIdx.x * 256 + threadIdx.x;
    if (g >= NG) return;
    float s = bo[0];
    #pragma unroll
    for (int k = 0; k < 32; ++k) s += y[g * 32 + k] * Wo[k];
    out[g] = s;
}

__global__ __launch_bounds__(256)
void diag_fill(float* __restrict__ out, int n, float v)
{
    const int i = blockIdx.x * 256 + threadIdx.x;
    if (i < n) out[i] = v;
}

// ---------------------------------------------------------------------------
extern "C" void kernel_launch(void* const* d_in, const int* in_sizes, int n_in,
                              void* d_out, int out_size, void* d_ws, size_t ws_size,
                              hipStream_t stream)
{
    const float* x    = (const float*)d_in[0];
    const int*   ei   = (const int*)d_in[1];
    const int*   batch= (const int*)d_in[2];
    const float* ea   = (const float*)d_in[3];
    const float* We[3] = {(const float*)d_in[4],  (const float*)d_in[10], (const float*)d_in[16]};
    const float* be[3] = {(const float*)d_in[5],  (const float*)d_in[11], (const float*)d_in[17]};
    const float* Wn[3] = {(const float*)d_in[6],  (const float*)d_in[12], (const float*)d_in[18]};
    const float* bnb[3]= {(const float*)d_in[7],  (const float*)d_in[13], (const float*)d_in[19]};
    const float* gm[3] = {(const float*)d_in[8],  (const float*)d_in[14], (const float*)d_in[20]};
    const float* bt[3] = {(const float*)d_in[9],  (const float*)d_in[15], (const float*)d_in[21]};
    const float* Wd0 = (const float*)d_in[22]; const float* bd0 = (const float*)d_in[23];
    const float* Wd1 = (const float*)d_in[24]; const float* bd1 = (const float*)d_in[25];
    const float* Wd2 = (const float*)d_in[26]; const float* bd2 = (const float*)d_in[27];
    const float* Wo  = (const float*)d_in[28]; const float* bo  = (const float*)d_in[29];
    float* out = (float*)d_out;
    float* ws  = (float*)d_ws;

    // ---- workspace layout (float offsets; 16B alignment kept) ----
    constexpr size_t OFF_H    = 0;                            // NN*256 bf16
    constexpr size_t OFF_AGG  = 25600000;                     // NN*256 bf16
    constexpr size_t OFF_ST   = 51200000;                     // 1536 fl
    constexpr size_t OFF_WT0  = OFF_ST + 1536;                // 128*256 bf16
    constexpr size_t OFF_WT1  = OFF_WT0 + 16384;              // 256*256 bf16
    constexpr size_t OFF_WT2  = OFF_WT1 + 32768;              // 256*256 bf16
    constexpr size_t OFF_WTE0 = OFF_WT2 + 32768;              // 128*32 bf16
    constexpr size_t OFF_WTE1 = OFF_WTE0 + 2048;              // 256*32 bf16
    constexpr size_t OFF_WTE2 = OFF_WTE1 + 4096;              // 256*32 bf16
    constexpr size_t OFF_EA   = OFF_WTE2 + 4096;              // NE*32 bf16
    constexpr size_t OFF_SRC  = OFF_EA + 12800000;            // NE int
    constexpr size_t OFF_RP   = OFF_SRC + NE;                 // NN+1 int
    constexpr size_t OFF_CUR  = OFF_RP + (NN + 1);            // NN int
    constexpr size_t OFF_PERM = OFF_CUR + NN;                 // NE int
    constexpr size_t OFF_BSUM = OFF_PERM + NE;                // SCAN_NBLK int
    constexpr size_t OFF_NB   = OFF_BSUM + SCAN_NBLK;         // NB+1 int
    constexpr size_t BASE_END = OFF_NB + (NB + 4);
    constexpr size_t NEED_BASE = BASE_END * 4;

    bf16*  H        = (bf16*)(ws + OFF_H);
    bf16*  AGG      = (bf16*)(ws + OFF_AGG);
    float* st       = ws + OFF_ST;
    bf16*  wt0      = (bf16*)(ws + OFF_WT0);
    bf16*  wt1      = (bf16*)(ws + OFF_WT1);
    bf16*  wt2      = (bf16*)(ws + OFF_WT2);
    bf16*  wte[3]   = {(bf16*)(ws + OFF_WTE0), (bf16*)(ws + OFF_WTE1), (bf16*)(ws + OFF_WTE2)};
    bf16*  ea_bf    = (bf16*)(ws + OFF_EA);
    int*   src_perm = (int*)(ws + OFF_SRC);
    int*   row_ptr  = (int*)(ws + OFF_RP);
    int*   cursor   = (int*)(ws + OFF_CUR);
    int*   perm     = (int*)(ws + OFF_PERM);
    int*   bsum     = (int*)(ws + OFF_BSUM);
    int*   nb       = (int*)(ws + OFF_NB);

    if (ws_size < NEED_BASE) {
        diag_fill<<<(NG + 255) / 256, 256, 0, stream>>>(out, NG, (float)(ws_size >> 20));
        return;
    }

    // ---- one-time prep: CSR build, edge pre-gather, weight transpose ----
    hipMemsetAsync(row_ptr, 0, (size_t)(NN + 1) * 4, stream);
    k_hist<<<1024, 256, 0, stream>>>(ei, row_ptr);
    k_scan_block<<<SCAN_NBLK, 256, 0, stream>>>(row_ptr, bsum);
    k_scan_top<<<1, 256, 0, stream>>>(bsum, SCAN_NBLK);
    k_scan_emit<<<SCAN_NBLK, 256, 0, stream>>>(row_ptr, bsum, row_ptr, cursor);
    k_scatter<<<1024, 256, 0, stream>>>(ei, cursor, perm);
    k_bounds2<<<(NB + 256) / 256, 256, 0, stream>>>(row_ptr, nb);
    k_gather_edges_bf<<<(NE * 16 + 255) / 256, 256, 0, stream>>>(ei, ea, perm, src_perm, ea_bf);
    k_wte<<<(128 * 32 + 255) / 256, 256, 0, stream>>>(We[0], wte[0], 128);
    k_wte<<<(256 * 32 + 255) / 256, 256, 0, stream>>>(We[1], wte[1], 256);
    k_wte<<<(256 * 32 + 255) / 256, 256, 0, stream>>>(We[2], wte[2], 256);
    k_wt<<<(128 * 256 + 255) / 256, 256, 0, stream>>>(Wn[0], wt0, 128, 256);
    k_wt<<<(256 * 256 + 255) / 256, 256, 0, stream>>>(Wn[1], wt1, 256, 256);
    k_wt<<<(256 * 256 + 255) / 256, 256, 0, stream>>>(Wn[2], wt2, 256, 256);

    const dim3 mfma_grid(2, (NN + 127) / 128);    // conv GEMMs: N=256

    // ---- layer 0 (cin=128 -> 256), input x fp32, no fold ----
    fused_agg<float, 128, false><<<NB, 256, 0, stream>>>(
        x, ea_bf, wte[0], be[0], src_perm, row_ptr, nb, st, AGG);
    hipMemsetAsync(st, 0, 512 * 4, stream);
    gemm_mfma<128, true><<<mfma_grid, 256, 0, stream>>>(AGG, wt0, bnb[0], H, NN, st);
    k_bnab<<<1, 256, 0, stream>>>(st, gm[0], bt[0]);

    // ---- layers 1,2 (256 -> 256), input H bf16 raw + fold(A,B) ----
    for (int l = 1; l < 3; ++l) {
        fused_agg<bf16, 256, true><<<NB, 256, 0, stream>>>(
            H, ea_bf, wte[l], be[l], src_perm, row_ptr, nb, st, AGG);
        hipMemsetAsync(st, 0, 512 * 4, stream);
        gemm_mfma<256, true><<<mfma_grid, 256, 0, stream>>>(
            AGG, (l == 1) ? wt1 : wt2, bnb[l], H, NN, st);
        k_bnab<<<1, 256, 0, stream>>>(st, gm[l], bt[l]);
    }

    // ---- head scratch overlays AGG (dead after last conv GEMM) ----
    float* poolb = (float*)AGG;           // NG*256 = 1,024,000 fl
    float* cnts  = poolb + 1024000;       // NG
    float* y1    = poolb + 1028000;       // NG*512
    float* y2    = poolb + 3076000;       // NG*128
    float* y3    = poolb + 3588000;       // NG*32

    hipMemsetAsync(poolb, 0, (size_t)NG * 256 * 4, stream);
    hipMemsetAsync(cnts, 0, (size_t)NG * 4, stream);
    pool_sum<bf16, true><<<(NN + 127) / 128, 256, 0, stream>>>(H, batch, st, poolb, cnts);
    pool_div<<<NG, 256, 0, stream>>>(poolb, cnts);

    // ---- dense head (fp32) ----
    gemm_rk<true, float, float><<<dim3(8, (NG + 63) / 64), 256, 0, stream>>>(poolb, Wd0, bd0, y1, NG, 512, 256);
    gemm_rk<true, float, float><<<dim3(2, (NG + 63) / 64), 256, 0, stream>>>(y1, Wd1, bd1, y2, NG, 128, 512);
    gemm_rk<true, float, float><<<dim3(1, (NG + 63) / 64), 256, 0, stream>>>(y2, Wd2, bd2, y3, NG, 32, 128);
    head_out<<<(NG + 255) / 256, 256, 0, stream>>>(y3, Wo, bo, out);
}

// Round 6
// 1477.720 us; speedup vs baseline: 1.5020x; 1.1167x over previous
//
#include <hip/hip_runtime.h>
#include <hip/hip_bf16.h>

using bf16 = __hip_bfloat16;
typedef __attribute__((ext_vector_type(8))) short bf16x8;   // 8 bf16 (4 VGPRs)
typedef __attribute__((ext_vector_type(4))) float f32x4;    // MFMA accumulator

constexpr int NN = 200000;   // nodes
constexpr int NE = 800000;   // edges
constexpr int NG = 4000;     // graphs
constexpr int ED = 16;       // edge feature dim
constexpr float BN_EPS = 1e-5f;

constexpr int WSTEP = 88;                              // block weight step
constexpr int NB    = (NE + NN + WSTEP - 1) / WSTEP;   // 11364 fused blocks

// ---------------- storage-type helpers (fp32 or bf16 node features) --------
__device__ __forceinline__ float  ld1(const float* p) { return *p; }
__device__ __forceinline__ float  ld1(const bf16*  p) { return __bfloat162float(*p); }
__device__ __forceinline__ float2 ld2f(const float* p) { return *(const float2*)p; }
__device__ __forceinline__ float2 ld2f(const bf16*  p) {
    union { ushort2 u; bf16 h[2]; } t;
    t.u = *(const ushort2*)p;
    return make_float2(__bfloat162float(t.h[0]), __bfloat162float(t.h[1]));
}
__device__ __forceinline__ float4 ld4(const float* p) { return *(const float4*)p; }
__device__ __forceinline__ float4 ld4(const bf16*  p) {
    union { ushort4 u; bf16 h[4]; } t;
    t.u = *(const ushort4*)p;
    return make_float4(__bfloat162float(t.h[0]), __bfloat162float(t.h[1]),
                       __bfloat162float(t.h[2]), __bfloat162float(t.h[3]));
}
__device__ __forceinline__ void st1(float* p, float v) { *p = v; }
__device__ __forceinline__ void st1(bf16*  p, float v) { *p = __float2bfloat16(v); }
__device__ __forceinline__ void st4(float* p, float4 v) { *(float4*)p = v; }
__device__ __forceinline__ void st4(bf16*  p, float4 v) {
    union { ushort4 u; bf16 h[4]; } t;
    t.h[0] = __float2bfloat16(v.x); t.h[1] = __float2bfloat16(v.y);
    t.h[2] = __float2bfloat16(v.z); t.h[3] = __float2bfloat16(v.w);
    *(ushort4*)p = t.u;
}
__device__ __forceinline__ float bfraw(unsigned short u) {
    union { unsigned short s; bf16 h; } t; t.s = u;
    return __bfloat162float(t.h);
}

// async global -> LDS, 16 B per lane (m97 pattern). LDS dest must be the
// wave-uniform chunk base; HW adds lane*16.
__device__ __forceinline__ void gld16(const void* g, void* l)
{
    __builtin_amdgcn_global_load_lds(
        (const __attribute__((address_space(1))) void*)g,
        (__attribute__((address_space(3))) void*)l, 16, 0, 0);
}

// ===========================================================================
// CSR-by-dst build (once per call; reused by all 3 conv layers)
// ===========================================================================
constexpr int SCAN_CHUNK = 1024;
constexpr int SCAN_NBLK  = (NN + SCAN_CHUNK - 1) / SCAN_CHUNK;   // 196

__global__ __launch_bounds__(256)
void k_hist(const int* __restrict__ ei, int* __restrict__ cnt)
{
    int e = blockIdx.x * 256 + threadIdx.x;
    const int stride = gridDim.x * 256;
    for (; e < NE; e += stride) atomicAdd(&cnt[ei[NE + e]], 1);
}

__global__ __launch_bounds__(256)
void k_scan_block(const int* __restrict__ cnt, int* __restrict__ bsum)
{
    __shared__ int red[256];
    const int b = blockIdx.x, t = threadIdx.x;
    const int base = b * SCAN_CHUNK + t * 4;
    int s = 0;
    #pragma unroll
    for (int k = 0; k < 4; ++k) { const int i = base + k; if (i < NN) s += cnt[i]; }
    red[t] = s; __syncthreads();
    for (int off = 128; off > 0; off >>= 1) {
        if (t < off) red[t] += red[t + off];
        __syncthreads();
    }
    if (t == 0) bsum[b] = red[0];
}

__global__ __launch_bounds__(256)
void k_scan_top(int* __restrict__ bsum, int n)
{
    __shared__ int sh[256];
    const int t = threadIdx.x;
    const int orig = (t < n) ? bsum[t] : 0;
    sh[t] = orig; __syncthreads();
    for (int off = 1; off < 256; off <<= 1) {
        const int v = (t >= off) ? sh[t - off] : 0;
        __syncthreads();
        sh[t] += v;
        __syncthreads();
    }
    if (t < n) bsum[t] = sh[t] - orig;   // exclusive
}

__global__ __launch_bounds__(256)
void k_scan_emit(const int* __restrict__ cnt, const int* __restrict__ bsum,
                 int* __restrict__ row_ptr, int* __restrict__ cursor)
{
    __shared__ int sh[256];
    const int b = blockIdx.x, t = threadIdx.x;
    const int base = b * SCAN_CHUNK + t * 4;
    int c[4]; int s = 0;
    #pragma unroll
    for (int k = 0; k < 4; ++k) {
        const int i = base + k;
        c[k] = (i < NN) ? cnt[i] : 0;    // read BEFORE aliased write below
        s += c[k];
    }
    const int orig = s;
    sh[t] = s; __syncthreads();
    for (int off = 1; off < 256; off <<= 1) {
        const int v = (t >= off) ? sh[t - off] : 0;
        __syncthreads();
        sh[t] += v;
        __syncthreads();
    }
    int run = bsum[b] + sh[t] - orig;     // exclusive prefix of this thread
    #pragma unroll
    for (int k = 0; k < 4; ++k) {
        const int i = base + k;
        if (i < NN) { row_ptr[i] = run; cursor[i] = run; run += c[k]; }
    }
    if (b == 0 && t == 0) row_ptr[NN] = NE;
}

__global__ __launch_bounds__(256)
void k_scatter(const int* __restrict__ ei, int* __restrict__ cursor,
               int* __restrict__ perm)
{
    int e = blockIdx.x * 256 + threadIdx.x;
    const int stride = gridDim.x * 256;
    for (; e < NE; e += stride) {
        const int d = ei[NE + e];
        const int p = atomicAdd(&cursor[d], 1);
        perm[p] = e;
    }
}

// Fused-block boundaries: nb[t] = first node of block t, by binary search on
// W(n) = row_ptr[n] + n with target t*(NE+NN)/NB.  Block weight <= step +
// max node weight (~20 here) <= 128, so edges/block <= 128 and nodes/block
// <= 128 (both clamped in the consumer as insurance).
__global__ __launch_bounds__(256)
void k_bounds2(const int* __restrict__ row_ptr, int* __restrict__ nb)
{
    const int t = blockIdx.x * 256 + threadIdx.x;
    if (t > NB) return;
    const long long target = (long long)t * (NE + NN) / NB;
    int lo = 0, hi = NN;
    while (lo < hi) {
        const int mid = (lo + hi) >> 1;
        const long long W = (long long)row_ptr[mid] + mid;
        if (W >= target) hi = mid; else lo = mid + 1;
    }
    nb[t] = lo;
}

// Edge features as bf16 [NE,32] in perm order, zero-padded K 16->32.
__global__ __launch_bounds__(256)
void k_gather_edges_bf(const int* __restrict__ ei, const float* __restrict__ ea,
                       const int* __restrict__ perm, int* __restrict__ src_perm,
                       bf16* __restrict__ ea_bf)
{
    const int t = blockIdx.x * 256 + threadIdx.x;    // over NE*16 (2 bf16 each)
    if (t >= NE * 16) return;
    const int idx = t >> 4, k2 = (t & 15) * 2;       // k2 in 0..30
    const int e = perm[idx];
    union { ushort2 u; bf16 h[2]; } o;
    if (k2 < ED) {
        const float2 v = *(const float2*)&ea[(size_t)e * ED + k2];
        o.h[0] = __float2bfloat16(v.x);
        o.h[1] = __float2bfloat16(v.y);
    } else {
        o.u = make_ushort2(0, 0);
    }
    *(ushort2*)&ea_bf[(size_t)idx * 32 + k2] = o.u;
    if ((t & 15) == 0) src_perm[idx] = ei[e];
}

// One-shot: W[K,N] fp32 -> Wt[N,K] bf16 (transposed for the MFMA GEMM).
__global__ __launch_bounds__(256)
void k_wt(const float* __restrict__ W, bf16* __restrict__ Wt, int K, int N)
{
    const int i = blockIdx.x * 256 + threadIdx.x;
    if (i >= K * N) return;
    const int k = i / N, n = i % N;
    Wt[(size_t)n * K + k] = __float2bfloat16(W[i]);
}

// One-shot: We[16,cin] fp32 -> Wte[cin,32] bf16, K zero-padded 16->32.
__global__ __launch_bounds__(256)
void k_wte(const float* __restrict__ We, bf16* __restrict__ Wte, int cin)
{
    const int i = blockIdx.x * 256 + threadIdx.x;    // over cin*32
    if (i >= cin * 32) return;
    const int n = i >> 5, k = i & 31;
    Wte[i] = __float2bfloat16((k < ED) ? We[k * cin + n] : 0.f);
}

// BN fold coefficients: A = g*rsqrt(var+eps), B = beta - mu*A.
// st layout: [0..255]=sum, [256..511]=sumsq, [512..767]=A, [768..1023]=B.
__global__ __launch_bounds__(256)
void k_bnab(float* __restrict__ st, const float* __restrict__ g,
            const float* __restrict__ b)
{
    const int c = threadIdx.x;
    const float inv = 1.f / (float)NN;
    const float mu  = st[c] * inv;
    const float var = st[256 + c] * inv - mu * mu;
    const float A   = g[c] * rsqrtf(var + BN_EPS);
    st[512 + c] = A;
    st[768 + c] = b[c] - mu * A;
}

// ===========================================================================
// FUSED edge-MLP + aggregation, CIN=128 (layer 0), 256 threads / 4 waves.
// Verified round-5 structure.
// ===========================================================================
template<typename XT, bool FOLD>
__global__ __launch_bounds__(256)
void fused_agg128(const XT* __restrict__ x, const bf16* __restrict__ ea_bf,
                  const bf16* __restrict__ Wte, const float* __restrict__ be,
                  const int* __restrict__ src_perm, const int* __restrict__ row_ptr,
                  const int* __restrict__ nb, const float* __restrict__ st,
                  bf16* __restrict__ agg)
{
    constexpr int CIN  = 128;
    constexpr int MSTR = CIN + 8;                  // msg LDS row stride (bf16)
    constexpr int CPL  = 2;                        // channels per lane
    __shared__ short ea_s[128 * 32];               // 8 KB
    __shared__ short msg[128 * MSTR];              // 34 KB

    const int tid  = threadIdx.x;
    const int lane = tid & 63;
    const int wv   = tid >> 6;
    const int b    = blockIdx.x;
    const int n0 = nb[b], n1 = nb[b + 1];
    if (n0 >= n1) return;
    const int e0 = row_ptr[n0];
    const int e1 = row_ptr[n1];
    int ne = e1 - e0; if (ne > 128) ne = 128;      // insurance clamp

    const int l15  = lane & 15;
    const int quad = lane >> 4;
    const int rsub = lane >> 2;
    const int part = lane & 3;

    #pragma unroll
    for (int i = 0; i < 2; ++i) {
        const int c = i * 4 + wv;                  // 16-row chunk id (0..7)
        int r = c * 16 + rsub;
        if (r >= ne) r = (ne > 0) ? ne - 1 : 0;
        size_t gr = (size_t)(e0 + r); if (gr >= NE) gr = NE - 1;
        gld16(&ea_bf[gr * 32 + part * 8], &ea_s[c * 512]);
    }

    const int wc = (wv & 1) * 64;
    const int wr = (wv >> 1) * 64;
    bf16x8 bfr[4];
    #pragma unroll
    for (int i = 0; i < 4; ++i)
        bfr[i] = *(const bf16x8*)&Wte[(size_t)(wc + i * 16 + l15) * 32 + quad * 8];
    float bv[4];
    #pragma unroll
    for (int ni = 0; ni < 4; ++ni)
        bv[ni] = be[wc + ni * 16 + l15];

    __syncthreads();

    {
        f32x4 acc[4][4];
        #pragma unroll
        for (int i = 0; i < 4; ++i)
            #pragma unroll
            for (int j = 0; j < 4; ++j)
                acc[i][j] = (f32x4){0.f, 0.f, 0.f, 0.f};
        bf16x8 af[4];
        #pragma unroll
        for (int i = 0; i < 4; ++i)
            af[i] = *(const bf16x8*)&ea_s[(wr + i * 16 + l15) * 32 + quad * 8];
        #pragma unroll
        for (int mi = 0; mi < 4; ++mi)
            #pragma unroll
            for (int ni = 0; ni < 4; ++ni)
                acc[mi][ni] = __builtin_amdgcn_mfma_f32_16x16x32_bf16(
                                  af[mi], bfr[ni], acc[mi][ni], 0, 0, 0);
        #pragma unroll
        for (int mi = 0; mi < 4; ++mi) {
            const int row0 = wr + mi * 16 + quad * 4;
            #pragma unroll
            for (int r = 0; r < 4; ++r) {
                const int row = row0 + r;
                #pragma unroll
                for (int ni = 0; ni < 4; ++ni) {
                    const float v = acc[mi][ni][r] + bv[ni];
                    msg[row * MSTR + wc + ni * 16 + l15] =
                        (short)__bfloat16_as_ushort(__float2bfloat16(v));
                }
            }
        }
    }
    __syncthreads();

    const int c0 = lane * CPL;
    float Af[CPL], Bf[CPL];
    #pragma unroll
    for (int q = 0; q < CPL; ++q) {
        Af[q] = FOLD ? st[512 + c0 + q] : 1.f;
        Bf[q] = FOLD ? st[768 + c0 + q] : 0.f;
    }

    for (int ni = wv; ni < n1 - n0; ni += 4) {
        const int node = n0 + ni;
        float acc2[CPL];
        const float2 v = ld2f(&x[(size_t)node * CIN + c0]);
        acc2[0] = fmaf(v.x, Af[0], Bf[0]);
        acc2[1] = fmaf(v.y, Af[1], Bf[1]);

        const int f0 = row_ptr[node], f1 = row_ptr[node + 1];
        for (int base2 = f0; base2 < f1; base2 += 4) {
            int ss[4], li[4];
            #pragma unroll
            for (int j = 0; j < 4; ++j) {
                int idx = base2 + j; if (idx >= f1) idx = f1 - 1;
                ss[j] = src_perm[idx];
                int l = idx - e0; if (l > 127) l = 127;
                li[j] = l;
            }
            float2 xv[4]; ushort2 mv[4];
            #pragma unroll
            for (int j = 0; j < 4; ++j) {
                xv[j] = ld2f(&x[(size_t)ss[j] * CIN + c0]);
                mv[j] = *(const ushort2*)&msg[li[j] * MSTR + c0];
            }
            #pragma unroll
            for (int j = 0; j < 4; ++j) {
                if (base2 + j < f1) {
                    acc2[0] += fmaxf(fmaf(xv[j].x, Af[0], Bf[0]) + bfraw(mv[j].x), 0.f);
                    acc2[1] += fmaxf(fmaf(xv[j].y, Af[1], Bf[1]) + bfraw(mv[j].y), 0.f);
                }
            }
        }

        union { ushort2 u; bf16 h[2]; } t;
        t.h[0] = __float2bfloat16(acc2[0]);
        t.h[1] = __float2bfloat16(acc2[1]);
        *(ushort2*)&agg[(size_t)node * CIN + c0] = t.u;
    }
}

// ===========================================================================
// FUSED edge-MLP + aggregation, CIN=256: 512 threads / 8 waves.
// Same LDS footprint as the 4-wave version (75.7 KB -> 2 blocks/CU) but
// 16 waves/CU instead of 8 -> doubles latency hiding for the phase-2 gather.
// Phase 1: 8 waves = 2x4 quadrants of the 128x256 MFMA tile (single pass).
// Phase 2: nodes strided by 8 waves, lanes = 4 channels each.
// ===========================================================================
template<typename XT, bool FOLD>
__global__ __launch_bounds__(512)
void fused_agg256(const XT* __restrict__ x, const bf16* __restrict__ ea_bf,
                  const bf16* __restrict__ Wte, const float* __restrict__ be,
                  const int* __restrict__ src_perm, const int* __restrict__ row_ptr,
                  const int* __restrict__ nb, const float* __restrict__ st,
                  bf16* __restrict__ agg)
{
    constexpr int CIN  = 256;
    constexpr int MSTR = CIN + 8;                  // msg LDS row stride (bf16)
    constexpr int CPL  = 4;
    __shared__ short ea_s[128 * 32];               // 8 KB
    __shared__ short msg[128 * MSTR];              // 66 KB

    const int tid  = threadIdx.x;
    const int lane = tid & 63;
    const int wv   = tid >> 6;                     // 0..7
    const int b    = blockIdx.x;
    const int n0 = nb[b], n1 = nb[b + 1];
    if (n0 >= n1) return;
    const int e0 = row_ptr[n0];
    const int e1 = row_ptr[n1];
    int ne = e1 - e0; if (ne > 128) ne = 128;      // insurance clamp

    const int l15  = lane & 15;
    const int quad = lane >> 4;
    const int rsub = lane >> 2;
    const int part = lane & 3;

    // ---- stage ea rows: 8 waves x 16 rows, 1 gld16 per thread ----
    {
        int r = wv * 16 + rsub;
        if (r >= ne) r = (ne > 0) ? ne - 1 : 0;
        size_t gr = (size_t)(e0 + r); if (gr >= NE) gr = NE - 1;
        gld16(&ea_bf[gr * 32 + part * 8], &ea_s[wv * 512]);
    }

    // ---- Wte fragments + bias: wave quadrant (wr, wc) of 128x256 ----
    const int wc = (wv & 3) * 64;
    const int wr = (wv >> 2) * 64;
    bf16x8 bfr[4];
    #pragma unroll
    for (int i = 0; i < 4; ++i)
        bfr[i] = *(const bf16x8*)&Wte[(size_t)(wc + i * 16 + l15) * 32 + quad * 8];
    float bv[4];
    #pragma unroll
    for (int ni = 0; ni < 4; ++ni)
        bv[ni] = be[wc + ni * 16 + l15];

    __syncthreads();                               // ea staged

    // ---- phase 1: MFMA edge-MLP -> msg LDS (single pass, 8 quadrants) ----
    {
        f32x4 acc[4][4];
        #pragma unroll
        for (int i = 0; i < 4; ++i)
            #pragma unroll
            for (int j = 0; j < 4; ++j)
                acc[i][j] = (f32x4){0.f, 0.f, 0.f, 0.f};
        bf16x8 af[4];
        #pragma unroll
        for (int i = 0; i < 4; ++i)
            af[i] = *(const bf16x8*)&ea_s[(wr + i * 16 + l15) * 32 + quad * 8];
        #pragma unroll
        for (int mi = 0; mi < 4; ++mi)
            #pragma unroll
            for (int ni = 0; ni < 4; ++ni)
                acc[mi][ni] = __builtin_amdgcn_mfma_f32_16x16x32_bf16(
                                  af[mi], bfr[ni], acc[mi][ni], 0, 0, 0);
        #pragma unroll
        for (int mi = 0; mi < 4; ++mi) {
            const int row0 = wr + mi * 16 + quad * 4;
            #pragma unroll
            for (int r = 0; r < 4; ++r) {
                const int row = row0 + r;
                #pragma unroll
                for (int ni = 0; ni < 4; ++ni) {
                    const float v = acc[mi][ni][r] + bv[ni];
                    msg[row * MSTR + wc + ni * 16 + l15] =
                        (short)__bfloat16_as_ushort(__float2bfloat16(v));
                }
            }
        }
    }
    __syncthreads();                               // msg ready

    // ---- phase 2: node-major aggregation, 8-wave stride ----
    const int c0 = lane * CPL;
    float Af[CPL], Bf[CPL];
    #pragma unroll
    for (int q = 0; q < CPL; ++q) {
        Af[q] = FOLD ? st[512 + c0 + q] : 1.f;
        Bf[q] = FOLD ? st[768 + c0 + q] : 0.f;
    }

    for (int ni = wv; ni < n1 - n0; ni += 8) {
        const int node = n0 + ni;
        float acc2[CPL];
        const float4 v = ld4(&x[(size_t)node * CIN + c0]);
        acc2[0] = fmaf(v.x, Af[0], Bf[0]); acc2[1] = fmaf(v.y, Af[1], Bf[1]);
        acc2[2] = fmaf(v.z, Af[2], Bf[2]); acc2[3] = fmaf(v.w, Af[3], Bf[3]);

        const int f0 = row_ptr[node], f1 = row_ptr[node + 1];
        for (int base2 = f0; base2 < f1; base2 += 4) {
            int ss[4], li[4];
            #pragma unroll
            for (int j = 0; j < 4; ++j) {
                int idx = base2 + j; if (idx >= f1) idx = f1 - 1;
                ss[j] = src_perm[idx];
                int l = idx - e0; if (l > 127) l = 127;
                li[j] = l;
            }
            float4 xv[4]; ushort4 mv[4];
            #pragma unroll
            for (int j = 0; j < 4; ++j) {
                xv[j] = ld4(&x[(size_t)ss[j] * CIN + c0]);
                mv[j] = *(const ushort4*)&msg[li[j] * MSTR + c0];
            }
            #pragma unroll
            for (int j = 0; j < 4; ++j) {
                if (base2 + j < f1) {
                    acc2[0] += fmaxf(fmaf(xv[j].x, Af[0], Bf[0]) + bfraw(mv[j].x), 0.f);
                    acc2[1] += fmaxf(fmaf(xv[j].y, Af[1], Bf[1]) + bfraw(mv[j].y), 0.f);
                    acc2[2] += fmaxf(fmaf(xv[j].z, Af[2], Bf[2]) + bfraw(mv[j].z), 0.f);
                    acc2[3] += fmaxf(fmaf(xv[j].w, Af[3], Bf[3]) + bfraw(mv[j].w), 0.f);
                }
            }
        }

        union { ushort4 u; bf16 h[4]; } t;
        t.h[0] = __float2bfloat16(acc2[0]); t.h[1] = __float2bfloat16(acc2[1]);
        t.h[2] = __float2bfloat16(acc2[2]); t.h[3] = __float2bfloat16(acc2[3]);
        *(ushort4*)&agg[(size_t)node * CIN + c0] = t.u;
    }
}

// ===========================================================================
// Conv MFMA GEMM: C[M,256] = relu(A[M,K] @ Wt[256,K]^T + bias), bf16 out.
// m97-style global_load_lds staging (linear [128][32] LDS, 16 B/lane).
// STATS: per-channel sum/sumsq of post-relu output into st (quad-reduce).
// ===========================================================================
template<int K, bool STATS>
__global__ __launch_bounds__(256, 3)
void gemm_mfma(const bf16* __restrict__ A, const bf16* __restrict__ Wt,
               const float* __restrict__ bias, bf16* __restrict__ C, int M,
               float* __restrict__ st)
{
    __shared__ short As[128 * 32];   // 8 KB, linear
    __shared__ short Bs[128 * 32];
    const int tid  = threadIdx.x;
    const int bm   = blockIdx.y * 128;
    const int bn   = blockIdx.x * 128;      // 0 or 128 (N = 256)
    const int lane = tid & 63;
    const int wave = tid >> 6;
    const int wr   = (wave >> 1) * 64;
    const int wc   = (wave & 1) * 64;
    const int l15  = lane & 15;
    const int quad = lane >> 4;
    const int rsub = lane >> 2;
    const int part = lane & 3;

    f32x4 acc[4][4];
    #pragma unroll
    for (int i = 0; i < 4; ++i)
        #pragma unroll
        for (int j = 0; j < 4; ++j)
            acc[i][j] = (f32x4){0.f, 0.f, 0.f, 0.f};

    for (int k0 = 0; k0 < K; k0 += 32) {
        #pragma unroll
        for (int i = 0; i < 2; ++i) {
            const int ca = wave * 2 + i;
            int ar = bm + ca * 16 + rsub; if (ar >= M) ar = M - 1;
            gld16(&A[(size_t)ar * K + k0 + part * 8], &As[ca * 512]);
            gld16(&Wt[(size_t)(bn + ca * 16 + rsub) * K + k0 + part * 8],
                  &Bs[ca * 512]);
        }
        __syncthreads();

        bf16x8 af[4], bfr[4];
        #pragma unroll
        for (int i = 0; i < 4; ++i) {
            af[i]  = *(const bf16x8*)&As[(wr + i * 16 + l15) * 32 + quad * 8];
            bfr[i] = *(const bf16x8*)&Bs[(wc + i * 16 + l15) * 32 + quad * 8];
        }
        #pragma unroll
        for (int mi = 0; mi < 4; ++mi)
            #pragma unroll
            for (int ni = 0; ni < 4; ++ni)
                acc[mi][ni] = __builtin_amdgcn_mfma_f32_16x16x32_bf16(
                                  af[mi], bfr[ni], acc[mi][ni], 0, 0, 0);
        __syncthreads();
    }

    float bv[4];
    #pragma unroll
    for (int ni = 0; ni < 4; ++ni)
        bv[ni] = bias[bn + wc + ni * 16 + l15];
    float ps[4]  = {0.f, 0.f, 0.f, 0.f};
    float ps2[4] = {0.f, 0.f, 0.f, 0.f};
    #pragma unroll
    for (int mi = 0; mi < 4; ++mi) {
        const int row0 = bm + wr + mi * 16 + quad * 4;
        #pragma unroll
        for (int r = 0; r < 4; ++r) {
            const int row = row0 + r;
            if (row < M) {
                #pragma unroll
                for (int ni = 0; ni < 4; ++ni) {
                    float v = acc[mi][ni][r] + bv[ni];
                    v = fmaxf(v, 0.f);
                    C[(size_t)row * 256 + bn + wc + ni * 16 + l15] = __float2bfloat16(v);
                    if (STATS) { ps[ni] += v; ps2[ni] = fmaf(v, v, ps2[ni]); }
                }
            }
        }
    }
    if (STATS) {
        #pragma unroll
        for (int ni = 0; ni < 4; ++ni) {
            float s = ps[ni], q = ps2[ni];
            s += __shfl_xor(s, 16); s += __shfl_xor(s, 32);
            q += __shfl_xor(q, 16); q += __shfl_xor(q, 32);
            if (quad == 0) {
                const int col = bn + wc + ni * 16 + l15;
                atomicAdd(&st[col], s);
                atomicAdd(&st[256 + col], q);
            }
        }
    }
}

// ---------------------------------------------------------------------------
// fp32 GEMM (dense head only): C = (relu?)(A @ W + bias)
// ---------------------------------------------------------------------------
template<bool RELU, typename InT, typename OutT>
__global__ __launch_bounds__(256)
void gemm_rk(const InT* __restrict__ A, const float* __restrict__ W,
             const float* __restrict__ bias, OutT* __restrict__ C,
             int M, int N, int K)
{
    __shared__ float Asm[16][64];
    __shared__ float Wsm[16][64];
    const int bm = blockIdx.y * 64;
    const int bn = blockIdx.x * 64;
    const int tid = threadIdx.x;
    const int tx = tid & 15, ty = tid >> 4;
    const int ar = tid >> 2, ac = (tid & 3) * 4;
    const int wrr = tid >> 4, wcc = (tid & 15) * 4;

    float acc[4][4] = {};

    for (int k0 = 0; k0 < K; k0 += 16) {
        float4 av = make_float4(0.f, 0.f, 0.f, 0.f);
        if (bm + ar < M)
            av = ld4(A + (size_t)(bm + ar) * K + k0 + ac);
        Asm[ac + 0][ar] = av.x; Asm[ac + 1][ar] = av.y;
        Asm[ac + 2][ar] = av.z; Asm[ac + 3][ar] = av.w;

        float4 wv = make_float4(0.f, 0.f, 0.f, 0.f);
        if (bn + wcc < N)
            wv = *(const float4*)(W + (size_t)(k0 + wrr) * N + bn + wcc);
        *(float4*)&Wsm[wrr][wcc] = wv;
        __syncthreads();

        #pragma unroll
        for (int k = 0; k < 16; ++k) {
            const float4 a4 = *(const float4*)&Asm[k][ty * 4];
            const float4 b4 = *(const float4*)&Wsm[k][tx * 4];
            const float aa[4] = {a4.x, a4.y, a4.z, a4.w};
            const float bb[4] = {b4.x, b4.y, b4.z, b4.w};
            #pragma unroll
            for (int i = 0; i < 4; ++i)
                #pragma unroll
                for (int j = 0; j < 4; ++j)
                    acc[i][j] += aa[i] * bb[j];
        }
        __syncthreads();
    }

    float bvals[4];
    #pragma unroll
    for (int j = 0; j < 4; ++j) {
        const int col = bn + tx * 4 + j;
        bvals[j] = (col < N) ? bias[col] : 0.f;
    }
    #pragma unroll
    for (int i = 0; i < 4; ++i) {
        const int row = bm + ty * 4 + i;
        if (row >= M) continue;
        float v[4];
        #pragma unroll
        for (int j = 0; j < 4; ++j) {
            v[j] = acc[i][j] + bvals[j];
            if (RELU) v[j] = fmaxf(v[j], 0.f);
        }
        if (bn + tx * 4 + 3 < N) {
            st4(C + (size_t)row * N + bn + tx * 4, make_float4(v[0], v[1], v[2], v[3]));
        } else {
            #pragma unroll
            for (int j = 0; j < 4; ++j) {
                const int col = bn + tx * 4 + j;
                if (col < N) st1(C + (size_t)row * N + col, v[j]);
            }
        }
    }
}

// ---------------------------------------------------------------------------
// Mean-pool over sorted batch ids, with BN fold applied on the fly.
// ---------------------------------------------------------------------------
template<typename InT, bool FOLD>
__global__ __launch_bounds__(256)
void pool_sum(const InT* __restrict__ h, const int* __restrict__ batch,
              const float* __restrict__ st,
              float* __restrict__ sums, float* __restrict__ cnts)
{
    const int c = threadIdx.x;
    size_t n0 = (size_t)blockIdx.x * 128;
    size_t n1 = n0 + 128; if (n1 > (size_t)NN) n1 = NN;
    if (n0 >= (size_t)NN) return;
    const float A = FOLD ? st[512 + c] : 1.f;
    const float B = FOLD ? st[768 + c] : 0.f;
    int cur = batch[n0];
    float s = 0.f, cnt = 0.f;
    for (size_t n = n0; n < n1; ++n) {
        const int b = batch[n];
        if (b != cur) {
            atomicAdd(&sums[(size_t)cur * 256 + c], s);
            if (c == 0) atomicAdd(&cnts[cur], cnt);
            s = 0.f; cnt = 0.f; cur = b;
        }
        const float v = ld1(&h[n * 256 + c]);
        s += fmaf(v, A, B);
        cnt += 1.f;
    }
    atomicAdd(&sums[(size_t)cur * 256 + c], s);
    if (c == 0) atomicAdd(&cnts[cur], cnt);
}

__global__ __launch_bounds__(256)
void pool_div(float* __restrict__ sums, const float* __restrict__ cnts)
{
    const int i = blockIdx.x * 256 + threadIdx.x;   // NG*256 threads exactly
    const int g = i >> 8;
    sums[i] = sums[i] / fmaxf(cnts[g], 1.f);
}

__global__ __launch_bounds__(256)
void head_out(const float* __restrict__ y, const float* __restrict__ Wo,
              const float* __restrict__ bo, float* __restrict__ out)
{
    const int g = blockIdx.x * 256 + threadIdx.x;
    if (g >= NG) return;
    float s = bo[0];
    #pragma unroll
    for (int k = 0; k < 32; ++k) s += y[g * 32 + k] * Wo[k];
    out[g] = s;
}

__global__ __launch_bounds__(256)
void diag_fill(float* __restrict__ out, int n, float v)
{
    const int i = blockIdx.x * 256 + threadIdx.x;
    if (i < n) out[i] = v;
}

// ---------------------------------------------------------------------------
extern "C" void kernel_launch(void* const* d_in, const int* in_sizes, int n_in,
                              void* d_out, int out_size, void* d_ws, size_t ws_size,
                              hipStream_t stream)
{
    const float* x    = (const float*)d_in[0];
    const int*   ei   = (const int*)d_in[1];
    const int*   batch= (const int*)d_in[2];
    const float* ea   = (const float*)d_in[3];
    const float* We[3] = {(const float*)d_in[4],  (const float*)d_in[10], (const float*)d_in[16]};
    const float* be[3] = {(const float*)d_in[5],  (const float*)d_in[11], (const float*)d_in[17]};
    const float* Wn[3] = {(const float*)d_in[6],  (const float*)d_in[12], (const float*)d_in[18]};
    const float* bnb[3]= {(const float*)d_in[7],  (const float*)d_in[13], (const float*)d_in[19]};
    const float* gm[3] = {(const float*)d_in[8],  (const float*)d_in[14], (const float*)d_in[20]};
    const float* bt[3] = {(const float*)d_in[9],  (const float*)d_in[15], (const float*)d_in[21]};
    const float* Wd0 = (const float*)d_in[22]; const float* bd0 = (const float*)d_in[23];
    const float* Wd1 = (const float*)d_in[24]; const float* bd1 = (const float*)d_in[25];
    const float* Wd2 = (const float*)d_in[26]; const float* bd2 = (const float*)d_in[27];
    const float* Wo  = (const float*)d_in[28]; const float* bo  = (const float*)d_in[29];
    float* out = (float*)d_out;
    float* ws  = (float*)d_ws;

    // ---- workspace layout (float offsets; 16B alignment kept) ----
    constexpr size_t OFF_H    = 0;                            // NN*256 bf16
    constexpr size_t OFF_AGG  = 25600000;                     // NN*256 bf16
    constexpr size_t OFF_ST   = 51200000;                     // 1536 fl
    constexpr size_t OFF_WT0  = OFF_ST + 1536;                // 128*256 bf16
    constexpr size_t OFF_WT1  = OFF_WT0 + 16384;              // 256*256 bf16
    constexpr size_t OFF_WT2  = OFF_WT1 + 32768;              // 256*256 bf16
    constexpr size_t OFF_WTE0 = OFF_WT2 + 32768;              // 128*32 bf16
    constexpr size_t OFF_WTE1 = OFF_WTE0 + 2048;              // 256*32 bf16
    constexpr size_t OFF_WTE2 = OFF_WTE1 + 4096;              // 256*32 bf16
    constexpr size_t OFF_EA   = OFF_WTE2 + 4096;              // NE*32 bf16
    constexpr size_t OFF_SRC  = OFF_EA + 12800000;            // NE int
    constexpr size_t OFF_RP   = OFF_SRC + NE;                 // NN+1 int
    constexpr size_t OFF_CUR  = OFF_RP + (NN + 1);            // NN int
    constexpr size_t OFF_PERM = OFF_CUR + NN;                 // NE int
    constexpr size_t OFF_BSUM = OFF_PERM + NE;                // SCAN_NBLK int
    constexpr size_t OFF_NB   = OFF_BSUM + SCAN_NBLK;         // NB+1 int
    constexpr size_t BASE_END = OFF_NB + (NB + 4);
    constexpr size_t NEED_BASE = BASE_END * 4;

    bf16*  H        = (bf16*)(ws + OFF_H);
    bf16*  AGG      = (bf16*)(ws + OFF_AGG);
    float* st       = ws + OFF_ST;
    bf16*  wt0      = (bf16*)(ws + OFF_WT0);
    bf16*  wt1      = (bf16*)(ws + OFF_WT1);
    bf16*  wt2      = (bf16*)(ws + OFF_WT2);
    bf16*  wte[3]   = {(bf16*)(ws + OFF_WTE0), (bf16*)(ws + OFF_WTE1), (bf16*)(ws + OFF_WTE2)};
    bf16*  ea_bf    = (bf16*)(ws + OFF_EA);
    int*   src_perm = (int*)(ws + OFF_SRC);
    int*   row_ptr  = (int*)(ws + OFF_RP);
    int*   cursor   = (int*)(ws + OFF_CUR);
    int*   perm     = (int*)(ws + OFF_PERM);
    int*   bsum     = (int*)(ws + OFF_BSUM);
    int*   nb       = (int*)(ws + OFF_NB);

    if (ws_size < NEED_BASE) {
        diag_fill<<<(NG + 255) / 256, 256, 0, stream>>>(out, NG, (float)(ws_size >> 20));
        return;
    }

    // ---- one-time prep: CSR build, edge pre-gather, weight transpose ----
    hipMemsetAsync(row_ptr, 0, (size_t)(NN + 1) * 4, stream);
    k_hist<<<1024, 256, 0, stream>>>(ei, row_ptr);
    k_scan_block<<<SCAN_NBLK, 256, 0, stream>>>(row_ptr, bsum);
    k_scan_top<<<1, 256, 0, stream>>>(bsum, SCAN_NBLK);
    k_scan_emit<<<SCAN_NBLK, 256, 0, stream>>>(row_ptr, bsum, row_ptr, cursor);
    k_scatter<<<1024, 256, 0, stream>>>(ei, cursor, perm);
    k_bounds2<<<(NB + 256) / 256, 256, 0, stream>>>(row_ptr, nb);
    k_gather_edges_bf<<<(NE * 16 + 255) / 256, 256, 0, stream>>>(ei, ea, perm, src_perm, ea_bf);
    k_wte<<<(128 * 32 + 255) / 256, 256, 0, stream>>>(We[0], wte[0], 128);
    k_wte<<<(256 * 32 + 255) / 256, 256, 0, stream>>>(We[1], wte[1], 256);
    k_wte<<<(256 * 32 + 255) / 256, 256, 0, stream>>>(We[2], wte[2], 256);
    k_wt<<<(128 * 256 + 255) / 256, 256, 0, stream>>>(Wn[0], wt0, 128, 256);
    k_wt<<<(256 * 256 + 255) / 256, 256, 0, stream>>>(Wn[1], wt1, 256, 256);
    k_wt<<<(256 * 256 + 255) / 256, 256, 0, stream>>>(Wn[2], wt2, 256, 256);

    const dim3 mfma_grid(2, (NN + 127) / 128);    // conv GEMMs: N=256

    // ---- layer 0 (cin=128 -> 256), input x fp32, no fold ----
    fused_agg128<float, false><<<NB, 256, 0, stream>>>(
        x, ea_bf, wte[0], be[0], src_perm, row_ptr, nb, st, AGG);
    hipMemsetAsync(st, 0, 512 * 4, stream);
    gemm_mfma<128, true><<<mfma_grid, 256, 0, stream>>>(AGG, wt0, bnb[0], H, NN, st);
    k_bnab<<<1, 256, 0, stream>>>(st, gm[0], bt[0]);

    // ---- layers 1,2 (256 -> 256), input H bf16 raw + fold(A,B) ----
    for (int l = 1; l < 3; ++l) {
        fused_agg256<bf16, true><<<NB, 512, 0, stream>>>(
            H, ea_bf, wte[l], be[l], src_perm, row_ptr, nb, st, AGG);
        hipMemsetAsync(st, 0, 512 * 4, stream);
        gemm_mfma<256, true><<<mfma_grid, 256, 0, stream>>>(
            AGG, (l == 1) ? wt1 : wt2, bnb[l], H, NN, st);
        k_bnab<<<1, 256, 0, stream>>>(st, gm[l], bt[l]);
    }

    // ---- head scratch overlays AGG (dead after last conv GEMM) ----
    float* poolb = (float*)AGG;           // NG*256 = 1,024,000 fl
    float* cnts  = poolb + 1024000;       // NG
    float* y1    = poolb + 1028000;       // NG*512
    float* y2    = poolb + 3076000;       // NG*128
    float* y3    = poolb + 3588000;       // NG*32

    hipMemsetAsync(poolb, 0, (size_t)NG * 256 * 4, stream);
    hipMemsetAsync(cnts, 0, (size_t)NG * 4, stream);
    pool_sum<bf16, true><<<(NN + 127) / 128, 256, 0, stream>>>(H, batch, st, poolb, cnts);
    pool_div<<<NG, 256, 0, stream>>>(poolb, cnts);

    // ---- dense head (fp32) ----
    gemm_rk<true, float, float><<<dim3(8, (NG + 63) / 64), 256, 0, stream>>>(poolb, Wd0, bd0, y1, NG, 512, 256);
    gemm_rk<true, float, float><<<dim3(2, (NG + 63) / 64), 256, 0, stream>>>(y1, Wd1, bd1, y2, NG, 128, 512);
    gemm_rk<true, float, float><<<dim3(1, (NG + 63) / 64), 256, 0, stream>>>(y2, Wd2, bd2, y3, NG, 32, 128);
    head_out<<<(NG + 255) / 256, 256, 0, stream>>>(y3, Wo, bo, out);
}

// Round 7
// 1337.224 us; speedup vs baseline: 1.6598x; 1.1051x over previous
//
#include <hip/hip_runtime.h>
#include <hip/hip_bf16.h>

using bf16 = __hip_bfloat16;
typedef __attribute__((ext_vector_type(8))) short bf16x8;   // 8 bf16 (4 VGPRs)
typedef __attribute__((ext_vector_type(4))) float f32x4;    // MFMA accumulator

constexpr int NN = 200000;   // nodes
constexpr int NE = 800000;   // edges
constexpr int NG = 4000;     // graphs
constexpr int ED = 16;       // edge feature dim
constexpr float BN_EPS = 1e-5f;

constexpr int WSTEP = 88;                              // block weight step
constexpr int NB    = (NE + NN + WSTEP - 1) / WSTEP;   // 11364 fused blocks

// ---------------- storage-type helpers (fp32 or bf16 node features) --------
__device__ __forceinline__ float  ld1(const float* p) { return *p; }
__device__ __forceinline__ float  ld1(const bf16*  p) { return __bfloat162float(*p); }
__device__ __forceinline__ float2 ld2f(const float* p) { return *(const float2*)p; }
__device__ __forceinline__ float2 ld2f(const bf16*  p) {
    union { ushort2 u; bf16 h[2]; } t;
    t.u = *(const ushort2*)p;
    return make_float2(__bfloat162float(t.h[0]), __bfloat162float(t.h[1]));
}
__device__ __forceinline__ float4 ld4(const float* p) { return *(const float4*)p; }
__device__ __forceinline__ float4 ld4(const bf16*  p) {
    union { ushort4 u; bf16 h[4]; } t;
    t.u = *(const ushort4*)p;
    return make_float4(__bfloat162float(t.h[0]), __bfloat162float(t.h[1]),
                       __bfloat162float(t.h[2]), __bfloat162float(t.h[3]));
}
__device__ __forceinline__ void st1(float* p, float v) { *p = v; }
__device__ __forceinline__ void st1(bf16*  p, float v) { *p = __float2bfloat16(v); }
__device__ __forceinline__ void st4(float* p, float4 v) { *(float4*)p = v; }
__device__ __forceinline__ void st4(bf16*  p, float4 v) {
    union { ushort4 u; bf16 h[4]; } t;
    t.h[0] = __float2bfloat16(v.x); t.h[1] = __float2bfloat16(v.y);
    t.h[2] = __float2bfloat16(v.z); t.h[3] = __float2bfloat16(v.w);
    *(ushort4*)p = t.u;
}
__device__ __forceinline__ float bfraw(unsigned short u) {
    union { unsigned short s; bf16 h; } t; t.s = u;
    return __bfloat162float(t.h);
}

// async global -> LDS, 16 B per lane (m97 pattern). LDS dest must be the
// wave-uniform chunk base; HW adds lane*16.
__device__ __forceinline__ void gld16(const void* g, void* l)
{
    __builtin_amdgcn_global_load_lds(
        (const __attribute__((address_space(1))) void*)g,
        (__attribute__((address_space(3))) void*)l, 16, 0, 0);
}

// ===========================================================================
// CSR-by-dst build (once per call; reused by all 3 conv layers)
// ===========================================================================
constexpr int SCAN_CHUNK = 1024;
constexpr int SCAN_NBLK  = (NN + SCAN_CHUNK - 1) / SCAN_CHUNK;   // 196

__global__ __launch_bounds__(256)
void k_hist(const int* __restrict__ ei, int* __restrict__ cnt)
{
    int e = blockIdx.x * 256 + threadIdx.x;
    const int stride = gridDim.x * 256;
    for (; e < NE; e += stride) atomicAdd(&cnt[ei[NE + e]], 1);
}

__global__ __launch_bounds__(256)
void k_scan_block(const int* __restrict__ cnt, int* __restrict__ bsum)
{
    __shared__ int red[256];
    const int b = blockIdx.x, t = threadIdx.x;
    const int base = b * SCAN_CHUNK + t * 4;
    int s = 0;
    #pragma unroll
    for (int k = 0; k < 4; ++k) { const int i = base + k; if (i < NN) s += cnt[i]; }
    red[t] = s; __syncthreads();
    for (int off = 128; off > 0; off >>= 1) {
        if (t < off) red[t] += red[t + off];
        __syncthreads();
    }
    if (t == 0) bsum[b] = red[0];
}

__global__ __launch_bounds__(256)
void k_scan_top(int* __restrict__ bsum, int n)
{
    __shared__ int sh[256];
    const int t = threadIdx.x;
    const int orig = (t < n) ? bsum[t] : 0;
    sh[t] = orig; __syncthreads();
    for (int off = 1; off < 256; off <<= 1) {
        const int v = (t >= off) ? sh[t - off] : 0;
        __syncthreads();
        sh[t] += v;
        __syncthreads();
    }
    if (t < n) bsum[t] = sh[t] - orig;   // exclusive
}

__global__ __launch_bounds__(256)
void k_scan_emit(const int* __restrict__ cnt, const int* __restrict__ bsum,
                 int* __restrict__ row_ptr, int* __restrict__ cursor)
{
    __shared__ int sh[256];
    const int b = blockIdx.x, t = threadIdx.x;
    const int base = b * SCAN_CHUNK + t * 4;
    int c[4]; int s = 0;
    #pragma unroll
    for (int k = 0; k < 4; ++k) {
        const int i = base + k;
        c[k] = (i < NN) ? cnt[i] : 0;    // read BEFORE aliased write below
        s += c[k];
    }
    const int orig = s;
    sh[t] = s; __syncthreads();
    for (int off = 1; off < 256; off <<= 1) {
        const int v = (t >= off) ? sh[t - off] : 0;
        __syncthreads();
        sh[t] += v;
        __syncthreads();
    }
    int run = bsum[b] + sh[t] - orig;     // exclusive prefix of this thread
    #pragma unroll
    for (int k = 0; k < 4; ++k) {
        const int i = base + k;
        if (i < NN) { row_ptr[i] = run; cursor[i] = run; run += c[k]; }
    }
    if (b == 0 && t == 0) row_ptr[NN] = NE;
}

__global__ __launch_bounds__(256)
void k_scatter(const int* __restrict__ ei, int* __restrict__ cursor,
               int* __restrict__ perm)
{
    int e = blockIdx.x * 256 + threadIdx.x;
    const int stride = gridDim.x * 256;
    for (; e < NE; e += stride) {
        const int d = ei[NE + e];
        const int p = atomicAdd(&cursor[d], 1);
        perm[p] = e;
    }
}

// Fused-block boundaries: nb[t] = first node of block t, by binary search on
// W(n) = row_ptr[n] + n with target t*(NE+NN)/NB.  Block weight <= step +
// max node weight (~20 here) <= 128, so edges/block <= 128 and nodes/block
// <= 128 (both clamped in the consumer as insurance).
__global__ __launch_bounds__(256)
void k_bounds2(const int* __restrict__ row_ptr, int* __restrict__ nb)
{
    const int t = blockIdx.x * 256 + threadIdx.x;
    if (t > NB) return;
    const long long target = (long long)t * (NE + NN) / NB;
    int lo = 0, hi = NN;
    while (lo < hi) {
        const int mid = (lo + hi) >> 1;
        const long long W = (long long)row_ptr[mid] + mid;
        if (W >= target) hi = mid; else lo = mid + 1;
    }
    nb[t] = lo;
}

// Edge features as bf16 [NE,32] in perm order, zero-padded K 16->32.
__global__ __launch_bounds__(256)
void k_gather_edges_bf(const int* __restrict__ ei, const float* __restrict__ ea,
                       const int* __restrict__ perm, int* __restrict__ src_perm,
                       bf16* __restrict__ ea_bf)
{
    const int t = blockIdx.x * 256 + threadIdx.x;    // over NE*16 (2 bf16 each)
    if (t >= NE * 16) return;
    const int idx = t >> 4, k2 = (t & 15) * 2;       // k2 in 0..30
    const int e = perm[idx];
    union { ushort2 u; bf16 h[2]; } o;
    if (k2 < ED) {
        const float2 v = *(const float2*)&ea[(size_t)e * ED + k2];
        o.h[0] = __float2bfloat16(v.x);
        o.h[1] = __float2bfloat16(v.y);
    } else {
        o.u = make_ushort2(0, 0);
    }
    *(ushort2*)&ea_bf[(size_t)idx * 32 + k2] = o.u;
    if ((t & 15) == 0) src_perm[idx] = ei[e];
}

// One-shot: W[K,N] fp32 -> Wt[N,K] bf16 (transposed for the MFMA GEMM).
__global__ __launch_bounds__(256)
void k_wt(const float* __restrict__ W, bf16* __restrict__ Wt, int K, int N)
{
    const int i = blockIdx.x * 256 + threadIdx.x;
    if (i >= K * N) return;
    const int k = i / N, n = i % N;
    Wt[(size_t)n * K + k] = __float2bfloat16(W[i]);
}

// One-shot: We[16,cin] fp32 -> Wte[cin,32] bf16, K zero-padded 16->32.
__global__ __launch_bounds__(256)
void k_wte(const float* __restrict__ We, bf16* __restrict__ Wte, int cin)
{
    const int i = blockIdx.x * 256 + threadIdx.x;    // over cin*32
    if (i >= cin * 32) return;
    const int n = i >> 5, k = i & 31;
    Wte[i] = __float2bfloat16((k < ED) ? We[k * cin + n] : 0.f);
}

// BN fold coefficients: A = g*rsqrt(var+eps), B = beta - mu*A.
// st layout: [0..255]=sum, [256..511]=sumsq, [512..767]=A, [768..1023]=B.
__global__ __launch_bounds__(256)
void k_bnab(float* __restrict__ st, const float* __restrict__ g,
            const float* __restrict__ b)
{
    const int c = threadIdx.x;
    const float inv = 1.f / (float)NN;
    const float mu  = st[c] * inv;
    const float var = st[256 + c] * inv - mu * mu;
    const float A   = g[c] * rsqrtf(var + BN_EPS);
    st[512 + c] = A;
    st[768 + c] = b[c] - mu * A;
}

// ===========================================================================
// FUSED edge-MLP + aggregation, CIN=128 (layer 0), 512 threads / 8 waves.
// Phase 1: 8 waves = 4x2 strips (32 rows x 64 cols) of the 128x128 MFMA tile.
// Phase 2: nodes strided by 8 waves; row_ptr/src staged in LDS (kills two
// global-latency levels of the per-node chain); 8-deep gather batch.
// ===========================================================================
template<typename XT, bool FOLD>
__global__ __launch_bounds__(512)
void fused_agg128(const XT* __restrict__ x, const bf16* __restrict__ ea_bf,
                  const bf16* __restrict__ Wte, const float* __restrict__ be,
                  const int* __restrict__ src_perm, const int* __restrict__ row_ptr,
                  const int* __restrict__ nb, const float* __restrict__ st,
                  bf16* __restrict__ agg)
{
    constexpr int CIN  = 128;
    constexpr int MSTR = CIN + 8;                  // msg LDS row stride (bf16)
    constexpr int CPL  = 2;                        // channels per lane
    __shared__ short ea_s[128 * 32];               // 8 KB
    __shared__ short msg[128 * MSTR];              // 34.8 KB
    __shared__ int   src_lds[128];
    __shared__ int   rp_lds[132];

    const int tid  = threadIdx.x;
    const int lane = tid & 63;
    const int wv   = tid >> 6;                     // 0..7
    const int b    = blockIdx.x;
    const int n0 = nb[b], n1 = nb[b + 1];
    if (n0 >= n1) return;
    const int e0 = row_ptr[n0];
    const int e1 = row_ptr[n1];
    int ne = e1 - e0; if (ne > 128) ne = 128;      // insurance clamp
    int nnb = n1 - n0; if (nnb > 128) nnb = 128;   // insurance clamp

    const int l15  = lane & 15;
    const int quad = lane >> 4;
    const int rsub = lane >> 2;
    const int part = lane & 3;

    // ---- stage ea rows: 8 waves x 16 rows, 1 gld16 per thread ----
    {
        int r = wv * 16 + rsub;
        if (r >= ne) r = ne - 1;
        gld16(&ea_bf[(size_t)(e0 + r) * 32 + part * 8], &ea_s[wv * 512]);
    }
    // ---- stage src + row_ptr slices (contiguous; overlaps with gld16) ----
    if (tid < 128) {
        const int i = (tid < ne) ? tid : ne - 1;
        src_lds[tid] = src_perm[e0 + i];
    } else if (tid < 384) {
        const int i = tid - 128;
        if (i <= nnb) rp_lds[i] = row_ptr[n0 + i];
    }

    // ---- Wte fragments + bias: wave strip (wr=32-row, wc=64-col) ----
    const int wc = (wv & 1) * 64;
    const int wr = (wv >> 1) * 32;
    bf16x8 bfr[4];
    #pragma unroll
    for (int i = 0; i < 4; ++i)
        bfr[i] = *(const bf16x8*)&Wte[(size_t)(wc + i * 16 + l15) * 32 + quad * 8];
    float bv[4];
    #pragma unroll
    for (int ni = 0; ni < 4; ++ni)
        bv[ni] = be[wc + ni * 16 + l15];

    __syncthreads();                               // ea + src + rp staged

    // ---- phase 1: MFMA edge-MLP -> msg LDS (8 MFMA per wave) ----
    {
        f32x4 acc[2][4];
        #pragma unroll
        for (int i = 0; i < 2; ++i)
            #pragma unroll
            for (int j = 0; j < 4; ++j)
                acc[i][j] = (f32x4){0.f, 0.f, 0.f, 0.f};
        bf16x8 af[2];
        #pragma unroll
        for (int i = 0; i < 2; ++i)
            af[i] = *(const bf16x8*)&ea_s[(wr + i * 16 + l15) * 32 + quad * 8];
        #pragma unroll
        for (int mi = 0; mi < 2; ++mi)
            #pragma unroll
            for (int ni = 0; ni < 4; ++ni)
                acc[mi][ni] = __builtin_amdgcn_mfma_f32_16x16x32_bf16(
                                  af[mi], bfr[ni], acc[mi][ni], 0, 0, 0);
        #pragma unroll
        for (int mi = 0; mi < 2; ++mi) {
            const int row0 = wr + mi * 16 + quad * 4;
            #pragma unroll
            for (int r = 0; r < 4; ++r) {
                const int row = row0 + r;
                #pragma unroll
                for (int ni = 0; ni < 4; ++ni) {
                    const float v = acc[mi][ni][r] + bv[ni];
                    msg[row * MSTR + wc + ni * 16 + l15] =
                        (short)__bfloat16_as_ushort(__float2bfloat16(v));
                }
            }
        }
    }
    __syncthreads();                               // msg ready

    // ---- phase 2: node-major aggregation, 8-wave stride ----
    const int c0 = lane * CPL;
    float Af[CPL], Bf[CPL];
    #pragma unroll
    for (int q = 0; q < CPL; ++q) {
        Af[q] = FOLD ? st[512 + c0 + q] : 1.f;
        Bf[q] = FOLD ? st[768 + c0 + q] : 0.f;
    }

    for (int ni = wv; ni < nnb; ni += 8) {
        const int node = n0 + ni;
        float acc2[CPL];
        const float2 v = ld2f(&x[(size_t)node * CIN + c0]);
        acc2[0] = fmaf(v.x, Af[0], Bf[0]);
        acc2[1] = fmaf(v.y, Af[1], Bf[1]);

        const int f0 = rp_lds[ni], f1 = rp_lds[ni + 1];
        for (int base2 = f0; base2 < f1; base2 += 8) {
            float2 xv[8]; ushort2 mv[8];
            #pragma unroll
            for (int j = 0; j < 8; ++j) {
                int idx = base2 + j; if (idx >= f1) idx = f1 - 1;
                int l = idx - e0; if (l > 127) l = 127;
                const int sv = src_lds[l];
                xv[j] = ld2f(&x[(size_t)sv * CIN + c0]);
                mv[j] = *(const ushort2*)&msg[l * MSTR + c0];
            }
            #pragma unroll
            for (int j = 0; j < 8; ++j) {
                if (base2 + j < f1) {
                    acc2[0] += fmaxf(fmaf(xv[j].x, Af[0], Bf[0]) + bfraw(mv[j].x), 0.f);
                    acc2[1] += fmaxf(fmaf(xv[j].y, Af[1], Bf[1]) + bfraw(mv[j].y), 0.f);
                }
            }
        }

        union { ushort2 u; bf16 h[2]; } t;
        t.h[0] = __float2bfloat16(acc2[0]);
        t.h[1] = __float2bfloat16(acc2[1]);
        *(ushort2*)&agg[(size_t)node * CIN + c0] = t.u;
    }
}

// ===========================================================================
// FUSED edge-MLP + aggregation, CIN=256 (layers 1,2): 512 threads / 8 waves.
// Phase 1: 8 waves = 2x4 quadrants of the 128x256 MFMA tile (single pass).
// Phase 2: nodes strided by 8 waves; row_ptr/src staged in LDS; 8-deep
// gather batch (raw ushort4 staging keeps VGPR under the 128 bin).
// ===========================================================================
template<bool FOLD>
__global__ __launch_bounds__(512)
void fused_agg256(const bf16* __restrict__ x, const bf16* __restrict__ ea_bf,
                  const bf16* __restrict__ Wte, const float* __restrict__ be,
                  const int* __restrict__ src_perm, const int* __restrict__ row_ptr,
                  const int* __restrict__ nb, const float* __restrict__ st,
                  bf16* __restrict__ agg)
{
    constexpr int CIN  = 256;
    constexpr int MSTR = CIN + 8;                  // msg LDS row stride (bf16)
    constexpr int CPL  = 4;
    __shared__ short ea_s[128 * 32];               // 8 KB
    __shared__ short msg[128 * MSTR];              // 66 KB
    __shared__ int   src_lds[128];
    __shared__ int   rp_lds[132];

    const int tid  = threadIdx.x;
    const int lane = tid & 63;
    const int wv   = tid >> 6;                     // 0..7
    const int b    = blockIdx.x;
    const int n0 = nb[b], n1 = nb[b + 1];
    if (n0 >= n1) return;
    const int e0 = row_ptr[n0];
    const int e1 = row_ptr[n1];
    int ne = e1 - e0; if (ne > 128) ne = 128;      // insurance clamp
    int nnb = n1 - n0; if (nnb > 128) nnb = 128;   // insurance clamp

    const int l15  = lane & 15;
    const int quad = lane >> 4;
    const int rsub = lane >> 2;
    const int part = lane & 3;

    // ---- stage ea rows: 8 waves x 16 rows, 1 gld16 per thread ----
    {
        int r = wv * 16 + rsub;
        if (r >= ne) r = ne - 1;
        gld16(&ea_bf[(size_t)(e0 + r) * 32 + part * 8], &ea_s[wv * 512]);
    }
    // ---- stage src + row_ptr slices (contiguous; overlaps with gld16) ----
    if (tid < 128) {
        const int i = (tid < ne) ? tid : ne - 1;
        src_lds[tid] = src_perm[e0 + i];
    } else if (tid < 384) {
        const int i = tid - 128;
        if (i <= nnb) rp_lds[i] = row_ptr[n0 + i];
    }

    // ---- Wte fragments + bias: wave quadrant (wr, wc) of 128x256 ----
    const int wc = (wv & 3) * 64;
    const int wr = (wv >> 2) * 64;
    bf16x8 bfr[4];
    #pragma unroll
    for (int i = 0; i < 4; ++i)
        bfr[i] = *(const bf16x8*)&Wte[(size_t)(wc + i * 16 + l15) * 32 + quad * 8];
    float bv[4];
    #pragma unroll
    for (int ni = 0; ni < 4; ++ni)
        bv[ni] = be[wc + ni * 16 + l15];

    __syncthreads();                               // ea + src + rp staged

    // ---- phase 1: MFMA edge-MLP -> msg LDS (single pass, 8 quadrants) ----
    {
        f32x4 acc[4][4];
        #pragma unroll
        for (int i = 0; i < 4; ++i)
            #pragma unroll
            for (int j = 0; j < 4; ++j)
                acc[i][j] = (f32x4){0.f, 0.f, 0.f, 0.f};
        bf16x8 af[4];
        #pragma unroll
        for (int i = 0; i < 4; ++i)
            af[i] = *(const bf16x8*)&ea_s[(wr + i * 16 + l15) * 32 + quad * 8];
        #pragma unroll
        for (int mi = 0; mi < 4; ++mi)
            #pragma unroll
            for (int ni = 0; ni < 4; ++ni)
                acc[mi][ni] = __builtin_amdgcn_mfma_f32_16x16x32_bf16(
                                  af[mi], bfr[ni], acc[mi][ni], 0, 0, 0);
        #pragma unroll
        for (int mi = 0; mi < 4; ++mi) {
            const int row0 = wr + mi * 16 + quad * 4;
            #pragma unroll
            for (int r = 0; r < 4; ++r) {
                const int row = row0 + r;
                #pragma unroll
                for (int ni = 0; ni < 4; ++ni) {
                    const float v = acc[mi][ni][r] + bv[ni];
                    msg[row * MSTR + wc + ni * 16 + l15] =
                        (short)__bfloat16_as_ushort(__float2bfloat16(v));
                }
            }
        }
    }
    __syncthreads();                               // msg ready

    // ---- phase 2: node-major aggregation, 8-wave stride ----
    const int c0 = lane * CPL;
    float Af[CPL], Bf[CPL];
    #pragma unroll
    for (int q = 0; q < CPL; ++q) {
        Af[q] = FOLD ? st[512 + c0 + q] : 1.f;
        Bf[q] = FOLD ? st[768 + c0 + q] : 0.f;
    }

    for (int ni = wv; ni < nnb; ni += 8) {
        const int node = n0 + ni;
        float acc2[CPL];
        const float4 v = ld4(&x[(size_t)node * CIN + c0]);
        acc2[0] = fmaf(v.x, Af[0], Bf[0]); acc2[1] = fmaf(v.y, Af[1], Bf[1]);
        acc2[2] = fmaf(v.z, Af[2], Bf[2]); acc2[3] = fmaf(v.w, Af[3], Bf[3]);

        const int f0 = rp_lds[ni], f1 = rp_lds[ni + 1];
        for (int base2 = f0; base2 < f1; base2 += 8) {
            ushort4 xr[8]; ushort4 mv[8];
            #pragma unroll
            for (int j = 0; j < 8; ++j) {
                int idx = base2 + j; if (idx >= f1) idx = f1 - 1;
                int l = idx - e0; if (l > 127) l = 127;
                const int sv = src_lds[l];
                xr[j] = *(const ushort4*)&x[(size_t)sv * CIN + c0];
                mv[j] = *(const ushort4*)&msg[l * MSTR + c0];
            }
            #pragma unroll
            for (int j = 0; j < 8; ++j) {
                if (base2 + j < f1) {
                    acc2[0] += fmaxf(fmaf(bfraw(xr[j].x), Af[0], Bf[0]) + bfraw(mv[j].x), 0.f);
                    acc2[1] += fmaxf(fmaf(bfraw(xr[j].y), Af[1], Bf[1]) + bfraw(mv[j].y), 0.f);
                    acc2[2] += fmaxf(fmaf(bfraw(xr[j].z), Af[2], Bf[2]) + bfraw(mv[j].z), 0.f);
                    acc2[3] += fmaxf(fmaf(bfraw(xr[j].w), Af[3], Bf[3]) + bfraw(mv[j].w), 0.f);
                }
            }
        }

        union { ushort4 u; bf16 h[4]; } t;
        t.h[0] = __float2bfloat16(acc2[0]); t.h[1] = __float2bfloat16(acc2[1]);
        t.h[2] = __float2bfloat16(acc2[2]); t.h[3] = __float2bfloat16(acc2[3]);
        *(ushort4*)&agg[(size_t)node * CIN + c0] = t.u;
    }
}

// ===========================================================================
// Conv MFMA GEMM: C[M,256] = relu(A[M,K] @ Wt[256,K]^T + bias), bf16 out.
// m97-style global_load_lds staging (linear [128][32] LDS, 16 B/lane).
// STATS: per-channel sum/sumsq of post-relu output into st (quad-reduce).
// ===========================================================================
template<int K, bool STATS>
__global__ __launch_bounds__(256, 3)
void gemm_mfma(const bf16* __restrict__ A, const bf16* __restrict__ Wt,
               const float* __restrict__ bias, bf16* __restrict__ C, int M,
               float* __restrict__ st)
{
    __shared__ short As[128 * 32];   // 8 KB, linear
    __shared__ short Bs[128 * 32];
    const int tid  = threadIdx.x;
    const int bm   = blockIdx.y * 128;
    const int bn   = blockIdx.x * 128;      // 0 or 128 (N = 256)
    const int lane = tid & 63;
    const int wave = tid >> 6;
    const int wr   = (wave >> 1) * 64;
    const int wc   = (wave & 1) * 64;
    const int l15  = lane & 15;
    const int quad = lane >> 4;
    const int rsub = lane >> 2;
    const int part = lane & 3;

    f32x4 acc[4][4];
    #pragma unroll
    for (int i = 0; i < 4; ++i)
        #pragma unroll
        for (int j = 0; j < 4; ++j)
            acc[i][j] = (f32x4){0.f, 0.f, 0.f, 0.f};

    for (int k0 = 0; k0 < K; k0 += 32) {
        #pragma unroll
        for (int i = 0; i < 2; ++i) {
            const int ca = wave * 2 + i;
            int ar = bm + ca * 16 + rsub; if (ar >= M) ar = M - 1;
            gld16(&A[(size_t)ar * K + k0 + part * 8], &As[ca * 512]);
            gld16(&Wt[(size_t)(bn + ca * 16 + rsub) * K + k0 + part * 8],
                  &Bs[ca * 512]);
        }
        __syncthreads();

        bf16x8 af[4], bfr[4];
        #pragma unroll
        for (int i = 0; i < 4; ++i) {
            af[i]  = *(const bf16x8*)&As[(wr + i * 16 + l15) * 32 + quad * 8];
            bfr[i] = *(const bf16x8*)&Bs[(wc + i * 16 + l15) * 32 + quad * 8];
        }
        #pragma unroll
        for (int mi = 0; mi < 4; ++mi)
            #pragma unroll
            for (int ni = 0; ni < 4; ++ni)
                acc[mi][ni] = __builtin_amdgcn_mfma_f32_16x16x32_bf16(
                                  af[mi], bfr[ni], acc[mi][ni], 0, 0, 0);
        __syncthreads();
    }

    float bv[4];
    #pragma unroll
    for (int ni = 0; ni < 4; ++ni)
        bv[ni] = bias[bn + wc + ni * 16 + l15];
    float ps[4]  = {0.f, 0.f, 0.f, 0.f};
    float ps2[4] = {0.f, 0.f, 0.f, 0.f};
    #pragma unroll
    for (int mi = 0; mi < 4; ++mi) {
        const int row0 = bm + wr + mi * 16 + quad * 4;
        #pragma unroll
        for (int r = 0; r < 4; ++r) {
            const int row = row0 + r;
            if (row < M) {
                #pragma unroll
                for (int ni = 0; ni < 4; ++ni) {
                    float v = acc[mi][ni][r] + bv[ni];
                    v = fmaxf(v, 0.f);
                    C[(size_t)row * 256 + bn + wc + ni * 16 + l15] = __float2bfloat16(v);
                    if (STATS) { ps[ni] += v; ps2[ni] = fmaf(v, v, ps2[ni]); }
                }
            }
        }
    }
    if (STATS) {
        #pragma unroll
        for (int ni = 0; ni < 4; ++ni) {
            float s = ps[ni], q = ps2[ni];
            s += __shfl_xor(s, 16); s += __shfl_xor(s, 32);
            q += __shfl_xor(q, 16); q += __shfl_xor(q, 32);
            if (quad == 0) {
                const int col = bn + wc + ni * 16 + l15;
                atomicAdd(&st[col], s);
                atomicAdd(&st[256 + col], q);
            }
        }
    }
}

// ---------------------------------------------------------------------------
// fp32 GEMM (dense head only): C = (relu?)(A @ W + bias)
// ---------------------------------------------------------------------------
template<bool RELU, typename InT, typename OutT>
__global__ __launch_bounds__(256)
void gemm_rk(const InT* __restrict__ A, const float* __restrict__ W,
             const float* __restrict__ bias, OutT* __restrict__ C,
             int M, int N, int K)
{
    __shared__ float Asm[16][64];
    __shared__ float Wsm[16][64];
    const int bm = blockIdx.y * 64;
    const int bn = blockIdx.x * 64;
    const int tid = threadIdx.x;
    const int tx = tid & 15, ty = tid >> 4;
    const int ar = tid >> 2, ac = (tid & 3) * 4;
    const int wrr = tid >> 4, wcc = (tid & 15) * 4;

    float acc[4][4] = {};

    for (int k0 = 0; k0 < K; k0 += 16) {
        float4 av = make_float4(0.f, 0.f, 0.f, 0.f);
        if (bm + ar < M)
            av = ld4(A + (size_t)(bm + ar) * K + k0 + ac);
        Asm[ac + 0][ar] = av.x; Asm[ac + 1][ar] = av.y;
        Asm[ac + 2][ar] = av.z; Asm[ac + 3][ar] = av.w;

        float4 wv = make_float4(0.f, 0.f, 0.f, 0.f);
        if (bn + wcc < N)
            wv = *(const float4*)(W + (size_t)(k0 + wrr) * N + bn + wcc);
        *(float4*)&Wsm[wrr][wcc] = wv;
        __syncthreads();

        #pragma unroll
        for (int k = 0; k < 16; ++k) {
            const float4 a4 = *(const float4*)&Asm[k][ty * 4];
            const float4 b4 = *(const float4*)&Wsm[k][tx * 4];
            const float aa[4] = {a4.x, a4.y, a4.z, a4.w};
            const float bb[4] = {b4.x, b4.y, b4.z, b4.w};
            #pragma unroll
            for (int i = 0; i < 4; ++i)
                #pragma unroll
                for (int j = 0; j < 4; ++j)
                    acc[i][j] += aa[i] * bb[j];
        }
        __syncthreads();
    }

    float bvals[4];
    #pragma unroll
    for (int j = 0; j < 4; ++j) {
        const int col = bn + tx * 4 + j;
        bvals[j] = (col < N) ? bias[col] : 0.f;
    }
    #pragma unroll
    for (int i = 0; i < 4; ++i) {
        const int row = bm + ty * 4 + i;
        if (row >= M) continue;
        float v[4];
        #pragma unroll
        for (int j = 0; j < 4; ++j) {
            v[j] = acc[i][j] + bvals[j];
            if (RELU) v[j] = fmaxf(v[j], 0.f);
        }
        if (bn + tx * 4 + 3 < N) {
            st4(C + (size_t)row * N + bn + tx * 4, make_float4(v[0], v[1], v[2], v[3]));
        } else {
            #pragma unroll
            for (int j = 0; j < 4; ++j) {
                const int col = bn + tx * 4 + j;
                if (col < N) st1(C + (size_t)row * N + col, v[j]);
            }
        }
    }
}

// ---------------------------------------------------------------------------
// Mean-pool over sorted batch ids, with BN fold applied on the fly.
// ---------------------------------------------------------------------------
template<typename InT, bool FOLD>
__global__ __launch_bounds__(256)
void pool_sum(const InT* __restrict__ h, const int* __restrict__ batch,
              const float* __restrict__ st,
              float* __restrict__ sums, float* __restrict__ cnts)
{
    const int c = threadIdx.x;
    size_t n0 = (size_t)blockIdx.x * 128;
    size_t n1 = n0 + 128; if (n1 > (size_t)NN) n1 = NN;
    if (n0 >= (size_t)NN) return;
    const float A = FOLD ? st[512 + c] : 1.f;
    const float B = FOLD ? st[768 + c] : 0.f;
    int cur = batch[n0];
    float s = 0.f, cnt = 0.f;
    for (size_t n = n0; n < n1; ++n) {
        const int b = batch[n];
        if (b != cur) {
            atomicAdd(&sums[(size_t)cur * 256 + c], s);
            if (c == 0) atomicAdd(&cnts[cur], cnt);
            s = 0.f; cnt = 0.f; cur = b;
        }
        const float v = ld1(&h[n * 256 + c]);
        s += fmaf(v, A, B);
        cnt += 1.f;
    }
    atomicAdd(&sums[(size_t)cur * 256 + c], s);
    if (c == 0) atomicAdd(&cnts[cur], cnt);
}

__global__ __launch_bounds__(256)
void pool_div(float* __restrict__ sums, const float* __restrict__ cnts)
{
    const int i = blockIdx.x * 256 + threadIdx.x;   // NG*256 threads exactly
    const int g = i >> 8;
    sums[i] = sums[i] / fmaxf(cnts[g], 1.f);
}

__global__ __launch_bounds__(256)
void head_out(const float* __restrict__ y, const float* __restrict__ Wo,
              const float* __restrict__ bo, float* __restrict__ out)
{
    const int g = blockIdx.x * 256 + threadIdx.x;
    if (g >= NG) return;
    float s = bo[0];
    #pragma unroll
    for (int k = 0; k < 32; ++k) s += y[g * 32 + k] * Wo[k];
    out[g] = s;
}

__global__ __launch_bounds__(256)
void diag_fill(float* __restrict__ out, int n, float v)
{
    const int i = blockIdx.x * 256 + threadIdx.x;
    if (i < n) out[i] = v;
}

// ---------------------------------------------------------------------------
extern "C" void kernel_launch(void* const* d_in, const int* in_sizes, int n_in,
                              void* d_out, int out_size, void* d_ws, size_t ws_size,
                              hipStream_t stream)
{
    const float* x    = (const float*)d_in[0];
    const int*   ei   = (const int*)d_in[1];
    const int*   batch= (const int*)d_in[2];
    const float* ea   = (const float*)d_in[3];
    const float* We[3] = {(const float*)d_in[4],  (const float*)d_in[10], (const float*)d_in[16]};
    const float* be[3] = {(const float*)d_in[5],  (const float*)d_in[11], (const float*)d_in[17]};
    const float* Wn[3] = {(const float*)d_in[6],  (const float*)d_in[12], (const float*)d_in[18]};
    const float* bnb[3]= {(const float*)d_in[7],  (const float*)d_in[13], (const float*)d_in[19]};
    const float* gm[3] = {(const float*)d_in[8],  (const float*)d_in[14], (const float*)d_in[20]};
    const float* bt[3] = {(const float*)d_in[9],  (const float*)d_in[15], (const float*)d_in[21]};
    const float* Wd0 = (const float*)d_in[22]; const float* bd0 = (const float*)d_in[23];
    const float* Wd1 = (const float*)d_in[24]; const float* bd1 = (const float*)d_in[25];
    const float* Wd2 = (const float*)d_in[26]; const float* bd2 = (const float*)d_in[27];
    const float* Wo  = (const float*)d_in[28]; const float* bo  = (const float*)d_in[29];
    float* out = (float*)d_out;
    float* ws  = (float*)d_ws;

    // ---- workspace layout (float offsets; 16B alignment kept) ----
    constexpr size_t OFF_H    = 0;                            // NN*256 bf16
    constexpr size_t OFF_AGG  = 25600000;                     // NN*256 bf16
    constexpr size_t OFF_ST   = 51200000;                     // 1536 fl
    constexpr size_t OFF_WT0  = OFF_ST + 1536;                // 128*256 bf16
    constexpr size_t OFF_WT1  = OFF_WT0 + 16384;              // 256*256 bf16
    constexpr size_t OFF_WT2  = OFF_WT1 + 32768;              // 256*256 bf16
    constexpr size_t OFF_WTE0 = OFF_WT2 + 32768;              // 128*32 bf16
    constexpr size_t OFF_WTE1 = OFF_WTE0 + 2048;              // 256*32 bf16
    constexpr size_t OFF_WTE2 = OFF_WTE1 + 4096;              // 256*32 bf16
    constexpr size_t OFF_EA   = OFF_WTE2 + 4096;              // NE*32 bf16
    constexpr size_t OFF_SRC  = OFF_EA + 12800000;            // NE int
    constexpr size_t OFF_RP   = OFF_SRC + NE;                 // NN+1 int
    constexpr size_t OFF_CUR  = OFF_RP + (NN + 1);            // NN int
    constexpr size_t OFF_PERM = OFF_CUR + NN;                 // NE int
    constexpr size_t OFF_BSUM = OFF_PERM + NE;                // SCAN_NBLK int
    constexpr size_t OFF_NB   = OFF_BSUM + SCAN_NBLK;         // NB+1 int
    constexpr size_t BASE_END = OFF_NB + (NB + 4);
    constexpr size_t NEED_BASE = BASE_END * 4;

    bf16*  H        = (bf16*)(ws + OFF_H);
    bf16*  AGG      = (bf16*)(ws + OFF_AGG);
    float* st       = ws + OFF_ST;
    bf16*  wt0      = (bf16*)(ws + OFF_WT0);
    bf16*  wt1      = (bf16*)(ws + OFF_WT1);
    bf16*  wt2      = (bf16*)(ws + OFF_WT2);
    bf16*  wte[3]   = {(bf16*)(ws + OFF_WTE0), (bf16*)(ws + OFF_WTE1), (bf16*)(ws + OFF_WTE2)};
    bf16*  ea_bf    = (bf16*)(ws + OFF_EA);
    int*   src_perm = (int*)(ws + OFF_SRC);
    int*   row_ptr  = (int*)(ws + OFF_RP);
    int*   cursor   = (int*)(ws + OFF_CUR);
    int*   perm     = (int*)(ws + OFF_PERM);
    int*   bsum     = (int*)(ws + OFF_BSUM);
    int*   nb       = (int*)(ws + OFF_NB);

    if (ws_size < NEED_BASE) {
        diag_fill<<<(NG + 255) / 256, 256, 0, stream>>>(out, NG, (float)(ws_size >> 20));
        return;
    }

    // ---- one-time prep: CSR build, edge pre-gather, weight transpose ----
    hipMemsetAsync(row_ptr, 0, (size_t)(NN + 1) * 4, stream);
    k_hist<<<1024, 256, 0, stream>>>(ei, row_ptr);
    k_scan_block<<<SCAN_NBLK, 256, 0, stream>>>(row_ptr, bsum);
    k_scan_top<<<1, 256, 0, stream>>>(bsum, SCAN_NBLK);
    k_scan_emit<<<SCAN_NBLK, 256, 0, stream>>>(row_ptr, bsum, row_ptr, cursor);
    k_scatter<<<1024, 256, 0, stream>>>(ei, cursor, perm);
    k_bounds2<<<(NB + 256) / 256, 256, 0, stream>>>(row_ptr, nb);
    k_gather_edges_bf<<<(NE * 16 + 255) / 256, 256, 0, stream>>>(ei, ea, perm, src_perm, ea_bf);
    k_wte<<<(128 * 32 + 255) / 256, 256, 0, stream>>>(We[0], wte[0], 128);
    k_wte<<<(256 * 32 + 255) / 256, 256, 0, stream>>>(We[1], wte[1], 256);
    k_wte<<<(256 * 32 + 255) / 256, 256, 0, stream>>>(We[2], wte[2], 256);
    k_wt<<<(128 * 256 + 255) / 256, 256, 0, stream>>>(Wn[0], wt0, 128, 256);
    k_wt<<<(256 * 256 + 255) / 256, 256, 0, stream>>>(Wn[1], wt1, 256, 256);
    k_wt<<<(256 * 256 + 255) / 256, 256, 0, stream>>>(Wn[2], wt2, 256, 256);

    const dim3 mfma_grid(2, (NN + 127) / 128);    // conv GEMMs: N=256

    // ---- layer 0 (cin=128 -> 256), input x fp32, no fold ----
    fused_agg128<float, false><<<NB, 512, 0, stream>>>(
        x, ea_bf, wte[0], be[0], src_perm, row_ptr, nb, st, AGG);
    hipMemsetAsync(st, 0, 512 * 4, stream);
    gemm_mfma<128, true><<<mfma_grid, 256, 0, stream>>>(AGG, wt0, bnb[0], H, NN, st);
    k_bnab<<<1, 256, 0, stream>>>(st, gm[0], bt[0]);

    // ---- layers 1,2 (256 -> 256), input H bf16 raw + fold(A,B) ----
    for (int l = 1; l < 3; ++l) {
        fused_agg256<true><<<NB, 512, 0, stream>>>(
            H, ea_bf, wte[l], be[l], src_perm, row_ptr, nb, st, AGG);
        hipMemsetAsync(st, 0, 512 * 4, stream);
        gemm_mfma<256, true><<<mfma_grid, 256, 0, stream>>>(
            AGG, (l == 1) ? wt1 : wt2, bnb[l], H, NN, st);
        k_bnab<<<1, 256, 0, stream>>>(st, gm[l], bt[l]);
    }

    // ---- head scratch overlays AGG (dead after last conv GEMM) ----
    float* poolb = (float*)AGG;           // NG*256 = 1,024,000 fl
    float* cnts  = poolb + 1024000;       // NG
    float* y1    = poolb + 1028000;       // NG*512
    float* y2    = poolb + 3076000;       // NG*128
    float* y3    = poolb + 3588000;       // NG*32

    hipMemsetAsync(poolb, 0, (size_t)NG * 256 * 4, stream);
    hipMemsetAsync(cnts, 0, (size_t)NG * 4, stream);
    pool_sum<bf16, true><<<(NN + 127) / 128, 256, 0, stream>>>(H, batch, st, poolb, cnts);
    pool_div<<<NG, 256, 0, stream>>>(poolb, cnts);

    // ---- dense head (fp32) ----
    gemm_rk<true, float, float><<<dim3(8, (NG + 63) / 64), 256, 0, stream>>>(poolb, Wd0, bd0, y1, NG, 512, 256);
    gemm_rk<true, float, float><<<dim3(2, (NG + 63) / 64), 256, 0, stream>>>(y1, Wd1, bd1, y2, NG, 128, 512);
    gemm_rk<true, float, float><<<dim3(1, (NG + 63) / 64), 256, 0, stream>>>(y2, Wd2, bd2, y3, NG, 32, 128);
    head_out<<<(NG + 255) / 256, 256, 0, stream>>>(y3, Wo, bo, out);
}